// Round 2
// baseline (1243.640 us; speedup 1.0000x reference)
//
#include <hip/hip_runtime.h>
#include <hip/hip_bf16.h>

using bf16 = __hip_bfloat16;

#define N_NODES 8192

static __device__ __forceinline__ float b2f(bf16 v) { return __bfloat162float(v); }

// ---------------- workspace layout (float offsets from fb) ----------------
// ints (alias float region start):
//   cnt    [0, 8192)      rowptr [8192, 16385)
//   fill   [16448, 24640) ssrc   [24640, 286784)
//   flag   ib[286784]
#define OFF_DIS 286848
#define OFF_W   295040
#define OFF_C   410880    /* 8192*64  : x32 -> z -> Bo (attention out) */
#define OFF_D   935168    /* 8192*128 : gemm out; flash partials spill into E */
#define OFF_E   1983744   /* 8192*128 : h1/h3/za/g2 */
#define OFF_F   3032320   /* 8192*128 : h2/g1/g3; qkv bf16 home */
// total: 4080896 floats = 16.32 MB

// canonical weight offsets (relative to OFF_W)
#define W_E1 0
#define W_E2 8192
#define W_E3 24576
#define W_E4 40960
#define W_D1 49152
#define W_D2 57344
#define W_D3 73728
#define W_D4 90112
#define W_AIW 98304     /* transposed: [64,192] */
#define W_AOW 110592    /* transposed: [64,64]  */
#define B_E1 114688
#define B_E2 114816
#define B_E3 114944
#define B_E4 115072
#define B_D1 115136
#define B_D2 115264
#define B_D3 115392
#define B_D4 115520
#define B_AI 115584
#define B_AO 115776

// ---------------- dtype sniff ----------------
// Genuine bf16 ~N(0,1): exponent field in [~118,130]. fp32 data read as bf16:
// even-position words are float mantissa bits -> near-uniform exponents.
__global__ void k_sniff(const unsigned short* __restrict__ xb, int* __restrict__ flagp) {
    __shared__ int cnt;
    if (threadIdx.x == 0) cnt = 0;
    __syncthreads();
    unsigned short w = xb[threadIdx.x * 2];   // even bf16 positions, first 1KB
    int e = (w >> 7) & 0xFF;
    int m = w & 0x7F;
    int weird = (e >= 134) || (e != 0 && e <= 90) || (e == 0 && m != 0);
    if (weird) atomicAdd(&cnt, 1);
    __syncthreads();
    if (threadIdx.x == 0) *flagp = (cnt >= 32) ? 1 : 0;   // 1 => inputs are fp32
}

// ---------------- input canonicalization to fp32 ----------------
struct CvtEnt { const void* src; int dst; int n; int cols; int tld; };
struct CvtTab { CvtEnt e[21]; };

__global__ void k_convert(CvtTab tab, float* __restrict__ fb, const int* __restrict__ flagp) {
    int i = blockIdx.x * blockDim.x + threadIdx.x;
    int fl = *flagp;
#pragma unroll 1
    for (int t = 0; t < 21; t++) {
        int n = tab.e[t].n;
        if (i < n) {
            float v = fl ? ((const float*)tab.e[t].src)[i]
                         : b2f(((const bf16*)tab.e[t].src)[i]);
            int d;
            if (tab.e[t].tld) {
                int r = i / tab.e[t].cols, c = i - r * tab.e[t].cols;
                d = tab.e[t].dst + c * tab.e[t].tld + r;
            } else {
                d = tab.e[t].dst + i;
            }
            fb[d] = v;
            return;
        }
        i -= n;
    }
}

// ---------------- CSR construction ----------------
__global__ void k_zero_int(int* __restrict__ p, int n) {
    int i = blockIdx.x * blockDim.x + threadIdx.x;
    if (i < n) p[i] = 0;
}

__global__ void k_count(const int* __restrict__ ei, int E, int* __restrict__ cnt) {
    int e = blockIdx.x * blockDim.x + threadIdx.x;
    if (e < E) atomicAdd(&cnt[ei[E + e]], 1);
}

__global__ void k_scan(const int* __restrict__ cnt, int* __restrict__ rowptr,
                       int* __restrict__ fill, float* __restrict__ dis) {
    __shared__ int sums[256];
    int t = threadIdx.x;
    int base = t * 32;
    int s = 0;
#pragma unroll
    for (int i = 0; i < 32; i++) s += cnt[base + i];
    sums[t] = s;
    __syncthreads();
    for (int off = 1; off < 256; off <<= 1) {
        int v = (t >= off) ? sums[t - off] : 0;
        __syncthreads();
        sums[t] += v;
        __syncthreads();
    }
    int run = (t == 0) ? 0 : sums[t - 1];
#pragma unroll
    for (int i = 0; i < 32; i++) {
        int idx = base + i;
        rowptr[idx] = run;
        fill[idx] = run;
        dis[idx] = rsqrtf((float)(cnt[idx] + 1));
        run += cnt[idx];
    }
    if (t == 255) rowptr[N_NODES] = run;
}

__global__ void k_scatter(const int* __restrict__ ei, int E,
                          int* __restrict__ fill, int* __restrict__ ssrc) {
    int e = blockIdx.x * blockDim.x + threadIdx.x;
    if (e < E) {
        int pos = atomicAdd(&fill[ei[E + e]], 1);
        ssrc[pos] = ei[e];
    }
}

// ---------------- GEMM: C[r,j] = sum_k A[r,k]*W[k*dout+j] (+bias) ----------------
// blockDim.x == dout. 8 rows/block, A-tile in LDS, float4 LDS reads.
__global__ void k_gemm(const float* __restrict__ A, const float* __restrict__ W,
                       const float* __restrict__ bias, float* __restrict__ C,
                       bf16* __restrict__ Cb, int K, int dout) {
    const int ROWS = 8;
    __shared__ float As[ROWS * 128];
    int j = threadIdx.x;
    int r0 = blockIdx.x * ROWS;
    for (int idx = j; idx < ROWS * K; idx += blockDim.x) As[idx] = A[(size_t)r0 * K + idx];
    __syncthreads();
    float acc[ROWS];
#pragma unroll
    for (int r = 0; r < ROWS; r++) acc[r] = 0.f;
    for (int k = 0; k < K; k += 4) {
        float w0 = W[(k + 0) * dout + j];
        float w1 = W[(k + 1) * dout + j];
        float w2 = W[(k + 2) * dout + j];
        float w3 = W[(k + 3) * dout + j];
#pragma unroll
        for (int r = 0; r < ROWS; r++) {
            const float4 a = *(const float4*)&As[r * K + k];
            acc[r] += a.x * w0 + a.y * w1 + a.z * w2 + a.w * w3;
        }
    }
    float b = bias ? bias[j] : 0.f;
#pragma unroll
    for (int r = 0; r < ROWS; r++) {
        float v = acc[r] + b;
        size_t o = (size_t)(r0 + r) * dout + j;
        if (Cb) Cb[o] = __float2bfloat16(v);
        else    C[o] = v;
    }
}

// ---------------- GCN aggregation ----------------
__global__ void k_aggregate(const float* __restrict__ h, const int* __restrict__ rowptr,
                            const int* __restrict__ ssrc, const float* __restrict__ dis,
                            const float* __restrict__ bias, const float* __restrict__ resid,
                            float* __restrict__ outF, void* __restrict__ outAny, int outOff,
                            const int* __restrict__ flagp, int dout, int relu) {
    int i = blockIdx.x;
    int f = threadIdx.x;
    float di = dis[i];
    float acc = h[(size_t)i * dout + f] * (di * di);
    int e0 = rowptr[i], e1 = rowptr[i + 1];
    for (int e = e0; e < e1; e++) {
        int s = ssrc[e];
        acc += h[(size_t)s * dout + f] * (dis[s] * di);
    }
    acc += bias[f];
    if (relu) acc = fmaxf(acc, 0.f);
    if (resid) acc += resid[(size_t)i * dout + f];
    size_t o = (size_t)i * dout + f;
    if (outF) outF[o] = acc;
    if (outAny) {
        if (*flagp) ((float*)outAny)[(size_t)outOff + o] = acc;
        else        ((bf16*)outAny)[(size_t)outOff + o] = __float2bfloat16(acc);
    }
}

// ---------------- flash attention ----------------
// qkv bf16 [8192,192]. grid: 256 blocks = c(2) x qb(32) x h(4), 256 thr.
// part[((c*4+h)*8192+n)*18 + {0..15:o,16:m,17:l}]
__global__ void k_flash_partial(const bf16* __restrict__ qkv, float* __restrict__ part) {
    const int CH = 128;
    int b = blockIdx.x;
    int c = b & 1;
    int qb = (b >> 1) & 31;
    int h = b >> 6;
    int t = threadIdx.x;
    int n = qb * 256 + t;
    __shared__ float ks[CH * 16];
    __shared__ float vs[CH * 16];
    float q[16];
#pragma unroll
    for (int j = 0; j < 16; j++) q[j] = b2f(qkv[(size_t)n * 192 + h * 16 + j]);
    float o[16];
#pragma unroll
    for (int j = 0; j < 16; j++) o[j] = 0.f;
    float mx = -1e30f, l = 0.f;
    int m0 = c * 4096;
    for (int mb = 0; mb < 4096; mb += CH) {
        __syncthreads();
        for (int idx = t; idx < CH * 16; idx += 256) {
            int m = m0 + mb + (idx >> 4);
            int j = idx & 15;
            ks[idx] = b2f(qkv[(size_t)m * 192 + 64 + h * 16 + j]);
            vs[idx] = b2f(qkv[(size_t)m * 192 + 128 + h * 16 + j]);
        }
        __syncthreads();
        for (int mm = 0; mm < CH; mm++) {
            const float* kr = &ks[mm * 16];
            float s = 0.f;
#pragma unroll
            for (int j = 0; j < 16; j++) s += q[j] * kr[j];
            s *= 0.25f;  // 1/sqrt(16)
            if (s > mx) {               // rare after warmup -> usually wave-uniform skip
                float alpha = __expf(mx - s);
                l *= alpha;
#pragma unroll
                for (int j = 0; j < 16; j++) o[j] *= alpha;
                mx = s;
            }
            float p = __expf(s - mx);
            l += p;
            const float* vr = &vs[mm * 16];
#pragma unroll
            for (int j = 0; j < 16; j++) o[j] += p * vr[j];
        }
    }
    float* P = &part[(size_t)(((c * 4 + h) * 8192) + n) * 18];
#pragma unroll
    for (int j = 0; j < 16; j++) P[j] = o[j];
    P[16] = mx;
    P[17] = l;
}

__global__ void k_flash_merge(const float* __restrict__ part, float* __restrict__ Bo) {
    int idx = blockIdx.x * blockDim.x + threadIdx.x;   // h*8192+n
    if (idx >= 4 * 8192) return;
    int h = idx >> 13;
    int n = idx & 8191;
    float M = fmaxf(part[(size_t)((0 * 4 + h) * 8192 + n) * 18 + 16],
                    part[(size_t)((1 * 4 + h) * 8192 + n) * 18 + 16]);
    float l = 0.f;
    float o[16];
#pragma unroll
    for (int j = 0; j < 16; j++) o[j] = 0.f;
#pragma unroll
    for (int c = 0; c < 2; c++) {
        const float* P = &part[(size_t)((c * 4 + h) * 8192 + n) * 18];
        float w = __expf(P[16] - M);
        l += P[17] * w;
#pragma unroll
        for (int j = 0; j < 16; j++) o[j] += P[j] * w;
    }
    float inv = 1.f / l;
#pragma unroll
    for (int j = 0; j < 16; j++) Bo[(size_t)n * 64 + h * 16 + j] = o[j] * inv;
}

// ---------------- launch ----------------
extern "C" void kernel_launch(void* const* d_in, const int* in_sizes, int n_in,
                              void* d_out, int out_size, void* d_ws, size_t ws_size,
                              hipStream_t stream) {
    int E = in_sizes[1] / 2;
    const int* ei = (const int*)d_in[1];

    int*   ib = (int*)d_ws;
    float* fb = (float*)d_ws;
    int* cnt    = ib;
    int* rowptr = ib + 8192;
    int* fill   = ib + 16448;
    int* ssrc   = ib + 24640;
    int* flagp  = ib + 286784;
    float* dis  = fb + OFF_DIS;
    float* W32  = fb + OFF_W;
    float* C    = fb + OFF_C;
    float* D    = fb + OFF_D;
    float* Ebuf = fb + OFF_E;
    float* F    = fb + OFF_F;
    bf16*  Qbf  = (bf16*)F;
    float* part = D;

    dim3 b256(256);
    int eb = (E + 255) / 256;

    k_sniff<<<dim3(1), b256, 0, stream>>>((const unsigned short*)d_in[0], flagp);
    k_zero_int<<<dim3(32), b256, 0, stream>>>(cnt, 8192);
    k_count<<<dim3(eb), b256, 0, stream>>>(ei, E, cnt);
    k_scan<<<dim3(1), b256, 0, stream>>>(cnt, rowptr, fill, dis);
    k_scatter<<<dim3(eb), b256, 0, stream>>>(ei, E, fill, ssrc);

    CvtTab tab;
    auto ent = [&](int idx, const void* src, int dst, int n, int cols, int tld) {
        tab.e[idx] = CvtEnt{src, dst, n, cols, tld};
    };
    ent(0,  d_in[0],  OFF_C, 8192 * 64, 0, 0);                 // x
    ent(1,  d_in[2],  OFF_W + W_E1, 64 * 128, 0, 0);
    ent(2,  d_in[3],  OFF_W + B_E1, 128, 0, 0);
    ent(3,  d_in[4],  OFF_W + W_E2, 128 * 128, 0, 0);
    ent(4,  d_in[5],  OFF_W + B_E2, 128, 0, 0);
    ent(5,  d_in[6],  OFF_W + W_E3, 128 * 128, 0, 0);
    ent(6,  d_in[7],  OFF_W + B_E3, 128, 0, 0);
    ent(7,  d_in[8],  OFF_W + W_E4, 128 * 64, 0, 0);
    ent(8,  d_in[9],  OFF_W + B_E4, 64, 0, 0);
    ent(9,  d_in[10], OFF_W + W_D1, 64 * 128, 0, 0);
    ent(10, d_in[11], OFF_W + B_D1, 128, 0, 0);
    ent(11, d_in[12], OFF_W + W_D2, 128 * 128, 0, 0);
    ent(12, d_in[13], OFF_W + B_D2, 128, 0, 0);
    ent(13, d_in[14], OFF_W + W_D3, 128 * 128, 0, 0);
    ent(14, d_in[15], OFF_W + B_D3, 128, 0, 0);
    ent(15, d_in[16], OFF_W + W_D4, 128 * 64, 0, 0);
    ent(16, d_in[17], OFF_W + B_D4, 64, 0, 0);
    ent(17, d_in[18], OFF_W + W_AIW, 192 * 64, 64, 192);       // [192,64] -> [64,192]
    ent(18, d_in[19], OFF_W + B_AI, 192, 0, 0);
    ent(19, d_in[20], OFF_W + W_AOW, 64 * 64, 64, 64);         // [64,64] -> [64,64]^T
    ent(20, d_in[21], OFF_W + B_AO, 64, 0, 0);
    k_convert<<<dim3(2501), b256, 0, stream>>>(tab, fb, flagp);

    auto gemm = [&](const float* A, int wOff, int bOff, float* Cf, bf16* Cb, int K, int dout) {
        k_gemm<<<dim3(1024), dim3(dout), 0, stream>>>(A, W32 + wOff,
                                                      bOff >= 0 ? W32 + bOff : nullptr,
                                                      Cf, Cb, K, dout);
    };
    auto agg = [&](const float* h, int bOff, const float* resid, float* oF,
                   void* oAny, int oOff, int dout, int relu) {
        k_aggregate<<<dim3(8192), dim3(dout), 0, stream>>>(h, rowptr, ssrc, dis,
                                                           W32 + bOff, resid, oF, oAny, oOff,
                                                           flagp, dout, relu);
    };

    // encoder
    gemm(C, W_E1, -1, D, nullptr, 64, 128);   agg(D, B_E1, nullptr, Ebuf, nullptr, 0, 128, 1);
    gemm(Ebuf, W_E2, -1, D, nullptr, 128, 128); agg(D, B_E2, Ebuf, F, nullptr, 0, 128, 1);
    gemm(F, W_E3, -1, D, nullptr, 128, 128);  agg(D, B_E3, F, Ebuf, nullptr, 0, 128, 1);
    gemm(Ebuf, W_E4, -1, D, nullptr, 128, 64); agg(D, B_E4, nullptr, C, d_out, 8192 * 64, 64, 0);

    // attention
    gemm(C, W_AIW, B_AI, nullptr, Qbf, 64, 192);
    k_flash_partial<<<dim3(256), b256, 0, stream>>>(Qbf, part);
    k_flash_merge<<<dim3(128), b256, 0, stream>>>(part, C);
    gemm(C, W_AOW, B_AO, Ebuf, nullptr, 64, 64);

    // decoder
    gemm(Ebuf, W_D1, -1, D, nullptr, 64, 128); agg(D, B_D1, nullptr, F, nullptr, 0, 128, 1);
    gemm(F, W_D2, -1, D, nullptr, 128, 128);  agg(D, B_D2, F, Ebuf, nullptr, 0, 128, 1);
    gemm(Ebuf, W_D3, -1, D, nullptr, 128, 128); agg(D, B_D3, Ebuf, F, nullptr, 0, 128, 1);
    gemm(F, W_D4, -1, D, nullptr, 128, 64);   agg(D, B_D4, nullptr, nullptr, d_out, 0, 64, 0);
}

// Round 3
// 636.013 us; speedup vs baseline: 1.9554x; 1.9554x over previous
//
#include <hip/hip_runtime.h>
#include <hip/hip_bf16.h>

using bf16 = __hip_bfloat16;

#define N_NODES 8192

static __device__ __forceinline__ float b2f(bf16 v) { return __bfloat162float(v); }

typedef __attribute__((ext_vector_type(8))) short bf16x8_t;   // 8 bf16 in 4 VGPRs
typedef __attribute__((ext_vector_type(4))) float f32x4_t;

// ---------------- workspace layout (float offsets from fb) ----------------
// ints (alias float region start):
//   cnt [0,8192)  rowptr [8192,16385)  fill [16448,24640)  ssrc [24640,286784)  flag ib[286784]
#define OFF_DIS 286848
#define OFF_W   295040
#define OFF_C   410880    /* 8192*64  : x32 -> z -> Bo (attention out) */
#define OFF_D   935168    /* 8192*128 : gemm out; flash partials D+E+F[0:262144) */
#define OFF_E   1983744   /* 8192*128 */
#define OFF_F   3032320   /* 8192*128 ; qkv bf16 at F+262144 */
#define OFF_QKV 3294464   /* bf16[8192*192] = 393216 float slots */
// total: 3687680 floats = 14.75 MB

#define W_E1 0
#define W_E2 8192
#define W_E3 24576
#define W_E4 40960
#define W_D1 49152
#define W_D2 57344
#define W_D3 73728
#define W_D4 90112
#define W_AIW 98304     /* transposed: [64,192] */
#define W_AOW 110592    /* transposed: [64,64]  */
#define B_E1 114688
#define B_E2 114816
#define B_E3 114944
#define B_E4 115072
#define B_D1 115136
#define B_D2 115264
#define B_D3 115392
#define B_D4 115520
#define B_AI 115584
#define B_AO 115776

// log2(e)/4 : folds both the 1/sqrt(DH) score scale and the exp->exp2 change
#define QSCALE 0.36067376022224085f

// ---------------- dtype sniff ----------------
__global__ void k_sniff(const unsigned short* __restrict__ xb, int* __restrict__ flagp) {
    __shared__ int cnt;
    if (threadIdx.x == 0) cnt = 0;
    __syncthreads();
    unsigned short w = xb[threadIdx.x * 2];
    int e = (w >> 7) & 0xFF;
    int m = w & 0x7F;
    int weird = (e >= 134) || (e != 0 && e <= 90) || (e == 0 && m != 0);
    if (weird) atomicAdd(&cnt, 1);
    __syncthreads();
    if (threadIdx.x == 0) *flagp = (cnt >= 32) ? 1 : 0;   // 1 => inputs are fp32
}

// ---------------- input canonicalization to fp32 ----------------
struct CvtEnt { const void* src; int dst; int n; int cols; int tld; };
struct CvtTab { CvtEnt e[21]; };

__global__ void k_convert(CvtTab tab, float* __restrict__ fb, const int* __restrict__ flagp) {
    int i = blockIdx.x * blockDim.x + threadIdx.x;
    int fl = *flagp;
#pragma unroll 1
    for (int t = 0; t < 21; t++) {
        int n = tab.e[t].n;
        if (i < n) {
            float v = fl ? ((const float*)tab.e[t].src)[i]
                         : b2f(((const bf16*)tab.e[t].src)[i]);
            int d;
            if (tab.e[t].tld) {
                int r = i / tab.e[t].cols, c = i - r * tab.e[t].cols;
                d = tab.e[t].dst + c * tab.e[t].tld + r;
            } else {
                d = tab.e[t].dst + i;
            }
            fb[d] = v;
            return;
        }
        i -= n;
    }
}

// ---------------- CSR construction ----------------
__global__ void k_zero_int(int* __restrict__ p, int n) {
    int i = blockIdx.x * blockDim.x + threadIdx.x;
    if (i < n) p[i] = 0;
}

__global__ void k_count(const int* __restrict__ ei, int E, int* __restrict__ cnt) {
    int e = blockIdx.x * blockDim.x + threadIdx.x;
    if (e < E) atomicAdd(&cnt[ei[E + e]], 1);
}

__global__ void k_scan(const int* __restrict__ cnt, int* __restrict__ rowptr,
                       int* __restrict__ fill, float* __restrict__ dis) {
    __shared__ int sums[256];
    int t = threadIdx.x;
    int base = t * 32;
    int s = 0;
#pragma unroll
    for (int i = 0; i < 32; i++) s += cnt[base + i];
    sums[t] = s;
    __syncthreads();
    for (int off = 1; off < 256; off <<= 1) {
        int v = (t >= off) ? sums[t - off] : 0;
        __syncthreads();
        sums[t] += v;
        __syncthreads();
    }
    int run = (t == 0) ? 0 : sums[t - 1];
#pragma unroll
    for (int i = 0; i < 32; i++) {
        int idx = base + i;
        rowptr[idx] = run;
        fill[idx] = run;
        dis[idx] = rsqrtf((float)(cnt[idx] + 1));
        run += cnt[idx];
    }
    if (t == 255) rowptr[N_NODES] = run;
}

__global__ void k_scatter(const int* __restrict__ ei, int E,
                          int* __restrict__ fill, int* __restrict__ ssrc) {
    int e = blockIdx.x * blockDim.x + threadIdx.x;
    if (e < E) {
        int pos = atomicAdd(&fill[ei[E + e]], 1);
        ssrc[pos] = ei[e];
    }
}

// ---------------- GEMM ----------------
// If Cb != null this is the qkv projection: q columns (j<64) get QSCALE folded in
// (fp32, before the single bf16 rounding -> no extra error).
__global__ void k_gemm(const float* __restrict__ A, const float* __restrict__ W,
                       const float* __restrict__ bias, float* __restrict__ C,
                       bf16* __restrict__ Cb, int K, int dout) {
    const int ROWS = 8;
    __shared__ float As[ROWS * 128];
    int j = threadIdx.x;
    int r0 = blockIdx.x * ROWS;
    for (int idx = j; idx < ROWS * K; idx += blockDim.x) As[idx] = A[(size_t)r0 * K + idx];
    __syncthreads();
    float acc[ROWS];
#pragma unroll
    for (int r = 0; r < ROWS; r++) acc[r] = 0.f;
    for (int k = 0; k < K; k += 4) {
        float w0 = W[(k + 0) * dout + j];
        float w1 = W[(k + 1) * dout + j];
        float w2 = W[(k + 2) * dout + j];
        float w3 = W[(k + 3) * dout + j];
#pragma unroll
        for (int r = 0; r < ROWS; r++) {
            const float4 a = *(const float4*)&As[r * K + k];
            acc[r] += a.x * w0 + a.y * w1 + a.z * w2 + a.w * w3;
        }
    }
    float b = bias ? bias[j] : 0.f;
#pragma unroll
    for (int r = 0; r < ROWS; r++) {
        float v = acc[r] + b;
        size_t o = (size_t)(r0 + r) * dout + j;
        if (Cb) {
            if (j < 64) v *= QSCALE;
            Cb[o] = __float2bfloat16(v);
        } else {
            C[o] = v;
        }
    }
}

// ---------------- GCN aggregation ----------------
__global__ void k_aggregate(const float* __restrict__ h, const int* __restrict__ rowptr,
                            const int* __restrict__ ssrc, const float* __restrict__ dis,
                            const float* __restrict__ bias, const float* __restrict__ resid,
                            float* __restrict__ outF, void* __restrict__ outAny, int outOff,
                            const int* __restrict__ flagp, int dout, int relu) {
    int i = blockIdx.x;
    int f = threadIdx.x;
    float di = dis[i];
    float acc = h[(size_t)i * dout + f] * (di * di);
    int e0 = rowptr[i], e1 = rowptr[i + 1];
    for (int e = e0; e < e1; e++) {
        int s = ssrc[e];
        acc += h[(size_t)s * dout + f] * (dis[s] * di);
    }
    acc += bias[f];
    if (relu) acc = fmaxf(acc, 0.f);
    if (resid) acc += resid[(size_t)i * dout + f];
    size_t o = (size_t)i * dout + f;
    if (outF) outF[o] = acc;
    if (outAny) {
        if (*flagp) ((float*)outAny)[(size_t)outOff + o] = acc;
        else        ((bf16*)outAny)[(size_t)outOff + o] = __float2bfloat16(acc);
    }
}

// ---------------- MFMA flash attention ----------------
// qkv bf16 [8192,192] rows [q|k|v], head h at +h*16; q pre-scaled by QSCALE.
// Wave-independent: wave = (c,h,qt): 32 q rows, sweeps m-chunk c (2048 m).
// S^T tile = K_tile x Q^T via mfma_16x16x32 (d=16, upper K half zeroed):
//   C layout: row = m' = 4*(lane>>4)+reg, col = q' = lane&15  -> per-lane fixed q.
// P^T goes through per-wave LDS [q'][m'] (pad to 40 shorts) and re-enters the
// PV mfma as the B operand; O^T accumulates in C layout (row=d', col=q').
// Partials: part[((c*4+h)*8192+q)*18 + {0..15:o(d), 16:m(log2 dom), 17:l}]

static __device__ __forceinline__ unsigned pack_bf16_rne(float a, float b) {
    unsigned ua = __float_as_uint(a); ua += 0x7FFFu + ((ua >> 16) & 1u);
    unsigned ub = __float_as_uint(b); ub += 0x7FFFu + ((ub >> 16) & 1u);
    return (ua >> 16) | (ub & 0xFFFF0000u);
}

__global__ void __launch_bounds__(256, 4)
k_flash_mfma(const bf16* __restrict__ qkv, float* __restrict__ part) {
    __shared__ unsigned short plds[4][2][16][40];   // [wave][qsub][q'][m' padded]
    int w = threadIdx.x >> 6;
    int lane = threadIdx.x & 63;
    int lo = lane & 15;
    int g = lane >> 4;
    int wid = blockIdx.x * 4 + w;
    int qt = wid & 255;
    int h = (wid >> 8) & 3;
    int c = wid >> 10;
    int q0 = qt * 32;
    int m0base = c * 2048;

    const f32x4_t Z = {0.f, 0.f, 0.f, 0.f};
    bf16x8_t zf;
#pragma unroll
    for (int i = 0; i < 8; i++) zf[i] = 0;

    // Q B-frags (B[k=d=8g+j][n=q'=lo]), loaded once; quads 2,3 are the d>=16 pad
    bf16x8_t qf[2];
#pragma unroll
    for (int s = 0; s < 2; s++) {
        if (g < 2) qf[s] = *(const bf16x8_t*)(qkv + (size_t)(q0 + s * 16 + lo) * 192 + h * 16 + g * 8);
        else       qf[s] = zf;
    }

    f32x4_t oacc[2] = {Z, Z};
    float mr[2] = {-1e30f, -1e30f};
    float lr[2] = {0.f, 0.f};

    const int koff = 64 + h * 16 + g * 8;
    const int voff = 128 + h * 16 + lo;

    for (int t = 0; t < 64; t++) {
        int m0 = m0base + t * 32;
        // K A-frags: A[m'=lo][d=8g+j]
        bf16x8_t kf0 = zf, kf1 = zf;
        if (g < 2) {
            kf0 = *(const bf16x8_t*)(qkv + (size_t)(m0 + lo) * 192 + koff);
            kf1 = *(const bf16x8_t*)(qkv + (size_t)(m0 + 16 + lo) * 192 + koff);
        }
        // V^T A-frag: A[d'=lo][m'=8g+j] = V[m0+8g+j][lo]
        union { unsigned u[4]; bf16x8_t v; } vt;
#pragma unroll
        for (int jj = 0; jj < 4; jj++) {
            unsigned a = *(const unsigned short*)(qkv + (size_t)(m0 + 8 * g + 2 * jj) * 192 + voff);
            unsigned b = *(const unsigned short*)(qkv + (size_t)(m0 + 8 * g + 2 * jj + 1) * 192 + voff);
            vt.u[jj] = a | (b << 16);
        }
#pragma unroll
        for (int s = 0; s < 2; s++) {
            f32x4_t s0 = __builtin_amdgcn_mfma_f32_16x16x32_bf16(kf0, qf[s], Z, 0, 0, 0);
            f32x4_t s1 = __builtin_amdgcn_mfma_f32_16x16x32_bf16(kf1, qf[s], Z, 0, 0, 0);
            float tmax = fmaxf(fmaxf(fmaxf(s0[0], s0[1]), fmaxf(s0[2], s0[3])),
                               fmaxf(fmaxf(s1[0], s1[1]), fmaxf(s1[2], s1[3])));
            tmax = fmaxf(tmax, __shfl_xor(tmax, 16));
            tmax = fmaxf(tmax, __shfl_xor(tmax, 32));
            float mnew = fmaxf(mr[s], tmax);
            float alpha = __builtin_amdgcn_exp2f(mr[s] - mnew);
            mr[s] = mnew;
            float p0 = __builtin_amdgcn_exp2f(s0[0] - mnew);
            float p1 = __builtin_amdgcn_exp2f(s0[1] - mnew);
            float p2 = __builtin_amdgcn_exp2f(s0[2] - mnew);
            float p3 = __builtin_amdgcn_exp2f(s0[3] - mnew);
            float p4 = __builtin_amdgcn_exp2f(s1[0] - mnew);
            float p5 = __builtin_amdgcn_exp2f(s1[1] - mnew);
            float p6 = __builtin_amdgcn_exp2f(s1[2] - mnew);
            float p7 = __builtin_amdgcn_exp2f(s1[3] - mnew);
            lr[s] = lr[s] * alpha + (((p0 + p1) + (p2 + p3)) + ((p4 + p5) + (p6 + p7)));
            // write P^T: row q'=lo, cols {4g..4g+3} and {16+4g..}
            unsigned* dst0 = (unsigned*)&plds[w][s][lo][4 * g];
            dst0[0] = pack_bf16_rne(p0, p1);
            dst0[1] = pack_bf16_rne(p2, p3);
            unsigned* dst1 = (unsigned*)&plds[w][s][lo][16 + 4 * g];
            dst1[0] = pack_bf16_rne(p4, p5);
            dst1[1] = pack_bf16_rne(p6, p7);
            f32x4_t oo;
#pragma unroll
            for (int r = 0; r < 4; r++) oo[r] = oacc[s][r] * alpha;
            // read B-frag: B[k=m'=8g+j][n=q'=lo]
            bf16x8_t pf = *(const bf16x8_t*)&plds[w][s][lo][8 * g];
            oacc[s] = __builtin_amdgcn_mfma_f32_16x16x32_bf16(vt.v, pf, oo, 0, 0, 0);
        }
    }
#pragma unroll
    for (int s = 0; s < 2; s++) {
        float l = lr[s];
        l += __shfl_xor(l, 16);
        l += __shfl_xor(l, 32);
        int q = q0 + s * 16 + lo;
        float* P = part + (size_t)((c * 4 + h) * 8192 + q) * 18;
#pragma unroll
        for (int r = 0; r < 4; r++) P[4 * g + r] = oacc[s][r];
        if (g == 0) { P[16] = mr[s]; P[17] = l; }
    }
}

__global__ void k_flash_merge(const float* __restrict__ part, float* __restrict__ Bo) {
    int idx = blockIdx.x * blockDim.x + threadIdx.x;   // h*8192+n
    if (idx >= 4 * 8192) return;
    int h = idx >> 13;
    int n = idx & 8191;
    float M = -1e30f;
#pragma unroll
    for (int c = 0; c < 4; c++)
        M = fmaxf(M, part[(size_t)((c * 4 + h) * 8192 + n) * 18 + 16]);
    float l = 0.f;
    float o[16];
#pragma unroll
    for (int j = 0; j < 16; j++) o[j] = 0.f;
#pragma unroll
    for (int c = 0; c < 4; c++) {
        const float* P = &part[(size_t)((c * 4 + h) * 8192 + n) * 18];
        float wgt = exp2f(P[16] - M);
        l += P[17] * wgt;
#pragma unroll
        for (int j = 0; j < 16; j++) o[j] += P[j] * wgt;
    }
    float inv = 1.f / l;
#pragma unroll
    for (int j = 0; j < 16; j++) Bo[(size_t)n * 64 + h * 16 + j] = o[j] * inv;
}

// ---------------- launch ----------------
extern "C" void kernel_launch(void* const* d_in, const int* in_sizes, int n_in,
                              void* d_out, int out_size, void* d_ws, size_t ws_size,
                              hipStream_t stream) {
    int E = in_sizes[1] / 2;
    const int* ei = (const int*)d_in[1];

    int*   ib = (int*)d_ws;
    float* fb = (float*)d_ws;
    int* cnt    = ib;
    int* rowptr = ib + 8192;
    int* fill   = ib + 16448;
    int* ssrc   = ib + 24640;
    int* flagp  = ib + 286784;
    float* dis  = fb + OFF_DIS;
    float* W32  = fb + OFF_W;
    float* C    = fb + OFF_C;
    float* D    = fb + OFF_D;
    float* Ebuf = fb + OFF_E;
    float* F    = fb + OFF_F;
    bf16*  Qbf  = (bf16*)(fb + OFF_QKV);
    float* part = D;     // spans D,E,F[0:262144) = 2359296 floats

    dim3 b256(256);
    int eb = (E + 255) / 256;

    k_sniff<<<dim3(1), b256, 0, stream>>>((const unsigned short*)d_in[0], flagp);
    k_zero_int<<<dim3(32), b256, 0, stream>>>(cnt, 8192);
    k_count<<<dim3(eb), b256, 0, stream>>>(ei, E, cnt);
    k_scan<<<dim3(1), b256, 0, stream>>>(cnt, rowptr, fill, dis);
    k_scatter<<<dim3(eb), b256, 0, stream>>>(ei, E, fill, ssrc);

    CvtTab tab;
    auto ent = [&](int idx, const void* src, int dst, int n, int cols, int tld) {
        tab.e[idx] = CvtEnt{src, dst, n, cols, tld};
    };
    ent(0,  d_in[0],  OFF_C, 8192 * 64, 0, 0);                 // x
    ent(1,  d_in[2],  OFF_W + W_E1, 64 * 128, 0, 0);
    ent(2,  d_in[3],  OFF_W + B_E1, 128, 0, 0);
    ent(3,  d_in[4],  OFF_W + W_E2, 128 * 128, 0, 0);
    ent(4,  d_in[5],  OFF_W + B_E2, 128, 0, 0);
    ent(5,  d_in[6],  OFF_W + W_E3, 128 * 128, 0, 0);
    ent(6,  d_in[7],  OFF_W + B_E3, 128, 0, 0);
    ent(7,  d_in[8],  OFF_W + W_E4, 128 * 64, 0, 0);
    ent(8,  d_in[9],  OFF_W + B_E4, 64, 0, 0);
    ent(9,  d_in[10], OFF_W + W_D1, 64 * 128, 0, 0);
    ent(10, d_in[11], OFF_W + B_D1, 128, 0, 0);
    ent(11, d_in[12], OFF_W + W_D2, 128 * 128, 0, 0);
    ent(12, d_in[13], OFF_W + B_D2, 128, 0, 0);
    ent(13, d_in[14], OFF_W + W_D3, 128 * 128, 0, 0);
    ent(14, d_in[15], OFF_W + B_D3, 128, 0, 0);
    ent(15, d_in[16], OFF_W + W_D4, 128 * 64, 0, 0);
    ent(16, d_in[17], OFF_W + B_D4, 64, 0, 0);
    ent(17, d_in[18], OFF_W + W_AIW, 192 * 64, 64, 192);       // [192,64] -> [64,192]
    ent(18, d_in[19], OFF_W + B_AI, 192, 0, 0);
    ent(19, d_in[20], OFF_W + W_AOW, 64 * 64, 64, 64);         // [64,64] -> transposed
    ent(20, d_in[21], OFF_W + B_AO, 64, 0, 0);
    k_convert<<<dim3(2501), b256, 0, stream>>>(tab, fb, flagp);

    auto gemm = [&](const float* A, int wOff, int bOff, float* Cf, bf16* Cb, int K, int dout) {
        k_gemm<<<dim3(1024), dim3(dout), 0, stream>>>(A, W32 + wOff,
                                                      bOff >= 0 ? W32 + bOff : nullptr,
                                                      Cf, Cb, K, dout);
    };
    auto agg = [&](const float* h, int bOff, const float* resid, float* oF,
                   void* oAny, int oOff, int dout, int relu) {
        k_aggregate<<<dim3(8192), dim3(dout), 0, stream>>>(h, rowptr, ssrc, dis,
                                                           W32 + bOff, resid, oF, oAny, oOff,
                                                           flagp, dout, relu);
    };

    // encoder
    gemm(C, W_E1, -1, D, nullptr, 64, 128);   agg(D, B_E1, nullptr, Ebuf, nullptr, 0, 128, 1);
    gemm(Ebuf, W_E2, -1, D, nullptr, 128, 128); agg(D, B_E2, Ebuf, F, nullptr, 0, 128, 1);
    gemm(F, W_E3, -1, D, nullptr, 128, 128);  agg(D, B_E3, F, Ebuf, nullptr, 0, 128, 1);
    gemm(Ebuf, W_E4, -1, D, nullptr, 128, 64); agg(D, B_E4, nullptr, C, d_out, 8192 * 64, 64, 0);

    // attention: qkv = z @ in_w.T + in_b (q cols pre-scaled); mfma flash; out proj
    gemm(C, W_AIW, B_AI, nullptr, Qbf, 64, 192);
    k_flash_mfma<<<dim3(1024), b256, 0, stream>>>(Qbf, part);
    k_flash_merge<<<dim3(128), b256, 0, stream>>>(part, C);
    gemm(C, W_AOW, B_AO, Ebuf, nullptr, 64, 64);

    // decoder
    gemm(Ebuf, W_D1, -1, D, nullptr, 64, 128); agg(D, B_D1, nullptr, F, nullptr, 0, 128, 1);
    gemm(F, W_D2, -1, D, nullptr, 128, 128);  agg(D, B_D2, F, Ebuf, nullptr, 0, 128, 1);
    gemm(Ebuf, W_D3, -1, D, nullptr, 128, 128); agg(D, B_D3, Ebuf, F, nullptr, 0, 128, 1);
    gemm(F, W_D4, -1, D, nullptr, 128, 64);   agg(D, B_D4, nullptr, nullptr, d_out, 0, 64, 0);
}

// Round 7
// 597.564 us; speedup vs baseline: 2.0812x; 1.0643x over previous
//
#include <hip/hip_runtime.h>
#include <hip/hip_bf16.h>

using bf16 = __hip_bfloat16;

typedef __attribute__((ext_vector_type(8))) short bf16x8_t;   // 8 bf16 in 4 VGPRs
typedef __attribute__((ext_vector_type(4))) float f32x4_t;

static __device__ __forceinline__ float b2f(bf16 v) { return __bfloat162float(v); }

// pack two fp32 -> 2 bf16 (RNE)
static __device__ __forceinline__ unsigned pk(float a, float b) {
    unsigned ua = __float_as_uint(a); ua += 0x7FFFu + ((ua >> 16) & 1u);
    unsigned ub = __float_as_uint(b); ub += 0x7FFFu + ((ub >> 16) & 1u);
    return (ua >> 16) | (ub & 0xFFFF0000u);
}
static __device__ __forceinline__ float lo16f(unsigned u) { return __uint_as_float(u << 16); }
static __device__ __forceinline__ float hi16f(unsigned u) { return __uint_as_float(u & 0xFFFF0000u); }

// log2(e)/4 : folds 1/sqrt(DH) and exp->exp2. Applied at qkv GEMM OUTPUT (fp32,
// before the single bf16 rounding) exactly as the R3-proven kernel did.
#define QSCALE 0.36067376022224085f

// ---------------- workspace layout (float offsets) ----------------
// ints: cnt[0,8192) rowptr[8192,16385) fill[16448,24640) ssrc[24640,286784) flag ib[286784]
#define OFF_DIS  286848
#define OFF_BIAS 295040   /* 1152 fp32 */
#define OFF_WB   296192   /* bf16 weights (split hi+lo), 229376 shorts = 114688 floats */
#define OFF_X    410880   /* fp32 x [8192,64] */
#define OFF_HD   935168   /* fp32 gemm out [8192,128]; flash part (2359296) aliases HD.. */
#define OFF_HA   1983744  /* fp32 act [8192,128] */
#define OFF_HB   3032320  /* fp32 act [8192,128] */
#define OFF_HZ   4080896  /* fp32 z [8192,64] */
#define OFF_BO   4605184  /* fp32 attention out [8192,64] */
#define OFF_ZA   5129472  /* fp32 za [8192,64] */
#define OFF_QKV  5653760  /* bf16 qkv [8192,192] = 786432 float slots */
// total 6440192 floats = 25.76 MB (R0 demonstrated >=26.3 MB available)

// weight short-offsets (relative to OFF_WB as bf16*), each region hi plane then lo plane
#define HS_E1 0
#define HS_E2 16384
#define HS_E3 49152
#define HS_E4 81920
#define HS_D1 98304
#define HS_D2 114688
#define HS_D3 147456
#define HS_D4 180224
#define HS_AI 196608
#define HS_AO 221184

// bias fp32 offsets (relative to OFF_BIAS)
#define BF_E1 0
#define BF_E2 128
#define BF_E3 256
#define BF_E4 384
#define BF_D1 448
#define BF_D2 576
#define BF_D3 704
#define BF_D4 832
#define BF_AI 896
#define BF_AO 1088

// ---------------- dtype sniff (1 => inputs are fp32) ----------------
__global__ void k_sniff(const unsigned short* __restrict__ xb, int* __restrict__ flagp) {
    __shared__ int cnt;
    if (threadIdx.x == 0) cnt = 0;
    __syncthreads();
    unsigned short w = xb[threadIdx.x * 2];
    int e = (w >> 7) & 0xFF;
    int m = w & 0x7F;
    int weird = (e >= 134) || (e != 0 && e <= 90) || (e == 0 && m != 0);
    if (weird) atomicAdd(&cnt, 1);
    __syncthreads();
    if (threadIdx.x == 0) *flagp = (cnt >= 32) ? 1 : 0;
}

// ---------------- input canonicalization ----------------
// mode 0: fp32 -> fb[dst+i]
// mode 2: split weight swizzle from [K,dout=p0]: idx=((k>>3)*dout+n)*8+(k&7); lo at dst+n+idx
// mode 3: split weight transpose+swizzle from [rows,64]: k=i&63, n=i>>6, dout=p1; lo at dst+n+idx
struct CvtEnt { const void* src; int n; int dst; int mode; int p0; int p1; };
struct CvtTab { CvtEnt e[21]; };

__global__ void k_convert(CvtTab tab, float* __restrict__ fb, bf16* __restrict__ hb,
                          const int* __restrict__ flagp) {
    int i = blockIdx.x * blockDim.x + threadIdx.x;
    int fl = *flagp;
#pragma unroll 1
    for (int t = 0; t < 21; t++) {
        int n = tab.e[t].n;
        if (i < n) {
            float v = fl ? ((const float*)tab.e[t].src)[i]
                         : b2f(((const bf16*)tab.e[t].src)[i]);
            int mode = tab.e[t].mode, dst = tab.e[t].dst;
            if (mode == 0) {
                fb[dst + i] = v;
            } else {
                int idx;
                if (mode == 2) {
                    int dout = tab.e[t].p0;
                    int r = i / dout, c = i - r * dout;
                    idx = ((r >> 3) * dout + c) * 8 + (r & 7);
                } else {
                    int r = i >> 6, c = i & 63;       // r = n_eff, c = k_eff
                    idx = ((c >> 3) * tab.e[t].p1 + r) * 8 + (c & 7);
                }
                bf16 hv = __float2bfloat16(v);
                hb[dst + idx] = hv;
                hb[dst + n + idx] = __float2bfloat16(v - b2f(hv));
            }
            return;
        }
        i -= n;
    }
}

// ---------------- CSR construction ----------------
__global__ void k_zero_int(int* __restrict__ p, int n) {
    int i = blockIdx.x * blockDim.x + threadIdx.x;
    if (i < n) p[i] = 0;
}

__global__ void k_count(const int* __restrict__ ei, int E, int* __restrict__ cnt) {
    int e = blockIdx.x * blockDim.x + threadIdx.x;
    if (e < E) atomicAdd(&cnt[ei[E + e]], 1);
}

__global__ void k_scan(const int* __restrict__ cnt, int* __restrict__ rowptr,
                       int* __restrict__ fill, float* __restrict__ dis) {
    __shared__ int sums[256];
    int t = threadIdx.x;
    int base = t * 32;
    int s = 0;
#pragma unroll
    for (int i = 0; i < 32; i++) s += cnt[base + i];
    sums[t] = s;
    __syncthreads();
    for (int off = 1; off < 256; off <<= 1) {
        int v = (t >= off) ? sums[t - off] : 0;
        __syncthreads();
        sums[t] += v;
        __syncthreads();
    }
    int run = (t == 0) ? 0 : sums[t - 1];
#pragma unroll
    for (int i = 0; i < 32; i++) {
        int idx = base + i;
        rowptr[idx] = run;
        fill[idx] = run;
        dis[idx] = rsqrtf((float)(cnt[idx] + 1));
        run += cnt[idx];
    }
    if (t == 255) rowptr[8192] = run;
}

__global__ void k_scatter(const int* __restrict__ ei, int E,
                          int* __restrict__ fill, int* __restrict__ ssrc) {
    int e = blockIdx.x * blockDim.x + threadIdx.x;
    if (e < E) {
        int pos = atomicAdd(&fill[ei[E + e]], 1);
        ssrc[pos] = ei[e];
    }
}

// ---------------- MFMA GEMM: fp32 A (in-register hi/lo split) x split-bf16 W ----------------
// 3 MFMAs/tile: ah*wh + al*wh + ah*wl  (al*wl ~ 2^-18, dropped).
// OMODE: 0 -> fp32 outF; 1 -> bf16 outH; 2 -> bf16 outH with QSCALE on cols n<64 (qkv)
template<int K, int DOUT, int OMODE>
__global__ void __launch_bounds__(256) k_mgemm(const float* __restrict__ A,
                                               const bf16* __restrict__ Wb,
                                               const float* __restrict__ bias,
                                               float* __restrict__ outF,
                                               bf16* __restrict__ outH) {
    constexpr int NCT = DOUT / 16, NKS = K / 32;
    constexpr int WPL = K * DOUT;
    int w = threadIdx.x >> 6, lane = threadIdx.x & 63;
    int lo = lane & 15, g = lane >> 4;
    int r0 = (blockIdx.x * 4 + w) * 16;
    const f32x4_t Z = {0.f, 0.f, 0.f, 0.f};
    f32x4_t acc[NCT];
#pragma unroll
    for (int ct = 0; ct < NCT; ct++) acc[ct] = Z;
#pragma unroll
    for (int kk = 0; kk < NKS; kk++) {
        const float* ap = A + (size_t)(r0 + lo) * K + kk * 32 + g * 8;
        float4 x0 = *(const float4*)ap;
        float4 x1 = *(const float4*)(ap + 4);
        union { unsigned u[4]; bf16x8_t v; } ah, al;
        ah.u[0] = pk(x0.x, x0.y);
        ah.u[1] = pk(x0.z, x0.w);
        ah.u[2] = pk(x1.x, x1.y);
        ah.u[3] = pk(x1.z, x1.w);
        al.u[0] = pk(x0.x - lo16f(ah.u[0]), x0.y - hi16f(ah.u[0]));
        al.u[1] = pk(x0.z - lo16f(ah.u[1]), x0.w - hi16f(ah.u[1]));
        al.u[2] = pk(x1.x - lo16f(ah.u[2]), x1.y - hi16f(ah.u[2]));
        al.u[3] = pk(x1.z - lo16f(ah.u[3]), x1.w - hi16f(ah.u[3]));
#pragma unroll
        for (int ct = 0; ct < NCT; ct++) {
            size_t wi = (size_t)((kk * 4 + g) * DOUT + ct * 16 + lo) * 8;
            bf16x8_t wh = *(const bf16x8_t*)(Wb + wi);
            bf16x8_t wl = *(const bf16x8_t*)(Wb + WPL + wi);
            acc[ct] = __builtin_amdgcn_mfma_f32_16x16x32_bf16(ah.v, wh, acc[ct], 0, 0, 0);
            acc[ct] = __builtin_amdgcn_mfma_f32_16x16x32_bf16(al.v, wh, acc[ct], 0, 0, 0);
            acc[ct] = __builtin_amdgcn_mfma_f32_16x16x32_bf16(ah.v, wl, acc[ct], 0, 0, 0);
        }
    }
#pragma unroll
    for (int ct = 0; ct < NCT; ct++) {
        int n = ct * 16 + lo;
        float bs = bias ? bias[n] : 0.f;
#pragma unroll
        for (int r = 0; r < 4; r++) {
            float v = acc[ct][r] + bs;
            size_t o = (size_t)(r0 + 4 * g + r) * DOUT + n;
            if (OMODE == 0) {
                outF[o] = v;
            } else {
                if (OMODE == 2 && n < 64) v *= QSCALE;
                outH[o] = __float2bfloat16(v);
            }
        }
    }
}

// ---------------- GCN aggregation (all fp32, R3 numerics / R4 thread shape) ----------------
// 64 threads, 2 feats/thread; dout=128: 1 node/block; dout=64: 2 nodes/block.
__global__ void k_agg(const float* __restrict__ hd, const int* __restrict__ rowptr,
                      const int* __restrict__ ssrc, const float* __restrict__ dis,
                      const float* __restrict__ bias, const float* __restrict__ resid,
                      float* __restrict__ outF, void* __restrict__ outAny, int outOff,
                      const int* __restrict__ flagp, int dout, int relu) {
    int t = threadIdx.x;
    int local = 2 * t;
    int node = blockIdx.x * (128 / dout) + local / dout;
    int f = local & (dout - 1);
    float di = dis[node];
    float dii = di * di;
    float2 self = *(const float2*)(hd + (size_t)node * dout + f);
    float a0 = self.x * dii, a1 = self.y * dii;
    int e0 = rowptr[node], e1 = rowptr[node + 1];
    for (int e = e0; e < e1; e++) {
        int s = ssrc[e];
        float wgt = dis[s] * di;
        float2 v = *(const float2*)(hd + (size_t)s * dout + f);
        a0 += v.x * wgt;
        a1 += v.y * wgt;
    }
    a0 += bias[f];
    a1 += bias[f + 1];
    if (relu) { a0 = fmaxf(a0, 0.f); a1 = fmaxf(a1, 0.f); }
    if (resid) {
        float2 rv = *(const float2*)(resid + (size_t)node * dout + f);
        a0 += rv.x;
        a1 += rv.y;
    }
    size_t o = (size_t)node * dout + f;
    if (outF) *(float2*)(outF + o) = make_float2(a0, a1);
    if (outAny) {
        if (*flagp) {
            float* po = (float*)outAny + outOff;
            po[o] = a0; po[o + 1] = a1;
        } else {
            *(unsigned*)((bf16*)outAny + outOff + o) = pk(a0, a1);
        }
    }
}

// ---------------- MFMA flash attention — R3-PROVEN KERNEL, VERBATIM ----------------
// qkv bf16 [8192,192] rows [q|k|v], head h at +h*16; q pre-scaled by QSCALE.
// wave = (c,h,qt): 32 q rows, sweeps m-chunk c (2048 m). 1024 blocks.
// part[((c*4+h)*8192+q)*18 + {0..15:o(d), 16:m(log2 dom), 17:l}]
__global__ void __launch_bounds__(256, 4)
k_flash_mfma(const bf16* __restrict__ qkv, float* __restrict__ part) {
    __shared__ unsigned short plds[4][2][16][40];   // [wave][qsub][q'][m' padded]
    int w = threadIdx.x >> 6;
    int lane = threadIdx.x & 63;
    int lo = lane & 15;
    int g = lane >> 4;
    int wid = blockIdx.x * 4 + w;
    int qt = wid & 255;
    int h = (wid >> 8) & 3;
    int c = wid >> 10;
    int q0 = qt * 32;
    int m0base = c * 2048;

    const f32x4_t Z = {0.f, 0.f, 0.f, 0.f};
    bf16x8_t zf;
#pragma unroll
    for (int i = 0; i < 8; i++) zf[i] = 0;

    bf16x8_t qf[2];
#pragma unroll
    for (int s = 0; s < 2; s++) {
        if (g < 2) qf[s] = *(const bf16x8_t*)(qkv + (size_t)(q0 + s * 16 + lo) * 192 + h * 16 + g * 8);
        else       qf[s] = zf;
    }

    f32x4_t oacc[2] = {Z, Z};
    float mr[2] = {-1e30f, -1e30f};
    float lr[2] = {0.f, 0.f};

    const int koff = 64 + h * 16 + g * 8;
    const int voff = 128 + h * 16 + lo;

    for (int t = 0; t < 64; t++) {
        int m0 = m0base + t * 32;
        bf16x8_t kf0 = zf, kf1 = zf;
        if (g < 2) {
            kf0 = *(const bf16x8_t*)(qkv + (size_t)(m0 + lo) * 192 + koff);
            kf1 = *(const bf16x8_t*)(qkv + (size_t)(m0 + 16 + lo) * 192 + koff);
        }
        union { unsigned u[4]; bf16x8_t v; } vt;
#pragma unroll
        for (int jj = 0; jj < 4; jj++) {
            unsigned a = *(const unsigned short*)(qkv + (size_t)(m0 + 8 * g + 2 * jj) * 192 + voff);
            unsigned b = *(const unsigned short*)(qkv + (size_t)(m0 + 8 * g + 2 * jj + 1) * 192 + voff);
            vt.u[jj] = a | (b << 16);
        }
#pragma unroll
        for (int s = 0; s < 2; s++) {
            f32x4_t s0 = __builtin_amdgcn_mfma_f32_16x16x32_bf16(kf0, qf[s], Z, 0, 0, 0);
            f32x4_t s1 = __builtin_amdgcn_mfma_f32_16x16x32_bf16(kf1, qf[s], Z, 0, 0, 0);
            float tmax = fmaxf(fmaxf(fmaxf(s0[0], s0[1]), fmaxf(s0[2], s0[3])),
                               fmaxf(fmaxf(s1[0], s1[1]), fmaxf(s1[2], s1[3])));
            tmax = fmaxf(tmax, __shfl_xor(tmax, 16));
            tmax = fmaxf(tmax, __shfl_xor(tmax, 32));
            float mnew = fmaxf(mr[s], tmax);
            float alpha = __builtin_amdgcn_exp2f(mr[s] - mnew);
            mr[s] = mnew;
            float p0 = __builtin_amdgcn_exp2f(s0[0] - mnew);
            float p1 = __builtin_amdgcn_exp2f(s0[1] - mnew);
            float p2 = __builtin_amdgcn_exp2f(s0[2] - mnew);
            float p3 = __builtin_amdgcn_exp2f(s0[3] - mnew);
            float p4 = __builtin_amdgcn_exp2f(s1[0] - mnew);
            float p5 = __builtin_amdgcn_exp2f(s1[1] - mnew);
            float p6 = __builtin_amdgcn_exp2f(s1[2] - mnew);
            float p7 = __builtin_amdgcn_exp2f(s1[3] - mnew);
            lr[s] = lr[s] * alpha + (((p0 + p1) + (p2 + p3)) + ((p4 + p5) + (p6 + p7)));
            unsigned* dst0 = (unsigned*)&plds[w][s][lo][4 * g];
            dst0[0] = pk(p0, p1);
            dst0[1] = pk(p2, p3);
            unsigned* dst1 = (unsigned*)&plds[w][s][lo][16 + 4 * g];
            dst1[0] = pk(p4, p5);
            dst1[1] = pk(p6, p7);
            f32x4_t oo;
#pragma unroll
            for (int r = 0; r < 4; r++) oo[r] = oacc[s][r] * alpha;
            bf16x8_t pf = *(const bf16x8_t*)&plds[w][s][lo][8 * g];
            oacc[s] = __builtin_amdgcn_mfma_f32_16x16x32_bf16(vt.v, pf, oo, 0, 0, 0);
        }
    }
#pragma unroll
    for (int s = 0; s < 2; s++) {
        float l = lr[s];
        l += __shfl_xor(l, 16);
        l += __shfl_xor(l, 32);
        int q = q0 + s * 16 + lo;
        float* P = part + (size_t)((c * 4 + h) * 8192 + q) * 18;
#pragma unroll
        for (int r = 0; r < 4; r++) P[4 * g + r] = oacc[s][r];
        if (g == 0) { P[16] = mr[s]; P[17] = l; }
    }
}

__global__ void k_flash_merge(const float* __restrict__ part, float* __restrict__ Bo) {
    int idx = blockIdx.x * blockDim.x + threadIdx.x;   // h*8192+n
    if (idx >= 4 * 8192) return;
    int h = idx >> 13;
    int n = idx & 8191;
    float M = -1e30f;
#pragma unroll
    for (int c = 0; c < 4; c++)
        M = fmaxf(M, part[(size_t)((c * 4 + h) * 8192 + n) * 18 + 16]);
    float l = 0.f;
    float o[16];
#pragma unroll
    for (int j = 0; j < 16; j++) o[j] = 0.f;
#pragma unroll
    for (int c = 0; c < 4; c++) {
        const float* P = &part[(size_t)((c * 4 + h) * 8192 + n) * 18];
        float wgt = exp2f(P[16] - M);
        l += P[17] * wgt;
#pragma unroll
        for (int j = 0; j < 16; j++) o[j] += P[j] * wgt;
    }
    float inv = 1.f / l;
#pragma unroll
    for (int j = 0; j < 16; j++) Bo[(size_t)n * 64 + h * 16 + j] = o[j] * inv;
}

// ---------------- launch ----------------
extern "C" void kernel_launch(void* const* d_in, const int* in_sizes, int n_in,
                              void* d_out, int out_size, void* d_ws, size_t ws_size,
                              hipStream_t stream) {
    int E = in_sizes[1] / 2;
    const int* ei = (const int*)d_in[1];

    int*   ib = (int*)d_ws;
    float* fb = (float*)d_ws;
    int* cnt    = ib;
    int* rowptr = ib + 8192;
    int* fill   = ib + 16448;
    int* ssrc   = ib + 24640;
    int* flagp  = ib + 286784;
    float* dis  = fb + OFF_DIS;
    float* Bias = fb + OFF_BIAS;
    bf16*  Wb   = (bf16*)(fb + OFF_WB);
    float* Hx   = fb + OFF_X;
    float* HD   = fb + OFF_HD;
    float* HA   = fb + OFF_HA;
    float* HB   = fb + OFF_HB;
    float* Hz   = fb + OFF_HZ;
    float* Bo   = fb + OFF_BO;
    float* ZA   = fb + OFF_ZA;
    bf16*  Qkv  = (bf16*)(fb + OFF_QKV);
    float* part = HD;    // 2359296 floats spanning HD..HA..into HB (all dead during attention)

    dim3 b256(256);
    int eb = (E + 255) / 256;

    k_sniff<<<dim3(1), b256, 0, stream>>>((const unsigned short*)d_in[0], flagp);
    k_zero_int<<<dim3(32), b256, 0, stream>>>(cnt, 8192);
    k_count<<<dim3(eb), b256, 0, stream>>>(ei, E, cnt);
    k_scan<<<dim3(1), b256, 0, stream>>>(cnt, rowptr, fill, dis);
    k_scatter<<<dim3(eb), b256, 0, stream>>>(ei, E, fill, ssrc);

    CvtTab tab;
    auto ent = [&](int i, const void* s, int n, int dst, int mode, int p0, int p1) {
        tab.e[i] = CvtEnt{s, n, dst, mode, p0, p1};
    };
    ent(0,  d_in[0],  524288, OFF_X, 0, 0, 0);
    ent(1,  d_in[2],  8192,  HS_E1, 2, 128, 0);
    ent(2,  d_in[3],  128,   OFF_BIAS + BF_E1, 0, 0, 0);
    ent(3,  d_in[4],  16384, HS_E2, 2, 128, 0);
    ent(4,  d_in[5],  128,   OFF_BIAS + BF_E2, 0, 0, 0);
    ent(5,  d_in[6],  16384, HS_E3, 2, 128, 0);
    ent(6,  d_in[7],  128,   OFF_BIAS + BF_E3, 0, 0, 0);
    ent(7,  d_in[8],  8192,  HS_E4, 2, 64, 0);
    ent(8,  d_in[9],  64,    OFF_BIAS + BF_E4, 0, 0, 0);
    ent(9,  d_in[10], 8192,  HS_D1, 2, 128, 0);
    ent(10, d_in[11], 128,   OFF_BIAS + BF_D1, 0, 0, 0);
    ent(11, d_in[12], 16384, HS_D2, 2, 128, 0);
    ent(12, d_in[13], 128,   OFF_BIAS + BF_D2, 0, 0, 0);
    ent(13, d_in[14], 16384, HS_D3, 2, 128, 0);
    ent(14, d_in[15], 128,   OFF_BIAS + BF_D3, 0, 0, 0);
    ent(15, d_in[16], 8192,  HS_D4, 2, 64, 0);
    ent(16, d_in[17], 64,    OFF_BIAS + BF_D4, 0, 0, 0);
    ent(17, d_in[18], 12288, HS_AI, 3, 0, 192);
    ent(18, d_in[19], 192,   OFF_BIAS + BF_AI, 0, 0, 0);
    ent(19, d_in[20], 4096,  HS_AO, 3, 0, 64);
    ent(20, d_in[21], 64,    OFF_BIAS + BF_AO, 0, 0, 0);
    k_convert<<<dim3(2501), b256, 0, stream>>>(tab, fb, Wb, flagp);

    dim3 g128(128), g4096(4096), g8192(8192), b64(64);

    // encoder: x -> h1(HA) -> h2(HB) -> h3(HA) -> z(Hz + d_out)
    k_mgemm<64, 128, 0><<<g128, b256, 0, stream>>>(Hx, Wb + HS_E1, nullptr, HD, nullptr);
    k_agg<<<g8192, b64, 0, stream>>>(HD, rowptr, ssrc, dis, Bias + BF_E1, nullptr,
                                     HA, nullptr, 0, flagp, 128, 1);
    k_mgemm<128, 128, 0><<<g128, b256, 0, stream>>>(HA, Wb + HS_E2, nullptr, HD, nullptr);
    k_agg<<<g8192, b64, 0, stream>>>(HD, rowptr, ssrc, dis, Bias + BF_E2, HA,
                                     HB, nullptr, 0, flagp, 128, 1);
    k_mgemm<128, 128, 0><<<g128, b256, 0, stream>>>(HB, Wb + HS_E3, nullptr, HD, nullptr);
    k_agg<<<g8192, b64, 0, stream>>>(HD, rowptr, ssrc, dis, Bias + BF_E3, HB,
                                     HA, nullptr, 0, flagp, 128, 1);
    k_mgemm<128, 64, 0><<<g128, b256, 0, stream>>>(HA, Wb + HS_E4, nullptr, HD, nullptr);
    k_agg<<<g4096, b64, 0, stream>>>(HD, rowptr, ssrc, dis, Bias + BF_E4, nullptr,
                                     Hz, d_out, 524288, flagp, 64, 0);

    // attention: qkv (q cols scaled in fp32 at output, R3 semantics); flash v1; merge; out-proj
    k_mgemm<64, 192, 2><<<g128, b256, 0, stream>>>(Hz, Wb + HS_AI, Bias + BF_AI, nullptr, Qkv);
    k_flash_mfma<<<dim3(1024), b256, 0, stream>>>(Qkv, part);
    k_flash_merge<<<g128, b256, 0, stream>>>(part, Bo);
    k_mgemm<64, 64, 0><<<g128, b256, 0, stream>>>(Bo, Wb + HS_AO, Bias + BF_AO, ZA, nullptr);

    // decoder: za -> g1(HA) -> g2(HB) -> g3(HA) -> x_recon(d_out)
    k_mgemm<64, 128, 0><<<g128, b256, 0, stream>>>(ZA, Wb + HS_D1, nullptr, HD, nullptr);
    k_agg<<<g8192, b64, 0, stream>>>(HD, rowptr, ssrc, dis, Bias + BF_D1, nullptr,
                                     HA, nullptr, 0, flagp, 128, 1);
    k_mgemm<128, 128, 0><<<g128, b256, 0, stream>>>(HA, Wb + HS_D2, nullptr, HD, nullptr);
    k_agg<<<g8192, b64, 0, stream>>>(HD, rowptr, ssrc, dis, Bias + BF_D2, HA,
                                     HB, nullptr, 0, flagp, 128, 1);
    k_mgemm<128, 128, 0><<<g128, b256, 0, stream>>>(HB, Wb + HS_D3, nullptr, HD, nullptr);
    k_agg<<<g8192, b64, 0, stream>>>(HD, rowptr, ssrc, dis, Bias + BF_D3, HB,
                                     HA, nullptr, 0, flagp, 128, 1);
    k_mgemm<128, 64, 0><<<g128, b256, 0, stream>>>(HA, Wb + HS_D4, nullptr, HD, nullptr);
    k_agg<<<g4096, b64, 0, stream>>>(HD, rowptr, ssrc, dis, Bias + BF_D4, nullptr,
                                     nullptr, d_out, 0, flagp, 64, 0);
}

// Round 8
// 522.148 us; speedup vs baseline: 2.3818x; 1.1444x over previous
//
#include <hip/hip_runtime.h>
#include <hip/hip_bf16.h>

using bf16 = __hip_bfloat16;

typedef __attribute__((ext_vector_type(8))) short bf16x8_t;   // 8 bf16 in 4 VGPRs
typedef __attribute__((ext_vector_type(4))) float f32x4_t;

static __device__ __forceinline__ float b2f(bf16 v) { return __bfloat162float(v); }

// pack two fp32 -> 2 bf16 (RNE)
static __device__ __forceinline__ unsigned pk(float a, float b) {
    unsigned ua = __float_as_uint(a); ua += 0x7FFFu + ((ua >> 16) & 1u);
    unsigned ub = __float_as_uint(b); ub += 0x7FFFu + ((ub >> 16) & 1u);
    return (ua >> 16) | (ub & 0xFFFF0000u);
}
static __device__ __forceinline__ float lo16f(unsigned u) { return __uint_as_float(u << 16); }
static __device__ __forceinline__ float hi16f(unsigned u) { return __uint_as_float(u & 0xFFFF0000u); }

// log2(e)/4 : folds 1/sqrt(DH) and exp->exp2. Applied at qkv GEMM output (fp32).
#define QSCALE 0.36067376022224085f

// ---------------- workspace layout (float offsets) ----------------
// ints: cnt[0,8192) rowptr[8192,16385) fill[16448,24640) ssrc[24640,286784) flag ib[286784]
#define OFF_DIS  286848
#define OFF_BIAS 295040   /* 1152 fp32 */
#define OFF_WB   296192   /* bf16 weights (split hi+lo), 229376 shorts = 114688 floats */
#define OFF_X    410880   /* fp32 x [8192,64] */
#define OFF_HD   935168   /* fp32 gemm out [8192,128]; flash acc (557056 f) aliases */
#define OFF_HA   1983744  /* fp32 act [8192,128] */
#define OFF_HB   3032320  /* fp32 act [8192,128] */
#define OFF_HZ   4080896  /* fp32 z [8192,64] */
#define OFF_BO   4605184  /* fp32 attention out [8192,64] */
#define OFF_ZA   5129472  /* fp32 za [8192,64] */
#define OFF_QKV  5653760  /* bf16 qkv [8192,192] = 786432 float slots */
// total 6440192 floats = 25.76 MB

// weight short-offsets (relative to OFF_WB as bf16*), each region hi plane then lo plane
#define HS_E1 0
#define HS_E2 16384
#define HS_E3 49152
#define HS_E4 81920
#define HS_D1 98304
#define HS_D2 114688
#define HS_D3 147456
#define HS_D4 180224
#define HS_AI 196608
#define HS_AO 221184

// bias fp32 offsets (relative to OFF_BIAS)
#define BF_E1 0
#define BF_E2 128
#define BF_E3 256
#define BF_E4 384
#define BF_D1 448
#define BF_D2 576
#define BF_D3 704
#define BF_D4 832
#define BF_AI 896
#define BF_AO 1088

// ---------------- dtype sniff (1 => inputs are fp32) ----------------
__global__ void k_sniff(const unsigned short* __restrict__ xb, int* __restrict__ flagp) {
    __shared__ int cnt;
    if (threadIdx.x == 0) cnt = 0;
    __syncthreads();
    unsigned short w = xb[threadIdx.x * 2];
    int e = (w >> 7) & 0xFF;
    int m = w & 0x7F;
    int weird = (e >= 134) || (e != 0 && e <= 90) || (e == 0 && m != 0);
    if (weird) atomicAdd(&cnt, 1);
    __syncthreads();
    if (threadIdx.x == 0) *flagp = (cnt >= 32) ? 1 : 0;
}

// ---------------- input canonicalization ----------------
// mode 0: fp32 -> fb[dst+i]
// mode 2: split weight swizzle from [K,dout=p0]: idx=((k>>3)*dout+n)*8+(k&7); lo at dst+n+idx
// mode 3: split weight transpose+swizzle from [rows,64]: k=i&63, n=i>>6, dout=p1; lo at dst+n+idx
struct CvtEnt { const void* src; int n; int dst; int mode; int p0; int p1; };
struct CvtTab { CvtEnt e[21]; };

__global__ void k_convert(CvtTab tab, float* __restrict__ fb, bf16* __restrict__ hb,
                          const int* __restrict__ flagp) {
    int i = blockIdx.x * blockDim.x + threadIdx.x;
    int fl = *flagp;
#pragma unroll 1
    for (int t = 0; t < 21; t++) {
        int n = tab.e[t].n;
        if (i < n) {
            float v = fl ? ((const float*)tab.e[t].src)[i]
                         : b2f(((const bf16*)tab.e[t].src)[i]);
            int mode = tab.e[t].mode, dst = tab.e[t].dst;
            if (mode == 0) {
                fb[dst + i] = v;
            } else {
                int idx;
                if (mode == 2) {
                    int dout = tab.e[t].p0;
                    int r = i / dout, c = i - r * dout;
                    idx = ((r >> 3) * dout + c) * 8 + (r & 7);
                } else {
                    int r = i >> 6, c = i & 63;       // r = n_eff, c = k_eff
                    idx = ((c >> 3) * tab.e[t].p1 + r) * 8 + (c & 7);
                }
                bf16 hv = __float2bfloat16(v);
                hb[dst + idx] = hv;
                hb[dst + n + idx] = __float2bfloat16(v - b2f(hv));
            }
            return;
        }
        i -= n;
    }
}

// ---------------- CSR construction ----------------
__global__ void k_zero_int(int* __restrict__ p, int n) {
    int i = blockIdx.x * blockDim.x + threadIdx.x;
    if (i < n) p[i] = 0;
}

__global__ void k_zero_f(float* __restrict__ p, int n) {
    int i = blockIdx.x * blockDim.x + threadIdx.x;
    if (i < n) p[i] = 0.f;
}

__global__ void k_count(const int* __restrict__ ei, int E, int* __restrict__ cnt) {
    int e = blockIdx.x * blockDim.x + threadIdx.x;
    if (e < E) atomicAdd(&cnt[ei[E + e]], 1);
}

__global__ void k_scan(const int* __restrict__ cnt, int* __restrict__ rowptr,
                       int* __restrict__ fill, float* __restrict__ dis) {
    __shared__ int sums[256];
    int t = threadIdx.x;
    int base = t * 32;
    int s = 0;
#pragma unroll
    for (int i = 0; i < 32; i++) s += cnt[base + i];
    sums[t] = s;
    __syncthreads();
    for (int off = 1; off < 256; off <<= 1) {
        int v = (t >= off) ? sums[t - off] : 0;
        __syncthreads();
        sums[t] += v;
        __syncthreads();
    }
    int run = (t == 0) ? 0 : sums[t - 1];
#pragma unroll
    for (int i = 0; i < 32; i++) {
        int idx = base + i;
        rowptr[idx] = run;
        fill[idx] = run;
        dis[idx] = rsqrtf((float)(cnt[idx] + 1));
        run += cnt[idx];
    }
    if (t == 255) rowptr[8192] = run;
}

__global__ void k_scatter(const int* __restrict__ ei, int E,
                          int* __restrict__ fill, int* __restrict__ ssrc) {
    int e = blockIdx.x * blockDim.x + threadIdx.x;
    if (e < E) {
        int pos = atomicAdd(&fill[ei[E + e]], 1);
        ssrc[pos] = ei[e];
    }
}

// ---------------- MFMA GEMM: fp32 A (in-register hi/lo split) x split-bf16 W ----------------
// 3 MFMAs/tile: ah*wh + al*wh + ah*wl  (al*wl ~ 2^-18, dropped).
// 2 waves/block (128 thr) -> 256 blocks fills all CUs.
// OMODE: 0 -> fp32 outF; 2 -> bf16 outH with QSCALE on cols n<64 (qkv)
template<int K, int DOUT, int OMODE>
__global__ void __launch_bounds__(128) k_mgemm(const float* __restrict__ A,
                                               const bf16* __restrict__ Wb,
                                               const float* __restrict__ bias,
                                               float* __restrict__ outF,
                                               bf16* __restrict__ outH) {
    constexpr int NCT = DOUT / 16, NKS = K / 32;
    constexpr int WPL = K * DOUT;
    int w = threadIdx.x >> 6, lane = threadIdx.x & 63;
    int lo = lane & 15, g = lane >> 4;
    int r0 = (blockIdx.x * 2 + w) * 16;
    const f32x4_t Z = {0.f, 0.f, 0.f, 0.f};
    f32x4_t acc[NCT];
#pragma unroll
    for (int ct = 0; ct < NCT; ct++) acc[ct] = Z;
#pragma unroll
    for (int kk = 0; kk < NKS; kk++) {
        const float* ap = A + (size_t)(r0 + lo) * K + kk * 32 + g * 8;
        float4 x0 = *(const float4*)ap;
        float4 x1 = *(const float4*)(ap + 4);
        union { unsigned u[4]; bf16x8_t v; } ah, al;
        ah.u[0] = pk(x0.x, x0.y);
        ah.u[1] = pk(x0.z, x0.w);
        ah.u[2] = pk(x1.x, x1.y);
        ah.u[3] = pk(x1.z, x1.w);
        al.u[0] = pk(x0.x - lo16f(ah.u[0]), x0.y - hi16f(ah.u[0]));
        al.u[1] = pk(x0.z - lo16f(ah.u[1]), x0.w - hi16f(ah.u[1]));
        al.u[2] = pk(x1.x - lo16f(ah.u[2]), x1.y - hi16f(ah.u[2]));
        al.u[3] = pk(x1.z - lo16f(ah.u[3]), x1.w - hi16f(ah.u[3]));
#pragma unroll
        for (int ct = 0; ct < NCT; ct++) {
            size_t wi = (size_t)((kk * 4 + g) * DOUT + ct * 16 + lo) * 8;
            bf16x8_t wh = *(const bf16x8_t*)(Wb + wi);
            bf16x8_t wl = *(const bf16x8_t*)(Wb + WPL + wi);
            acc[ct] = __builtin_amdgcn_mfma_f32_16x16x32_bf16(ah.v, wh, acc[ct], 0, 0, 0);
            acc[ct] = __builtin_amdgcn_mfma_f32_16x16x32_bf16(al.v, wh, acc[ct], 0, 0, 0);
            acc[ct] = __builtin_amdgcn_mfma_f32_16x16x32_bf16(ah.v, wl, acc[ct], 0, 0, 0);
        }
    }
#pragma unroll
    for (int ct = 0; ct < NCT; ct++) {
        int n = ct * 16 + lo;
        float bs = bias ? bias[n] : 0.f;
#pragma unroll
        for (int r = 0; r < 4; r++) {
            float v = acc[ct][r] + bs;
            size_t o = (size_t)(r0 + 4 * g + r) * DOUT + n;
            if (OMODE == 0) {
                outF[o] = v;
            } else {
                if (OMODE == 2 && n < 64) v *= QSCALE;
                outH[o] = __float2bfloat16(v);
            }
        }
    }
}

// ---------------- GCN aggregation (fp32, R7 numerics, 256-thr + 4x edge unroll) ----------------
// thread -> (node,f) map identical to R7 (local = 2*t over 512-feat strip).
// dout=128: 4 nodes/block (grid 2048); dout=64: 8 nodes/block (grid 1024).
__global__ void __launch_bounds__(256) k_agg(const float* __restrict__ hd,
                      const int* __restrict__ rowptr,
                      const int* __restrict__ ssrc, const float* __restrict__ dis,
                      const float* __restrict__ bias, const float* __restrict__ resid,
                      float* __restrict__ outF, void* __restrict__ outAny, int outOff,
                      const int* __restrict__ flagp, int dout, int relu) {
    int local = 2 * threadIdx.x;
    int node = blockIdx.x * (512 / dout) + local / dout;
    int f = local & (dout - 1);
    float di = dis[node];
    float dii = di * di;
    float2 self = *(const float2*)(hd + (size_t)node * dout + f);
    float a0 = self.x * dii, a1 = self.y * dii;
    int e0 = rowptr[node], e1 = rowptr[node + 1];
    int e = e0;
    for (; e + 4 <= e1; e += 4) {
        int s0 = ssrc[e], s1 = ssrc[e + 1], s2 = ssrc[e + 2], s3 = ssrc[e + 3];
        float w0 = dis[s0] * di, w1 = dis[s1] * di, w2 = dis[s2] * di, w3 = dis[s3] * di;
        float2 v0 = *(const float2*)(hd + (size_t)s0 * dout + f);
        float2 v1 = *(const float2*)(hd + (size_t)s1 * dout + f);
        float2 v2 = *(const float2*)(hd + (size_t)s2 * dout + f);
        float2 v3 = *(const float2*)(hd + (size_t)s3 * dout + f);
        a0 += v0.x * w0; a1 += v0.y * w0;
        a0 += v1.x * w1; a1 += v1.y * w1;
        a0 += v2.x * w2; a1 += v2.y * w2;
        a0 += v3.x * w3; a1 += v3.y * w3;
    }
    for (; e < e1; e++) {
        int s = ssrc[e];
        float wgt = dis[s] * di;
        float2 v = *(const float2*)(hd + (size_t)s * dout + f);
        a0 += v.x * wgt;
        a1 += v.y * wgt;
    }
    a0 += bias[f];
    a1 += bias[f + 1];
    if (relu) { a0 = fmaxf(a0, 0.f); a1 = fmaxf(a1, 0.f); }
    if (resid) {
        float2 rv = *(const float2*)(resid + (size_t)node * dout + f);
        a0 += rv.x;
        a1 += rv.y;
    }
    size_t o = (size_t)node * dout + f;
    if (outF) *(float2*)(outF + o) = make_float2(a0, a1);
    if (outAny) {
        if (*flagp) {
            float* po = (float*)outAny + outOff;
            po[o] = a0; po[o + 1] = a1;
        } else {
            *(unsigned*)((bf16*)outAny + outOff + o) = pk(a0, a1);
        }
    }
}

// ---------------- MFMA flash attention v3: no-max (shift-invariant), atomic merge ----------
// Scores are small (|s| << 100) so exp2 without max-shift is exact-in-fp32; softmax is
// shift-invariant so the result is mathematically identical to the R3-proven kernel.
// wave = (c,h,qt): 32 q rows, m-chunk c of 1024. 8192 waves / 2048 blocks.
// acc[(h*8192+q)*17 + {0..15:o(d), 16:l}], fp32 atomicAdd merged across the 8 chunks.
__global__ void __launch_bounds__(256, 8)
k_flash(const bf16* __restrict__ qkv, float* __restrict__ acc) {
    __shared__ unsigned short plds[4][2][16][40];   // [wave][qsub][q'][m' padded] (R7-proven)
    int w = threadIdx.x >> 6;
    int lane = threadIdx.x & 63;
    int lo = lane & 15;
    int g = lane >> 4;
    int wid = blockIdx.x * 4 + w;
    int qt = wid & 255;
    int h = (wid >> 8) & 3;
    int c = wid >> 10;
    int q0 = qt * 32;
    int m0base = c * 1024;

    const f32x4_t Z = {0.f, 0.f, 0.f, 0.f};
    bf16x8_t zf;
#pragma unroll
    for (int i = 0; i < 8; i++) zf[i] = 0;

    bf16x8_t qf[2];
#pragma unroll
    for (int s = 0; s < 2; s++) {
        if (g < 2) qf[s] = *(const bf16x8_t*)(qkv + (size_t)(q0 + s * 16 + lo) * 192 + h * 16 + g * 8);
        else       qf[s] = zf;
    }

    f32x4_t oacc[2] = {Z, Z};
    float lr[2] = {0.f, 0.f};

    const int koff = 64 + h * 16 + g * 8;
    const int voff = 128 + h * 16 + lo;

    for (int t = 0; t < 32; t++) {
        int m0 = m0base + t * 32;
        bf16x8_t kf0 = zf, kf1 = zf;
        if (g < 2) {
            kf0 = *(const bf16x8_t*)(qkv + (size_t)(m0 + lo) * 192 + koff);
            kf1 = *(const bf16x8_t*)(qkv + (size_t)(m0 + 16 + lo) * 192 + koff);
        }
        union { unsigned u[4]; bf16x8_t v; } vt;
#pragma unroll
        for (int jj = 0; jj < 4; jj++) {
            unsigned a = *(const unsigned short*)(qkv + (size_t)(m0 + 8 * g + 2 * jj) * 192 + voff);
            unsigned b = *(const unsigned short*)(qkv + (size_t)(m0 + 8 * g + 2 * jj + 1) * 192 + voff);
            vt.u[jj] = a | (b << 16);
        }
#pragma unroll
        for (int s = 0; s < 2; s++) {
            f32x4_t s0 = __builtin_amdgcn_mfma_f32_16x16x32_bf16(kf0, qf[s], Z, 0, 0, 0);
            f32x4_t s1 = __builtin_amdgcn_mfma_f32_16x16x32_bf16(kf1, qf[s], Z, 0, 0, 0);
            float p0 = __builtin_amdgcn_exp2f(s0[0]);
            float p1 = __builtin_amdgcn_exp2f(s0[1]);
            float p2 = __builtin_amdgcn_exp2f(s0[2]);
            float p3 = __builtin_amdgcn_exp2f(s0[3]);
            float p4 = __builtin_amdgcn_exp2f(s1[0]);
            float p5 = __builtin_amdgcn_exp2f(s1[1]);
            float p6 = __builtin_amdgcn_exp2f(s1[2]);
            float p7 = __builtin_amdgcn_exp2f(s1[3]);
            lr[s] += (((p0 + p1) + (p2 + p3)) + ((p4 + p5) + (p6 + p7)));
            unsigned* dst0 = (unsigned*)&plds[w][s][lo][4 * g];
            dst0[0] = pk(p0, p1);
            dst0[1] = pk(p2, p3);
            unsigned* dst1 = (unsigned*)&plds[w][s][lo][16 + 4 * g];
            dst1[0] = pk(p4, p5);
            dst1[1] = pk(p6, p7);
            bf16x8_t pf = *(const bf16x8_t*)&plds[w][s][lo][8 * g];
            oacc[s] = __builtin_amdgcn_mfma_f32_16x16x32_bf16(vt.v, pf, oacc[s], 0, 0, 0);
        }
    }
#pragma unroll
    for (int s = 0; s < 2; s++) {
        float l = lr[s];
        l += __shfl_xor(l, 16);
        l += __shfl_xor(l, 32);
        int q = q0 + s * 16 + lo;
        float* A = acc + (size_t)(h * 8192 + q) * 17;
#pragma unroll
        for (int r = 0; r < 4; r++) atomicAdd(A + 4 * g + r, oacc[s][r]);
        if (g == 0) atomicAdd(A + 16, l);
    }
}

__global__ void k_norm(const float* __restrict__ acc, float* __restrict__ Bo) {
    int idx = blockIdx.x * blockDim.x + threadIdx.x;   // h*8192+q, 32768 total
    int h = idx >> 13;
    int q = idx & 8191;
    const float* A = acc + (size_t)idx * 17;
    float inv = 1.f / A[16];
    float* dst = Bo + (size_t)q * 64 + h * 16;
#pragma unroll
    for (int j = 0; j < 16; j++) dst[j] = A[j] * inv;
}

// ---------------- launch ----------------
extern "C" void kernel_launch(void* const* d_in, const int* in_sizes, int n_in,
                              void* d_out, int out_size, void* d_ws, size_t ws_size,
                              hipStream_t stream) {
    int E = in_sizes[1] / 2;
    const int* ei = (const int*)d_in[1];

    int*   ib = (int*)d_ws;
    float* fb = (float*)d_ws;
    int* cnt    = ib;
    int* rowptr = ib + 8192;
    int* fill   = ib + 16448;
    int* ssrc   = ib + 24640;
    int* flagp  = ib + 286784;
    float* dis  = fb + OFF_DIS;
    float* Bias = fb + OFF_BIAS;
    bf16*  Wb   = (bf16*)(fb + OFF_WB);
    float* Hx   = fb + OFF_X;
    float* HD   = fb + OFF_HD;
    float* HA   = fb + OFF_HA;
    float* HB   = fb + OFF_HB;
    float* Hz   = fb + OFF_HZ;
    float* Bo   = fb + OFF_BO;
    float* ZA   = fb + OFF_ZA;
    bf16*  Qkv  = (bf16*)(fb + OFF_QKV);
    float* acc  = HD;    // 4*8192*17 = 557056 floats, HD dead during attention

    dim3 b256(256), b128(128);
    int eb = (E + 255) / 256;

    k_sniff<<<dim3(1), b256, 0, stream>>>((const unsigned short*)d_in[0], flagp);
    k_zero_int<<<dim3(32), b256, 0, stream>>>(cnt, 8192);
    k_count<<<dim3(eb), b256, 0, stream>>>(ei, E, cnt);
    k_scan<<<dim3(1), b256, 0, stream>>>(cnt, rowptr, fill, dis);
    k_scatter<<<dim3(eb), b256, 0, stream>>>(ei, E, fill, ssrc);

    CvtTab tab;
    auto ent = [&](int i, const void* s, int n, int dst, int mode, int p0, int p1) {
        tab.e[i] = CvtEnt{s, n, dst, mode, p0, p1};
    };
    ent(0,  d_in[0],  524288, OFF_X, 0, 0, 0);
    ent(1,  d_in[2],  8192,  HS_E1, 2, 128, 0);
    ent(2,  d_in[3],  128,   OFF_BIAS + BF_E1, 0, 0, 0);
    ent(3,  d_in[4],  16384, HS_E2, 2, 128, 0);
    ent(4,  d_in[5],  128,   OFF_BIAS + BF_E2, 0, 0, 0);
    ent(5,  d_in[6],  16384, HS_E3, 2, 128, 0);
    ent(6,  d_in[7],  128,   OFF_BIAS + BF_E3, 0, 0, 0);
    ent(7,  d_in[8],  8192,  HS_E4, 2, 64, 0);
    ent(8,  d_in[9],  64,    OFF_BIAS + BF_E4, 0, 0, 0);
    ent(9,  d_in[10], 8192,  HS_D1, 2, 128, 0);
    ent(10, d_in[11], 128,   OFF_BIAS + BF_D1, 0, 0, 0);
    ent(11, d_in[12], 16384, HS_D2, 2, 128, 0);
    ent(12, d_in[13], 128,   OFF_BIAS + BF_D2, 0, 0, 0);
    ent(13, d_in[14], 16384, HS_D3, 2, 128, 0);
    ent(14, d_in[15], 128,   OFF_BIAS + BF_D3, 0, 0, 0);
    ent(15, d_in[16], 8192,  HS_D4, 2, 64, 0);
    ent(16, d_in[17], 64,    OFF_BIAS + BF_D4, 0, 0, 0);
    ent(17, d_in[18], 12288, HS_AI, 3, 0, 192);
    ent(18, d_in[19], 192,   OFF_BIAS + BF_AI, 0, 0, 0);
    ent(19, d_in[20], 4096,  HS_AO, 3, 0, 64);
    ent(20, d_in[21], 64,    OFF_BIAS + BF_AO, 0, 0, 0);
    k_convert<<<dim3(2501), b256, 0, stream>>>(tab, fb, Wb, flagp);

    dim3 g256(256), g1024(1024), g2048(2048);

    // encoder: x -> h1(HA) -> h2(HB) -> h3(HA) -> z(Hz + d_out)
    k_mgemm<64, 128, 0><<<g256, b128, 0, stream>>>(Hx, Wb + HS_E1, nullptr, HD, nullptr);
    k_agg<<<g2048, b256, 0, stream>>>(HD, rowptr, ssrc, dis, Bias + BF_E1, nullptr,
                                      HA, nullptr, 0, flagp, 128, 1);
    k_mgemm<128, 128, 0><<<g256, b128, 0, stream>>>(HA, Wb + HS_E2, nullptr, HD, nullptr);
    k_agg<<<g2048, b256, 0, stream>>>(HD, rowptr, ssrc, dis, Bias + BF_E2, HA,
                                      HB, nullptr, 0, flagp, 128, 1);
    k_mgemm<128, 128, 0><<<g256, b128, 0, stream>>>(HB, Wb + HS_E3, nullptr, HD, nullptr);
    k_agg<<<g2048, b256, 0, stream>>>(HD, rowptr, ssrc, dis, Bias + BF_E3, HB,
                                      HA, nullptr, 0, flagp, 128, 1);
    k_mgemm<128, 64, 0><<<g256, b128, 0, stream>>>(HA, Wb + HS_E4, nullptr, HD, nullptr);
    k_agg<<<g1024, b256, 0, stream>>>(HD, rowptr, ssrc, dis, Bias + BF_E4, nullptr,
                                      Hz, d_out, 524288, flagp, 64, 0);

    // attention: qkv (q cols scaled fp32) ; zero acc ; flash v3 ; normalize ; out-proj
    k_mgemm<64, 192, 2><<<g256, b128, 0, stream>>>(Hz, Wb + HS_AI, Bias + BF_AI, nullptr, Qkv);
    k_zero_f<<<dim3(2176), b256, 0, stream>>>(acc, 557056);
    k_flash<<<g2048, b256, 0, stream>>>(Qkv, acc);
    k_norm<<<dim3(128), b256, 0, stream>>>(acc, Bo);
    k_mgemm<64, 64, 0><<<g256, b128, 0, stream>>>(Bo, Wb + HS_AO, Bias + BF_AO, ZA, nullptr);

    // decoder: za -> g1(HA) -> g2(HB) -> g3(HA) -> x_recon(d_out)
    k_mgemm<64, 128, 0><<<g256, b128, 0, stream>>>(ZA, Wb + HS_D1, nullptr, HD, nullptr);
    k_agg<<<g2048, b256, 0, stream>>>(HD, rowptr, ssrc, dis, Bias + BF_D1, nullptr,
                                      HA, nullptr, 0, flagp, 128, 1);
    k_mgemm<128, 128, 0><<<g256, b128, 0, stream>>>(HA, Wb + HS_D2, nullptr, HD, nullptr);
    k_agg<<<g2048, b256, 0, stream>>>(HD, rowptr, ssrc, dis, Bias + BF_D2, HA,
                                      HB, nullptr, 0, flagp, 128, 1);
    k_mgemm<128, 128, 0><<<g256, b128, 0, stream>>>(HB, Wb + HS_D3, nullptr, HD, nullptr);
    k_agg<<<g2048, b256, 0, stream>>>(HD, rowptr, ssrc, dis, Bias + BF_D3, HB,
                                      HA, nullptr, 0, flagp, 128, 1);
    k_mgemm<128, 64, 0><<<g256, b128, 0, stream>>>(HA, Wb + HS_D4, nullptr, HD, nullptr);
    k_agg<<<g1024, b256, 0, stream>>>(HD, rowptr, ssrc, dis, Bias + BF_D4, nullptr,
                                      nullptr, d_out, 0, flagp, 64, 0);
}

// Round 9
// 461.814 us; speedup vs baseline: 2.6929x; 1.1306x over previous
//
#include <hip/hip_runtime.h>
#include <hip/hip_bf16.h>

using bf16 = __hip_bfloat16;

typedef __attribute__((ext_vector_type(8))) short bf16x8_t;   // 8 bf16 in 4 VGPRs
typedef __attribute__((ext_vector_type(4))) float f32x4_t;

static __device__ __forceinline__ float b2f(bf16 v) { return __bfloat162float(v); }

// pack two fp32 -> 2 bf16 (RNE)
static __device__ __forceinline__ unsigned pk(float a, float b) {
    unsigned ua = __float_as_uint(a); ua += 0x7FFFu + ((ua >> 16) & 1u);
    unsigned ub = __float_as_uint(b); ub += 0x7FFFu + ((ub >> 16) & 1u);
    return (ua >> 16) | (ub & 0xFFFF0000u);
}
static __device__ __forceinline__ float lo16f(unsigned u) { return __uint_as_float(u << 16); }
static __device__ __forceinline__ float hi16f(unsigned u) { return __uint_as_float(u & 0xFFFF0000u); }

// log2(e)/4 : folds 1/sqrt(DH) and exp->exp2. Applied at qkv GEMM output (fp32).
#define QSCALE 0.36067376022224085f

// ---------------- workspace layout (float offsets) ----------------
// ints: cnt[0,8192) rowptr[8192,16385) fill[16448,24640) ssrc[24640,286784) flag ib[286784]
#define OFF_DIS  286848
#define OFF_BIAS 295040   /* 1152 fp32 */
#define OFF_WB   296192   /* bf16 weights (split hi+lo), 229376 shorts = 114688 floats */
#define OFF_X    410880   /* fp32 x [8192,64]; dsrc (262144 f) aliases after gemm1 reads X */
#define OFF_HD   935168   /* fp32 gemm out [8192,128] */
#define OFF_HA   1983744  /* fp32 act [8192,128] */
#define OFF_HB   3032320  /* fp32 act [8192,128] */
#define OFF_HZ   4080896  /* fp32 z [8192,64] */
#define OFF_BO   4605184  /* fp32 attention out [8192,64] */
#define OFF_ZA   5129472  /* fp32 za [8192,64] */
#define OFF_QKV  5653760  /* bf16: Qb[8192*64] | Kb[8192*64] | VT[64*8192] = 786432 f slots */
// total 6440192 floats = 25.76 MB

// weight short-offsets (relative to OFF_WB as bf16*), each region hi plane then lo plane
#define HS_E1 0
#define HS_E2 16384
#define HS_E3 49152
#define HS_E4 81920
#define HS_D1 98304
#define HS_D2 114688
#define HS_D3 147456
#define HS_D4 180224
#define HS_AI 196608
#define HS_AO 221184

// bias fp32 offsets (relative to OFF_BIAS)
#define BF_E1 0
#define BF_E2 128
#define BF_E3 256
#define BF_E4 384
#define BF_D1 448
#define BF_D2 576
#define BF_D3 704
#define BF_D4 832
#define BF_AI 896
#define BF_AO 1088

// ---------------- dtype sniff (1 => inputs are fp32) ----------------
__global__ void k_sniff(const unsigned short* __restrict__ xb, int* __restrict__ flagp) {
    __shared__ int cnt;
    if (threadIdx.x == 0) cnt = 0;
    __syncthreads();
    unsigned short w = xb[threadIdx.x * 2];
    int e = (w >> 7) & 0xFF;
    int m = w & 0x7F;
    int weird = (e >= 134) || (e != 0 && e <= 90) || (e == 0 && m != 0);
    if (weird) atomicAdd(&cnt, 1);
    __syncthreads();
    if (threadIdx.x == 0) *flagp = (cnt >= 32) ? 1 : 0;
}

// ---------------- input canonicalization ----------------
// mode 0: fp32 -> fb[dst+i]
// mode 2: split weight swizzle from [K,dout=p0]: idx=((k>>3)*dout+n)*8+(k&7); lo at dst+n+idx
// mode 3: split weight transpose+swizzle from [rows,64]: k=i&63, n=i>>6, dout=p1; lo at dst+n+idx
struct CvtEnt { const void* src; int n; int dst; int mode; int p0; int p1; };
struct CvtTab { CvtEnt e[21]; };

__global__ void k_convert(CvtTab tab, float* __restrict__ fb, bf16* __restrict__ hb,
                          const int* __restrict__ flagp) {
    int i = blockIdx.x * blockDim.x + threadIdx.x;
    int fl = *flagp;
#pragma unroll 1
    for (int t = 0; t < 21; t++) {
        int n = tab.e[t].n;
        if (i < n) {
            float v = fl ? ((const float*)tab.e[t].src)[i]
                         : b2f(((const bf16*)tab.e[t].src)[i]);
            int mode = tab.e[t].mode, dst = tab.e[t].dst;
            if (mode == 0) {
                fb[dst + i] = v;
            } else {
                int idx;
                if (mode == 2) {
                    int dout = tab.e[t].p0;
                    int r = i / dout, c = i - r * dout;
                    idx = ((r >> 3) * dout + c) * 8 + (r & 7);
                } else {
                    int r = i >> 6, c = i & 63;       // r = n_eff, c = k_eff
                    idx = ((c >> 3) * tab.e[t].p1 + r) * 8 + (c & 7);
                }
                bf16 hv = __float2bfloat16(v);
                hb[dst + idx] = hv;
                hb[dst + n + idx] = __float2bfloat16(v - b2f(hv));
            }
            return;
        }
        i -= n;
    }
}

// ---------------- CSR construction ----------------
__global__ void k_zero_int(int* __restrict__ p, int n) {
    int i = blockIdx.x * blockDim.x + threadIdx.x;
    if (i < n) p[i] = 0;
}

__global__ void k_count(const int* __restrict__ ei, int E, int* __restrict__ cnt) {
    int e = blockIdx.x * blockDim.x + threadIdx.x;
    if (e < E) atomicAdd(&cnt[ei[E + e]], 1);
}

__global__ void k_scan(const int* __restrict__ cnt, int* __restrict__ rowptr,
                       int* __restrict__ fill, float* __restrict__ dis) {
    __shared__ int sums[256];
    int t = threadIdx.x;
    int base = t * 32;
    int s = 0;
#pragma unroll
    for (int i = 0; i < 32; i++) s += cnt[base + i];
    sums[t] = s;
    __syncthreads();
    for (int off = 1; off < 256; off <<= 1) {
        int v = (t >= off) ? sums[t - off] : 0;
        __syncthreads();
        sums[t] += v;
        __syncthreads();
    }
    int run = (t == 0) ? 0 : sums[t - 1];
#pragma unroll
    for (int i = 0; i < 32; i++) {
        int idx = base + i;
        rowptr[idx] = run;
        fill[idx] = run;
        dis[idx] = rsqrtf((float)(cnt[idx] + 1));
        run += cnt[idx];
    }
    if (t == 255) rowptr[8192] = run;
}

// scatter also records dsrc[pos] = dis[src] so agg needs no dependent gather
__global__ void k_scatter(const int* __restrict__ ei, int E,
                          int* __restrict__ fill, int* __restrict__ ssrc,
                          const float* __restrict__ dis, float* __restrict__ dsrc) {
    int e = blockIdx.x * blockDim.x + threadIdx.x;
    if (e < E) {
        int s = ei[e];
        int pos = atomicAdd(&fill[ei[E + e]], 1);
        ssrc[pos] = s;
        dsrc[pos] = dis[s];
    }
}

// ---------------- MFMA GEMM: fp32 A (in-register hi/lo split) x split-bf16 W ----------------
// 3 MFMAs/tile: ah*wh + al*wh + ah*wl  (al*wl ~ 2^-18, dropped).
// OMODE: 0 -> fp32 outF; 2 -> qkv projection: Q (scaled, [8192,64]) | K [8192,64] | VT [64,8192]
template<int K, int DOUT, int OMODE>
__global__ void __launch_bounds__(128) k_mgemm(const float* __restrict__ A,
                                               const bf16* __restrict__ Wb,
                                               const float* __restrict__ bias,
                                               float* __restrict__ outF,
                                               bf16* __restrict__ outH) {
    constexpr int NCT = DOUT / 16, NKS = K / 32;
    constexpr int WPL = K * DOUT;
    int w = threadIdx.x >> 6, lane = threadIdx.x & 63;
    int lo = lane & 15, g = lane >> 4;
    int r0 = (blockIdx.x * 2 + w) * 16;
    const f32x4_t Z = {0.f, 0.f, 0.f, 0.f};
    f32x4_t acc[NCT];
#pragma unroll
    for (int ct = 0; ct < NCT; ct++) acc[ct] = Z;
#pragma unroll
    for (int kk = 0; kk < NKS; kk++) {
        const float* ap = A + (size_t)(r0 + lo) * K + kk * 32 + g * 8;
        float4 x0 = *(const float4*)ap;
        float4 x1 = *(const float4*)(ap + 4);
        union { unsigned u[4]; bf16x8_t v; } ah, al;
        ah.u[0] = pk(x0.x, x0.y);
        ah.u[1] = pk(x0.z, x0.w);
        ah.u[2] = pk(x1.x, x1.y);
        ah.u[3] = pk(x1.z, x1.w);
        al.u[0] = pk(x0.x - lo16f(ah.u[0]), x0.y - hi16f(ah.u[0]));
        al.u[1] = pk(x0.z - lo16f(ah.u[1]), x0.w - hi16f(ah.u[1]));
        al.u[2] = pk(x1.x - lo16f(ah.u[2]), x1.y - hi16f(ah.u[2]));
        al.u[3] = pk(x1.z - lo16f(ah.u[3]), x1.w - hi16f(ah.u[3]));
#pragma unroll
        for (int ct = 0; ct < NCT; ct++) {
            size_t wi = (size_t)((kk * 4 + g) * DOUT + ct * 16 + lo) * 8;
            bf16x8_t wh = *(const bf16x8_t*)(Wb + wi);
            bf16x8_t wl = *(const bf16x8_t*)(Wb + WPL + wi);
            acc[ct] = __builtin_amdgcn_mfma_f32_16x16x32_bf16(ah.v, wh, acc[ct], 0, 0, 0);
            acc[ct] = __builtin_amdgcn_mfma_f32_16x16x32_bf16(al.v, wh, acc[ct], 0, 0, 0);
            acc[ct] = __builtin_amdgcn_mfma_f32_16x16x32_bf16(ah.v, wl, acc[ct], 0, 0, 0);
        }
    }
#pragma unroll
    for (int ct = 0; ct < NCT; ct++) {
        int n = ct * 16 + lo;
        float bs = bias ? bias[n] : 0.f;
#pragma unroll
        for (int r = 0; r < 4; r++) {
            float v = acc[ct][r] + bs;
            int node = r0 + 4 * g + r;
            if (OMODE == 0) {
                outF[(size_t)node * DOUT + n] = v;
            } else {
                if (n < 64) {
                    outH[(size_t)node * 64 + n] = __float2bfloat16(v * QSCALE);
                } else if (n < 128) {
                    outH[524288 + (size_t)node * 64 + (n - 64)] = __float2bfloat16(v);
                } else {
                    outH[1048576 + (size_t)(n - 128) * 8192 + node] = __float2bfloat16(v);
                }
            }
        }
    }
}

// ---------------- GCN aggregation (fp32, dsrc-precomputed edge weights) ----------------
// thread -> (node,f) map as R8; wgt = dsrc[e]*di is BITWISE identical to dis[s]*di.
__global__ void __launch_bounds__(256) k_agg(const float* __restrict__ hd,
                      const int* __restrict__ rowptr,
                      const int* __restrict__ ssrc, const float* __restrict__ dsrc,
                      const float* __restrict__ dis,
                      const float* __restrict__ bias, const float* __restrict__ resid,
                      float* __restrict__ outF, void* __restrict__ outAny, int outOff,
                      const int* __restrict__ flagp, int dout, int relu) {
    int local = 2 * threadIdx.x;
    int node = blockIdx.x * (512 / dout) + local / dout;
    int f = local & (dout - 1);
    float di = dis[node];
    float dii = di * di;
    float2 self = *(const float2*)(hd + (size_t)node * dout + f);
    float a0 = self.x * dii, a1 = self.y * dii;
    int e0 = rowptr[node], e1 = rowptr[node + 1];
    int e = e0;
    for (; e + 4 <= e1; e += 4) {
        int s0 = ssrc[e], s1 = ssrc[e + 1], s2 = ssrc[e + 2], s3 = ssrc[e + 3];
        float w0 = dsrc[e] * di, w1 = dsrc[e + 1] * di;
        float w2 = dsrc[e + 2] * di, w3 = dsrc[e + 3] * di;
        float2 v0 = *(const float2*)(hd + (size_t)s0 * dout + f);
        float2 v1 = *(const float2*)(hd + (size_t)s1 * dout + f);
        float2 v2 = *(const float2*)(hd + (size_t)s2 * dout + f);
        float2 v3 = *(const float2*)(hd + (size_t)s3 * dout + f);
        a0 += v0.x * w0; a1 += v0.y * w0;
        a0 += v1.x * w1; a1 += v1.y * w1;
        a0 += v2.x * w2; a1 += v2.y * w2;
        a0 += v3.x * w3; a1 += v3.y * w3;
    }
    for (; e < e1; e++) {
        int s = ssrc[e];
        float wgt = dsrc[e] * di;
        float2 v = *(const float2*)(hd + (size_t)s * dout + f);
        a0 += v.x * wgt;
        a1 += v.y * wgt;
    }
    a0 += bias[f];
    a1 += bias[f + 1];
    if (relu) { a0 = fmaxf(a0, 0.f); a1 = fmaxf(a1, 0.f); }
    if (resid) {
        float2 rv = *(const float2*)(resid + (size_t)node * dout + f);
        a0 += rv.x;
        a1 += rv.y;
    }
    size_t o = (size_t)node * dout + f;
    if (outF) *(float2*)(outF + o) = make_float2(a0, a1);
    if (outAny) {
        if (*flagp) {
            float* po = (float*)outAny + outOff;
            po[o] = a0; po[o + 1] = a1;
        } else {
            *(unsigned*)((bf16*)outAny + outOff + o) = pk(a0, a1);
        }
    }
}

// ---------------- MFMA flash attention v4 ----------------
// Block = (qt, h): 512 threads = 8 waves, wave w owns m-chunk [w*1024, (w+1)*1024).
// No-max exp2 (R8-proven), per-wave private accumulation, LDS tree-reduce, plain
// normalized stores of Bo. V is pre-transposed (VT[64][8192]) -> contiguous A-frag load.
__global__ void __launch_bounds__(512)
k_flash(const bf16* __restrict__ Qb, const bf16* __restrict__ Kb,
        const bf16* __restrict__ VT, float* __restrict__ Bo) {
    __shared__ unsigned short plds[8][2][16][40];   // per-wave P^T staging (R7/R8-proven)
    __shared__ float redo[8][2][16][16];
    __shared__ float redl[8][2][16];
    int w = threadIdx.x >> 6;
    int lane = threadIdx.x & 63;
    int lo = lane & 15;
    int g = lane >> 4;
    int qt = blockIdx.x & 255;
    int h = blockIdx.x >> 8;
    int q0 = qt * 32;
    int m0base = w * 1024;

    const f32x4_t Z = {0.f, 0.f, 0.f, 0.f};
    bf16x8_t zf;
#pragma unroll
    for (int i = 0; i < 8; i++) zf[i] = 0;

    bf16x8_t qf[2];
#pragma unroll
    for (int s = 0; s < 2; s++) {
        if (g < 2) qf[s] = *(const bf16x8_t*)(Qb + (size_t)(q0 + s * 16 + lo) * 64 + h * 16 + g * 8);
        else       qf[s] = zf;
    }

    f32x4_t oacc[2] = {Z, Z};
    float lr[2] = {0.f, 0.f};
    const bf16* kbase = Kb + h * 16 + g * 8;
    const bf16* vbase = VT + (size_t)(h * 16 + lo) * 8192;

    for (int t = 0; t < 32; t++) {
        int m0 = m0base + t * 32;
        bf16x8_t kf0 = zf, kf1 = zf;
        if (g < 2) {
            kf0 = *(const bf16x8_t*)(kbase + (size_t)m0 * 64);
            kf1 = *(const bf16x8_t*)(kbase + (size_t)(m0 + 16) * 64);
        }
        bf16x8_t vt = *(const bf16x8_t*)(vbase + m0 + 8 * g);
#pragma unroll
        for (int s = 0; s < 2; s++) {
            f32x4_t s0 = __builtin_amdgcn_mfma_f32_16x16x32_bf16(kf0, qf[s], Z, 0, 0, 0);
            f32x4_t s1 = __builtin_amdgcn_mfma_f32_16x16x32_bf16(kf1, qf[s], Z, 0, 0, 0);
            float p0 = __builtin_amdgcn_exp2f(s0[0]);
            float p1 = __builtin_amdgcn_exp2f(s0[1]);
            float p2 = __builtin_amdgcn_exp2f(s0[2]);
            float p3 = __builtin_amdgcn_exp2f(s0[3]);
            float p4 = __builtin_amdgcn_exp2f(s1[0]);
            float p5 = __builtin_amdgcn_exp2f(s1[1]);
            float p6 = __builtin_amdgcn_exp2f(s1[2]);
            float p7 = __builtin_amdgcn_exp2f(s1[3]);
            lr[s] += (((p0 + p1) + (p2 + p3)) + ((p4 + p5) + (p6 + p7)));
            unsigned* dst0 = (unsigned*)&plds[w][s][lo][4 * g];
            dst0[0] = pk(p0, p1);
            dst0[1] = pk(p2, p3);
            unsigned* dst1 = (unsigned*)&plds[w][s][lo][16 + 4 * g];
            dst1[0] = pk(p4, p5);
            dst1[1] = pk(p6, p7);
            bf16x8_t pf = *(const bf16x8_t*)&plds[w][s][lo][8 * g];
            oacc[s] = __builtin_amdgcn_mfma_f32_16x16x32_bf16(vt, pf, oacc[s], 0, 0, 0);
        }
    }
#pragma unroll
    for (int s = 0; s < 2; s++) {
        float l = lr[s];
        l += __shfl_xor(l, 16);
        l += __shfl_xor(l, 32);
        *(f32x4_t*)&redo[w][s][lo][4 * g] = oacc[s];
        if (g == 0) redl[w][s][lo] = l;
    }
    __syncthreads();
    int tid = threadIdx.x;
    int s2 = tid >> 8, q2 = (tid >> 4) & 15, d2 = tid & 15;
    float o = 0.f, l = 0.f;
#pragma unroll
    for (int ww = 0; ww < 8; ww++) {
        o += redo[ww][s2][q2][d2];
        l += redl[ww][s2][q2];
    }
    Bo[(size_t)(q0 + s2 * 16 + q2) * 64 + h * 16 + d2] = o / l;
}

// ---------------- launch ----------------
extern "C" void kernel_launch(void* const* d_in, const int* in_sizes, int n_in,
                              void* d_out, int out_size, void* d_ws, size_t ws_size,
                              hipStream_t stream) {
    int E = in_sizes[1] / 2;
    const int* ei = (const int*)d_in[1];

    int*   ib = (int*)d_ws;
    float* fb = (float*)d_ws;
    int* cnt    = ib;
    int* rowptr = ib + 8192;
    int* fill   = ib + 16448;
    int* ssrc   = ib + 24640;
    int* flagp  = ib + 286784;
    float* dis  = fb + OFF_DIS;
    float* Bias = fb + OFF_BIAS;
    bf16*  Wb   = (bf16*)(fb + OFF_WB);
    float* Hx   = fb + OFF_X;
    float* dsrc = fb + OFF_X;     // aliases X; written by scatter AFTER gemm1 consumed X
    float* HD   = fb + OFF_HD;
    float* HA   = fb + OFF_HA;
    float* HB   = fb + OFF_HB;
    float* Hz   = fb + OFF_HZ;
    float* Bo   = fb + OFF_BO;
    float* ZA   = fb + OFF_ZA;
    bf16*  Qkv  = (bf16*)(fb + OFF_QKV);   // Qb | Kb(+524288) | VT(+1048576)

    dim3 b256(256), b128(128);
    int eb = (E + 255) / 256;

    k_sniff<<<dim3(1), b256, 0, stream>>>((const unsigned short*)d_in[0], flagp);
    k_zero_int<<<dim3(32), b256, 0, stream>>>(cnt, 8192);
    k_count<<<dim3(eb), b256, 0, stream>>>(ei, E, cnt);
    k_scan<<<dim3(1), b256, 0, stream>>>(cnt, rowptr, fill, dis);

    CvtTab tab;
    auto ent = [&](int i, const void* s, int n, int dst, int mode, int p0, int p1) {
        tab.e[i] = CvtEnt{s, n, dst, mode, p0, p1};
    };
    ent(0,  d_in[0],  524288, OFF_X, 0, 0, 0);
    ent(1,  d_in[2],  8192,  HS_E1, 2, 128, 0);
    ent(2,  d_in[3],  128,   OFF_BIAS + BF_E1, 0, 0, 0);
    ent(3,  d_in[4],  16384, HS_E2, 2, 128, 0);
    ent(4,  d_in[5],  128,   OFF_BIAS + BF_E2, 0, 0, 0);
    ent(5,  d_in[6],  16384, HS_E3, 2, 128, 0);
    ent(6,  d_in[7],  128,   OFF_BIAS + BF_E3, 0, 0, 0);
    ent(7,  d_in[8],  8192,  HS_E4, 2, 64, 0);
    ent(8,  d_in[9],  64,    OFF_BIAS + BF_E4, 0, 0, 0);
    ent(9,  d_in[10], 8192,  HS_D1, 2, 128, 0);
    ent(10, d_in[11], 128,   OFF_BIAS + BF_D1, 0, 0, 0);
    ent(11, d_in[12], 16384, HS_D2, 2, 128, 0);
    ent(12, d_in[13], 128,   OFF_BIAS + BF_D2, 0, 0, 0);
    ent(13, d_in[14], 16384, HS_D3, 2, 128, 0);
    ent(14, d_in[15], 128,   OFF_BIAS + BF_D3, 0, 0, 0);
    ent(15, d_in[16], 8192,  HS_D4, 2, 64, 0);
    ent(16, d_in[17], 64,    OFF_BIAS + BF_D4, 0, 0, 0);
    ent(17, d_in[18], 12288, HS_AI, 3, 0, 192);
    ent(18, d_in[19], 192,   OFF_BIAS + BF_AI, 0, 0, 0);
    ent(19, d_in[20], 4096,  HS_AO, 3, 0, 64);
    ent(20, d_in[21], 64,    OFF_BIAS + BF_AO, 0, 0, 0);
    k_convert<<<dim3(2501), b256, 0, stream>>>(tab, fb, Wb, flagp);

    dim3 g256(256), g1024(1024), g2048(2048);

    // gemm1 consumes X, then scatter may overwrite X-region with ssrc weights (dsrc)
    k_mgemm<64, 128, 0><<<g256, b128, 0, stream>>>(Hx, Wb + HS_E1, nullptr, HD, nullptr);
    k_scatter<<<dim3(eb), b256, 0, stream>>>(ei, E, fill, ssrc, dis, dsrc);

    // encoder: x -> h1(HA) -> h2(HB) -> h3(HA) -> z(Hz + d_out)
    k_agg<<<g2048, b256, 0, stream>>>(HD, rowptr, ssrc, dsrc, dis, Bias + BF_E1, nullptr,
                                      HA, nullptr, 0, flagp, 128, 1);
    k_mgemm<128, 128, 0><<<g256, b128, 0, stream>>>(HA, Wb + HS_E2, nullptr, HD, nullptr);
    k_agg<<<g2048, b256, 0, stream>>>(HD, rowptr, ssrc, dsrc, dis, Bias + BF_E2, HA,
                                      HB, nullptr, 0, flagp, 128, 1);
    k_mgemm<128, 128, 0><<<g256, b128, 0, stream>>>(HB, Wb + HS_E3, nullptr, HD, nullptr);
    k_agg<<<g2048, b256, 0, stream>>>(HD, rowptr, ssrc, dsrc, dis, Bias + BF_E3, HB,
                                      HA, nullptr, 0, flagp, 128, 1);
    k_mgemm<128, 64, 0><<<g256, b128, 0, stream>>>(HA, Wb + HS_E4, nullptr, HD, nullptr);
    k_agg<<<g1024, b256, 0, stream>>>(HD, rowptr, ssrc, dsrc, dis, Bias + BF_E4, nullptr,
                                      Hz, d_out, 524288, flagp, 64, 0);

    // attention: qkv projection (Q scaled, V transposed); flash v4 writes Bo directly
    k_mgemm<64, 192, 2><<<g256, b128, 0, stream>>>(Hz, Wb + HS_AI, Bias + BF_AI, nullptr, Qkv);
    k_flash<<<g1024, dim3(512), 0, stream>>>(Qkv, Qkv + 524288, Qkv + 1048576, Bo);
    k_mgemm<64, 64, 0><<<g256, b128, 0, stream>>>(Bo, Wb + HS_AO, Bias + BF_AO, ZA, nullptr);

    // decoder: za -> g1(HA) -> g2(HB) -> g3(HA) -> x_recon(d_out)
    k_mgemm<64, 128, 0><<<g256, b128, 0, stream>>>(ZA, Wb + HS_D1, nullptr, HD, nullptr);
    k_agg<<<g2048, b256, 0, stream>>>(HD, rowptr, ssrc, dsrc, dis, Bias + BF_D1, nullptr,
                                      HA, nullptr, 0, flagp, 128, 1);
    k_mgemm<128, 128, 0><<<g256, b128, 0, stream>>>(HA, Wb + HS_D2, nullptr, HD, nullptr);
    k_agg<<<g2048, b256, 0, stream>>>(HD, rowptr, ssrc, dsrc, dis, Bias + BF_D2, HA,
                                      HB, nullptr, 0, flagp, 128, 1);
    k_mgemm<128, 128, 0><<<g256, b128, 0, stream>>>(HB, Wb + HS_D3, nullptr, HD, nullptr);
    k_agg<<<g2048, b256, 0, stream>>>(HD, rowptr, ssrc, dsrc, dis, Bias + BF_D3, HB,
                                      HA, nullptr, 0, flagp, 128, 1);
    k_mgemm<128, 64, 0><<<g256, b128, 0, stream>>>(HA, Wb + HS_D4, nullptr, HD, nullptr);
    k_agg<<<g1024, b256, 0, stream>>>(HD, rowptr, ssrc, dsrc, dis, Bias + BF_D4, nullptr,
                                      nullptr, d_out, 0, flagp, 64, 0);
}

// Round 10
// 388.413 us; speedup vs baseline: 3.2018x; 1.1890x over previous
//
#include <hip/hip_runtime.h>
#include <hip/hip_bf16.h>

using bf16 = __hip_bfloat16;

typedef __attribute__((ext_vector_type(8))) short bf16x8_t;   // 8 bf16 in 4 VGPRs
typedef __attribute__((ext_vector_type(4))) float f32x4_t;

static __device__ __forceinline__ float b2f(bf16 v) { return __bfloat162float(v); }

// pack two fp32 -> 2 bf16 (RNE)
static __device__ __forceinline__ unsigned pk(float a, float b) {
    unsigned ua = __float_as_uint(a); ua += 0x7FFFu + ((ua >> 16) & 1u);
    unsigned ub = __float_as_uint(b); ub += 0x7FFFu + ((ub >> 16) & 1u);
    return (ua >> 16) | (ub & 0xFFFF0000u);
}
static __device__ __forceinline__ float lo16f(unsigned u) { return __uint_as_float(u << 16); }
static __device__ __forceinline__ float hi16f(unsigned u) { return __uint_as_float(u & 0xFFFF0000u); }

// log2(e)/4 : folds 1/sqrt(DH) and exp->exp2. Applied at qkv GEMM output (fp32).
#define QSCALE 0.36067376022224085f

// ---------------- workspace layout (float offsets) ----------------
// ints: cnt[0,8192) rowptr[8192,16385) fill[16448,24640) ssrc[24640,286784) flag ib[286784]
#define OFF_DIS  286848
#define OFF_BIAS 295040   /* 1152 fp32 */
#define OFF_WB   296192   /* bf16 weights (split hi+lo), 229376 shorts = 114688 floats */
#define OFF_X    410880   /* fp32 x [8192,64]; dsrc (262144 f) aliases after gemm1 reads X */
#define OFF_HD   935168   /* fp32 gemm out [8192,128] */
#define OFF_HA   1983744  /* fp32 act [8192,128] */
#define OFF_HB   3032320  /* fp32 act [8192,128] */
#define OFF_HZ   4080896  /* fp32 z [8192,64] */
#define OFF_BO   4605184  /* fp32 attention out [8192,64] */
#define OFF_ZA   5129472  /* fp32 za [8192,64] */
#define OFF_QKV  5653760  /* bf16: Qb[8192*64] | Kb[8192*64] | VT[64*8192] = 786432 f slots */
// total 6440192 floats = 25.76 MB

// weight short-offsets (relative to OFF_WB as bf16*), each region hi plane then lo plane
#define HS_E1 0
#define HS_E2 16384
#define HS_E3 49152
#define HS_E4 81920
#define HS_D1 98304
#define HS_D2 114688
#define HS_D3 147456
#define HS_D4 180224
#define HS_AI 196608
#define HS_AO 221184

// bias fp32 offsets (relative to OFF_BIAS)
#define BF_E1 0
#define BF_E2 128
#define BF_E3 256
#define BF_E4 384
#define BF_D1 448
#define BF_D2 576
#define BF_D3 704
#define BF_D4 832
#define BF_AI 896
#define BF_AO 1088

// ---------------- dtype sniff (1 => inputs are fp32) ----------------
__global__ void k_sniff(const unsigned short* __restrict__ xb, int* __restrict__ flagp) {
    __shared__ int cnt;
    if (threadIdx.x == 0) cnt = 0;
    __syncthreads();
    unsigned short w = xb[threadIdx.x * 2];
    int e = (w >> 7) & 0xFF;
    int m = w & 0x7F;
    int weird = (e >= 134) || (e != 0 && e <= 90) || (e == 0 && m != 0);
    if (weird) atomicAdd(&cnt, 1);
    __syncthreads();
    if (threadIdx.x == 0) *flagp = (cnt >= 32) ? 1 : 0;
}

// ---------------- input canonicalization ----------------
// mode 0: fp32 -> fb[dst+i]
// mode 2: split weight swizzle from [K,dout=p0]: idx=((k>>3)*dout+n)*8+(k&7); lo at dst+n+idx
// mode 3: split weight transpose+swizzle from [rows,64]: k=i&63, n=i>>6, dout=p1; lo at dst+n+idx
struct CvtEnt { const void* src; int n; int dst; int mode; int p0; int p1; };
struct CvtTab { CvtEnt e[21]; };

__global__ void k_convert(CvtTab tab, float* __restrict__ fb, bf16* __restrict__ hb,
                          const int* __restrict__ flagp) {
    int i = blockIdx.x * blockDim.x + threadIdx.x;
    int fl = *flagp;
#pragma unroll 1
    for (int t = 0; t < 21; t++) {
        int n = tab.e[t].n;
        if (i < n) {
            float v = fl ? ((const float*)tab.e[t].src)[i]
                         : b2f(((const bf16*)tab.e[t].src)[i]);
            int mode = tab.e[t].mode, dst = tab.e[t].dst;
            if (mode == 0) {
                fb[dst + i] = v;
            } else {
                int idx;
                if (mode == 2) {
                    int dout = tab.e[t].p0;
                    int r = i / dout, c = i - r * dout;
                    idx = ((r >> 3) * dout + c) * 8 + (r & 7);
                } else {
                    int r = i >> 6, c = i & 63;       // r = n_eff, c = k_eff
                    idx = ((c >> 3) * tab.e[t].p1 + r) * 8 + (c & 7);
                }
                bf16 hv = __float2bfloat16(v);
                hb[dst + idx] = hv;
                hb[dst + n + idx] = __float2bfloat16(v - b2f(hv));
            }
            return;
        }
        i -= n;
    }
}

// ---------------- CSR construction ----------------
__global__ void k_zero_int(int* __restrict__ p, int n) {
    int i = blockIdx.x * blockDim.x + threadIdx.x;
    if (i < n) p[i] = 0;
}

__global__ void k_count(const int* __restrict__ ei, int E, int* __restrict__ cnt) {
    int e = blockIdx.x * blockDim.x + threadIdx.x;
    if (e < E) atomicAdd(&cnt[ei[E + e]], 1);
}

__global__ void k_scan(const int* __restrict__ cnt, int* __restrict__ rowptr,
                       int* __restrict__ fill, float* __restrict__ dis) {
    __shared__ int sums[256];
    int t = threadIdx.x;
    int base = t * 32;
    int s = 0;
#pragma unroll
    for (int i = 0; i < 32; i++) s += cnt[base + i];
    sums[t] = s;
    __syncthreads();
    for (int off = 1; off < 256; off <<= 1) {
        int v = (t >= off) ? sums[t - off] : 0;
        __syncthreads();
        sums[t] += v;
        __syncthreads();
    }
    int run = (t == 0) ? 0 : sums[t - 1];
#pragma unroll
    for (int i = 0; i < 32; i++) {
        int idx = base + i;
        rowptr[idx] = run;
        fill[idx] = run;
        dis[idx] = rsqrtf((float)(cnt[idx] + 1));
        run += cnt[idx];
    }
    if (t == 255) rowptr[8192] = run;
}

// scatter also records dsrc[pos] = dis[src] so agg needs no dependent gather
__global__ void k_scatter(const int* __restrict__ ei, int E,
                          int* __restrict__ fill, int* __restrict__ ssrc,
                          const float* __restrict__ dis, float* __restrict__ dsrc) {
    int e = blockIdx.x * blockDim.x + threadIdx.x;
    if (e < E) {
        int s = ei[e];
        int pos = atomicAdd(&fill[ei[E + e]], 1);
        ssrc[pos] = s;
        dsrc[pos] = dis[s];
    }
}

// ---------------- MFMA GEMM: fp32 A (in-register hi/lo split) x split-bf16 W ----------------
// 3 MFMAs/tile: ah*wh + al*wh + ah*wl  (al*wl ~ 2^-18, dropped).
// Col-split waves: wave = (row-group, col-half) -> 1024 waves (4/CU); bit-identical outputs.
// OMODE: 0 -> fp32 outF; 2 -> qkv projection: Q (scaled, [8192,64]) | K [8192,64] | VT [64,8192]
template<int K, int DOUT, int OMODE>
__global__ void __launch_bounds__(128) k_mgemm(const float* __restrict__ A,
                                               const bf16* __restrict__ Wb,
                                               const float* __restrict__ bias,
                                               float* __restrict__ outF,
                                               bf16* __restrict__ outH) {
    constexpr int NCT = DOUT / 32, NKS = K / 32;
    constexpr int WPL = K * DOUT;
    int w = threadIdx.x >> 6, lane = threadIdx.x & 63;
    int lo = lane & 15, g = lane >> 4;
    int wg = blockIdx.x * 2 + w;           // [0,1024)
    int r0 = (wg >> 1) * 16;
    int c0 = (wg & 1) * (DOUT / 2);
    const f32x4_t Z = {0.f, 0.f, 0.f, 0.f};
    f32x4_t acc[NCT];
#pragma unroll
    for (int ct = 0; ct < NCT; ct++) acc[ct] = Z;
#pragma unroll
    for (int kk = 0; kk < NKS; kk++) {
        const float* ap = A + (size_t)(r0 + lo) * K + kk * 32 + g * 8;
        float4 x0 = *(const float4*)ap;
        float4 x1 = *(const float4*)(ap + 4);
        union { unsigned u[4]; bf16x8_t v; } ah, al;
        ah.u[0] = pk(x0.x, x0.y);
        ah.u[1] = pk(x0.z, x0.w);
        ah.u[2] = pk(x1.x, x1.y);
        ah.u[3] = pk(x1.z, x1.w);
        al.u[0] = pk(x0.x - lo16f(ah.u[0]), x0.y - hi16f(ah.u[0]));
        al.u[1] = pk(x0.z - lo16f(ah.u[1]), x0.w - hi16f(ah.u[1]));
        al.u[2] = pk(x1.x - lo16f(ah.u[2]), x1.y - hi16f(ah.u[2]));
        al.u[3] = pk(x1.z - lo16f(ah.u[3]), x1.w - hi16f(ah.u[3]));
#pragma unroll
        for (int ct = 0; ct < NCT; ct++) {
            size_t wi = (size_t)((kk * 4 + g) * DOUT + c0 + ct * 16 + lo) * 8;
            bf16x8_t wh = *(const bf16x8_t*)(Wb + wi);
            bf16x8_t wl = *(const bf16x8_t*)(Wb + WPL + wi);
            acc[ct] = __builtin_amdgcn_mfma_f32_16x16x32_bf16(ah.v, wh, acc[ct], 0, 0, 0);
            acc[ct] = __builtin_amdgcn_mfma_f32_16x16x32_bf16(al.v, wh, acc[ct], 0, 0, 0);
            acc[ct] = __builtin_amdgcn_mfma_f32_16x16x32_bf16(ah.v, wl, acc[ct], 0, 0, 0);
        }
    }
#pragma unroll
    for (int ct = 0; ct < NCT; ct++) {
        int n = c0 + ct * 16 + lo;
        float bs = bias ? bias[n] : 0.f;
#pragma unroll
        for (int r = 0; r < 4; r++) {
            float v = acc[ct][r] + bs;
            int node = r0 + 4 * g + r;
            if (OMODE == 0) {
                outF[(size_t)node * DOUT + n] = v;
            } else {
                if (n < 64) {
                    outH[(size_t)node * 64 + n] = __float2bfloat16(v * QSCALE);
                } else if (n < 128) {
                    outH[524288 + (size_t)node * 64 + (n - 64)] = __float2bfloat16(v);
                } else {
                    outH[1048576 + (size_t)(n - 128) * 8192 + node] = __float2bfloat16(v);
                }
            }
        }
    }
}

// ---------------- GCN aggregation v3: 4 parallel edge streams per node ----------------
// DOUT=128: LPR=32 (float4 x 32 lanes = row), 2 groups/wave, 2 waves/node, 2 nodes/block.
// DOUT=64 : LPR=16, 4 groups/wave, 1 wave/node, 4 nodes/block.
// Stream s takes edges e0+s, e0+s+4, ... ; partials combined via LDS in fixed order.
template<int DOUT>
__global__ void __launch_bounds__(256) k_agg(const float* __restrict__ hd,
                      const int* __restrict__ rowptr,
                      const int* __restrict__ ssrc, const float* __restrict__ dsrc,
                      const float* __restrict__ dis,
                      const float* __restrict__ bias, const float* __restrict__ resid,
                      float* __restrict__ outF, void* __restrict__ outAny, int outOff,
                      const int* __restrict__ flagp, int relu) {
    constexpr int LPR = DOUT / 4;          // lanes per row-group
    constexpr int GPW = 64 / LPR;          // groups per wave
    constexpr int WPN = 4 / GPW;           // waves per node
    constexpr int NPB = 4 / WPN;           // nodes per block
    __shared__ float red[NPB][4][DOUT];

    int w = threadIdx.x >> 6;
    int lane = threadIdx.x & 63;
    int g = lane / LPR;
    int fl = (lane % LPR) * 4;
    int nl = w / WPN;
    int s = (w % WPN) * GPW + g;
    int node = blockIdx.x * NPB + nl;

    float di = dis[node];
    int e0 = rowptr[node], e1 = rowptr[node + 1];
    float4 acc = {0.f, 0.f, 0.f, 0.f};
    int e = e0 + s;
    for (; e + 12 < e1; e += 16) {
        int s0 = ssrc[e], s1 = ssrc[e + 4], s2 = ssrc[e + 8], s3 = ssrc[e + 12];
        float w0 = dsrc[e] * di, w1 = dsrc[e + 4] * di;
        float w2 = dsrc[e + 8] * di, w3 = dsrc[e + 12] * di;
        float4 v0 = *(const float4*)(hd + (size_t)s0 * DOUT + fl);
        float4 v1 = *(const float4*)(hd + (size_t)s1 * DOUT + fl);
        float4 v2 = *(const float4*)(hd + (size_t)s2 * DOUT + fl);
        float4 v3 = *(const float4*)(hd + (size_t)s3 * DOUT + fl);
        acc.x += v0.x * w0; acc.y += v0.y * w0; acc.z += v0.z * w0; acc.w += v0.w * w0;
        acc.x += v1.x * w1; acc.y += v1.y * w1; acc.z += v1.z * w1; acc.w += v1.w * w1;
        acc.x += v2.x * w2; acc.y += v2.y * w2; acc.z += v2.z * w2; acc.w += v2.w * w2;
        acc.x += v3.x * w3; acc.y += v3.y * w3; acc.z += v3.z * w3; acc.w += v3.w * w3;
    }
    for (; e < e1; e += 4) {
        int sv = ssrc[e];
        float wgt = dsrc[e] * di;
        float4 v = *(const float4*)(hd + (size_t)sv * DOUT + fl);
        acc.x += v.x * wgt; acc.y += v.y * wgt; acc.z += v.z * wgt; acc.w += v.w * wgt;
    }
    *(float4*)&red[nl][s][fl] = acc;
    __syncthreads();

    // epilogue: thread per feature (NPB*DOUT == 256)
    int tid = threadIdx.x;
    int nl2 = tid / DOUT;
    int f = tid % DOUT;
    int node2 = blockIdx.x * NPB + nl2;
    float di2 = dis[node2];
    float a = hd[(size_t)node2 * DOUT + f] * (di2 * di2);
    a += (red[nl2][0][f] + red[nl2][1][f]) + (red[nl2][2][f] + red[nl2][3][f]);
    a += bias[f];
    if (relu) a = fmaxf(a, 0.f);
    if (resid) a += resid[(size_t)node2 * DOUT + f];
    size_t o = (size_t)node2 * DOUT + f;
    if (outF) outF[o] = a;
    if (outAny) {
        if (*flagp) ((float*)outAny)[(size_t)outOff + o] = a;
        else        ((bf16*)outAny)[(size_t)outOff + o] = __float2bfloat16(a);
    }
}

// ---------------- MFMA flash attention v4 (R9-proven) ----------------
__global__ void __launch_bounds__(512)
k_flash(const bf16* __restrict__ Qb, const bf16* __restrict__ Kb,
        const bf16* __restrict__ VT, float* __restrict__ Bo) {
    __shared__ unsigned short plds[8][2][16][40];
    __shared__ float redo[8][2][16][16];
    __shared__ float redl[8][2][16];
    int w = threadIdx.x >> 6;
    int lane = threadIdx.x & 63;
    int lo = lane & 15;
    int g = lane >> 4;
    int qt = blockIdx.x & 255;
    int h = blockIdx.x >> 8;
    int q0 = qt * 32;
    int m0base = w * 1024;

    const f32x4_t Z = {0.f, 0.f, 0.f, 0.f};
    bf16x8_t zf;
#pragma unroll
    for (int i = 0; i < 8; i++) zf[i] = 0;

    bf16x8_t qf[2];
#pragma unroll
    for (int s = 0; s < 2; s++) {
        if (g < 2) qf[s] = *(const bf16x8_t*)(Qb + (size_t)(q0 + s * 16 + lo) * 64 + h * 16 + g * 8);
        else       qf[s] = zf;
    }

    f32x4_t oacc[2] = {Z, Z};
    float lr[2] = {0.f, 0.f};
    const bf16* kbase = Kb + h * 16 + g * 8;
    const bf16* vbase = VT + (size_t)(h * 16 + lo) * 8192;

    for (int t = 0; t < 32; t++) {
        int m0 = m0base + t * 32;
        bf16x8_t kf0 = zf, kf1 = zf;
        if (g < 2) {
            kf0 = *(const bf16x8_t*)(kbase + (size_t)m0 * 64);
            kf1 = *(const bf16x8_t*)(kbase + (size_t)(m0 + 16) * 64);
        }
        bf16x8_t vt = *(const bf16x8_t*)(vbase + m0 + 8 * g);
#pragma unroll
        for (int s = 0; s < 2; s++) {
            f32x4_t s0 = __builtin_amdgcn_mfma_f32_16x16x32_bf16(kf0, qf[s], Z, 0, 0, 0);
            f32x4_t s1 = __builtin_amdgcn_mfma_f32_16x16x32_bf16(kf1, qf[s], Z, 0, 0, 0);
            float p0 = __builtin_amdgcn_exp2f(s0[0]);
            float p1 = __builtin_amdgcn_exp2f(s0[1]);
            float p2 = __builtin_amdgcn_exp2f(s0[2]);
            float p3 = __builtin_amdgcn_exp2f(s0[3]);
            float p4 = __builtin_amdgcn_exp2f(s1[0]);
            float p5 = __builtin_amdgcn_exp2f(s1[1]);
            float p6 = __builtin_amdgcn_exp2f(s1[2]);
            float p7 = __builtin_amdgcn_exp2f(s1[3]);
            lr[s] += (((p0 + p1) + (p2 + p3)) + ((p4 + p5) + (p6 + p7)));
            unsigned* dst0 = (unsigned*)&plds[w][s][lo][4 * g];
            dst0[0] = pk(p0, p1);
            dst0[1] = pk(p2, p3);
            unsigned* dst1 = (unsigned*)&plds[w][s][lo][16 + 4 * g];
            dst1[0] = pk(p4, p5);
            dst1[1] = pk(p6, p7);
            bf16x8_t pf = *(const bf16x8_t*)&plds[w][s][lo][8 * g];
            oacc[s] = __builtin_amdgcn_mfma_f32_16x16x32_bf16(vt, pf, oacc[s], 0, 0, 0);
        }
    }
#pragma unroll
    for (int s = 0; s < 2; s++) {
        float l = lr[s];
        l += __shfl_xor(l, 16);
        l += __shfl_xor(l, 32);
        *(f32x4_t*)&redo[w][s][lo][4 * g] = oacc[s];
        if (g == 0) redl[w][s][lo] = l;
    }
    __syncthreads();
    int tid = threadIdx.x;
    int s2 = tid >> 8, q2 = (tid >> 4) & 15, d2 = tid & 15;
    float o = 0.f, l = 0.f;
#pragma unroll
    for (int ww = 0; ww < 8; ww++) {
        o += redo[ww][s2][q2][d2];
        l += redl[ww][s2][q2];
    }
    Bo[(size_t)(q0 + s2 * 16 + q2) * 64 + h * 16 + d2] = o / l;
}

// ---------------- launch ----------------
extern "C" void kernel_launch(void* const* d_in, const int* in_sizes, int n_in,
                              void* d_out, int out_size, void* d_ws, size_t ws_size,
                              hipStream_t stream) {
    int E = in_sizes[1] / 2;
    const int* ei = (const int*)d_in[1];

    int*   ib = (int*)d_ws;
    float* fb = (float*)d_ws;
    int* cnt    = ib;
    int* rowptr = ib + 8192;
    int* fill   = ib + 16448;
    int* ssrc   = ib + 24640;
    int* flagp  = ib + 286784;
    float* dis  = fb + OFF_DIS;
    float* Bias = fb + OFF_BIAS;
    bf16*  Wb   = (bf16*)(fb + OFF_WB);
    float* Hx   = fb + OFF_X;
    float* dsrc = fb + OFF_X;     // aliases X; written by scatter AFTER gemm1 consumed X
    float* HD   = fb + OFF_HD;
    float* HA   = fb + OFF_HA;
    float* HB   = fb + OFF_HB;
    float* Hz   = fb + OFF_HZ;
    float* Bo   = fb + OFF_BO;
    float* ZA   = fb + OFF_ZA;
    bf16*  Qkv  = (bf16*)(fb + OFF_QKV);   // Qb | Kb(+524288) | VT(+1048576)

    dim3 b256(256), b128(128);
    int eb = (E + 255) / 256;

    k_sniff<<<dim3(1), b256, 0, stream>>>((const unsigned short*)d_in[0], flagp);
    k_zero_int<<<dim3(32), b256, 0, stream>>>(cnt, 8192);
    k_count<<<dim3(eb), b256, 0, stream>>>(ei, E, cnt);
    k_scan<<<dim3(1), b256, 0, stream>>>(cnt, rowptr, fill, dis);

    CvtTab tab;
    auto ent = [&](int i, const void* s, int n, int dst, int mode, int p0, int p1) {
        tab.e[i] = CvtEnt{s, n, dst, mode, p0, p1};
    };
    ent(0,  d_in[0],  524288, OFF_X, 0, 0, 0);
    ent(1,  d_in[2],  8192,  HS_E1, 2, 128, 0);
    ent(2,  d_in[3],  128,   OFF_BIAS + BF_E1, 0, 0, 0);
    ent(3,  d_in[4],  16384, HS_E2, 2, 128, 0);
    ent(4,  d_in[5],  128,   OFF_BIAS + BF_E2, 0, 0, 0);
    ent(5,  d_in[6],  16384, HS_E3, 2, 128, 0);
    ent(6,  d_in[7],  128,   OFF_BIAS + BF_E3, 0, 0, 0);
    ent(7,  d_in[8],  8192,  HS_E4, 2, 64, 0);
    ent(8,  d_in[9],  64,    OFF_BIAS + BF_E4, 0, 0, 0);
    ent(9,  d_in[10], 8192,  HS_D1, 2, 128, 0);
    ent(10, d_in[11], 128,   OFF_BIAS + BF_D1, 0, 0, 0);
    ent(11, d_in[12], 16384, HS_D2, 2, 128, 0);
    ent(12, d_in[13], 128,   OFF_BIAS + BF_D2, 0, 0, 0);
    ent(13, d_in[14], 16384, HS_D3, 2, 128, 0);
    ent(14, d_in[15], 128,   OFF_BIAS + BF_D3, 0, 0, 0);
    ent(15, d_in[16], 8192,  HS_D4, 2, 64, 0);
    ent(16, d_in[17], 64,    OFF_BIAS + BF_D4, 0, 0, 0);
    ent(17, d_in[18], 12288, HS_AI, 3, 0, 192);
    ent(18, d_in[19], 192,   OFF_BIAS + BF_AI, 0, 0, 0);
    ent(19, d_in[20], 4096,  HS_AO, 3, 0, 64);
    ent(20, d_in[21], 64,    OFF_BIAS + BF_AO, 0, 0, 0);
    k_convert<<<dim3(2501), b256, 0, stream>>>(tab, fb, Wb, flagp);

    dim3 g512(512), g1024(1024), g2048(2048), g4096(4096);

    // gemm1 consumes X, then scatter overwrites X-region with edge weights (dsrc)
    k_mgemm<64, 128, 0><<<g512, b128, 0, stream>>>(Hx, Wb + HS_E1, nullptr, HD, nullptr);
    k_scatter<<<dim3(eb), b256, 0, stream>>>(ei, E, fill, ssrc, dis, dsrc);

    // encoder: x -> h1(HA) -> h2(HB) -> h3(HA) -> z(Hz + d_out)
    k_agg<128><<<g4096, b256, 0, stream>>>(HD, rowptr, ssrc, dsrc, dis, Bias + BF_E1, nullptr,
                                           HA, nullptr, 0, flagp, 1);
    k_mgemm<128, 128, 0><<<g512, b128, 0, stream>>>(HA, Wb + HS_E2, nullptr, HD, nullptr);
    k_agg<128><<<g4096, b256, 0, stream>>>(HD, rowptr, ssrc, dsrc, dis, Bias + BF_E2, HA,
                                           HB, nullptr, 0, flagp, 1);
    k_mgemm<128, 128, 0><<<g512, b128, 0, stream>>>(HB, Wb + HS_E3, nullptr, HD, nullptr);
    k_agg<128><<<g4096, b256, 0, stream>>>(HD, rowptr, ssrc, dsrc, dis, Bias + BF_E3, HB,
                                           HA, nullptr, 0, flagp, 1);
    k_mgemm<128, 64, 0><<<g512, b128, 0, stream>>>(HA, Wb + HS_E4, nullptr, HD, nullptr);
    k_agg<64><<<g2048, b256, 0, stream>>>(HD, rowptr, ssrc, dsrc, dis, Bias + BF_E4, nullptr,
                                          Hz, d_out, 524288, flagp, 0);

    // attention: qkv projection (Q scaled, V transposed); flash v4 writes Bo directly
    k_mgemm<64, 192, 2><<<g512, b128, 0, stream>>>(Hz, Wb + HS_AI, Bias + BF_AI, nullptr, Qkv);
    k_flash<<<g1024, dim3(512), 0, stream>>>(Qkv, Qkv + 524288, Qkv + 1048576, Bo);
    k_mgemm<64, 64, 0><<<g512, b128, 0, stream>>>(Bo, Wb + HS_AO, Bias + BF_AO, ZA, nullptr);

    // decoder: za -> g1(HA) -> g2(HB) -> g3(HA) -> x_recon(d_out)
    k_mgemm<64, 128, 0><<<g512, b128, 0, stream>>>(ZA, Wb + HS_D1, nullptr, HD, nullptr);
    k_agg<128><<<g4096, b256, 0, stream>>>(HD, rowptr, ssrc, dsrc, dis, Bias + BF_D1, nullptr,
                                           HA, nullptr, 0, flagp, 1);
    k_mgemm<128, 128, 0><<<g512, b128, 0, stream>>>(HA, Wb + HS_D2, nullptr, HD, nullptr);
    k_agg<128><<<g4096, b256, 0, stream>>>(HD, rowptr, ssrc, dsrc, dis, Bias + BF_D2, HA,
                                           HB, nullptr, 0, flagp, 1);
    k_mgemm<128, 128, 0><<<g512, b128, 0, stream>>>(HB, Wb + HS_D3, nullptr, HD, nullptr);
    k_agg<128><<<g4096, b256, 0, stream>>>(HD, rowptr, ssrc, dsrc, dis, Bias + BF_D3, HB,
                                           HA, nullptr, 0, flagp, 1);
    k_mgemm<128, 64, 0><<<g512, b128, 0, stream>>>(HA, Wb + HS_D4, nullptr, HD, nullptr);
    k_agg<64><<<g2048, b256, 0, stream>>>(HD, rowptr, ssrc, dsrc, dis, Bias + BF_D4, nullptr,
                                          nullptr, d_out, 0, flagp, 0);
}

// Round 11
// 380.350 us; speedup vs baseline: 3.2697x; 1.0212x over previous
//
#include <hip/hip_runtime.h>
#include <hip/hip_bf16.h>

using bf16 = __hip_bfloat16;

typedef __attribute__((ext_vector_type(8))) short bf16x8_t;   // 8 bf16 in 4 VGPRs
typedef __attribute__((ext_vector_type(4))) float f32x4_t;

static __device__ __forceinline__ float b2f(bf16 v) { return __bfloat162float(v); }

// pack two fp32 -> 2 bf16 (RNE) via v_cvt_pk_bf16_f32 when available
static __device__ __forceinline__ unsigned pk2(float a, float b) {
    __hip_bfloat162 h = __float22bfloat162_rn(make_float2(a, b));
    return *reinterpret_cast<unsigned*>(&h);
}
static __device__ __forceinline__ float lo16f(unsigned u) { return __uint_as_float(u << 16); }
static __device__ __forceinline__ float hi16f(unsigned u) { return __uint_as_float(u & 0xFFFF0000u); }

// log2(e)/4 : folds 1/sqrt(DH) and exp->exp2. Applied at qkv GEMM output (fp32).
#define QSCALE 0.36067376022224085f

// ---------------- workspace layout (float offsets) ----------------
// ints: cnt[0,8192) rowptr[8192,16385) fill[16448,24640) ssrc[24640,286784) flag ib[286784]
#define OFF_DIS  286848
#define OFF_BIAS 295040   /* 1152 fp32 */
#define OFF_WB   296192   /* bf16 weights (split hi+lo), 229376 shorts = 114688 floats */
#define OFF_DSRC 410880   /* fp32 edge weights [262144] */
#define OFF_HD   935168   /* fp32 gemm/agg staging [8192,128]; XA/ZAg use first half */
#define OFF_HA   1983744  /* fp32 act [8192,128] */
#define OFF_HB   3032320  /* fp32 act [8192,128]; X [8192,64] lives in first half early */
#define OFF_HZ   4080896  /* fp32 z [8192,64] */
#define OFF_BO   4605184  /* fp32 attention out [8192,64] */
#define OFF_ZA   5129472  /* fp32 za [8192,64] */
#define OFF_QKV  5653760  /* bf16: Qb[8192*64] | Kb[8192*64] | VT[64*8192] = 786432 f slots */
// total 6440192 floats = 25.76 MB

// weight short-offsets (relative to OFF_WB as bf16*), each region hi plane then lo plane
#define HS_E1 0
#define HS_E2 16384
#define HS_E3 49152
#define HS_E4 81920
#define HS_D1 98304
#define HS_D2 114688
#define HS_D3 147456
#define HS_D4 180224
#define HS_AI 196608
#define HS_AO 221184

// bias fp32 offsets (relative to OFF_BIAS)
#define BF_E1 0
#define BF_E2 128
#define BF_E3 256
#define BF_E4 384
#define BF_D1 448
#define BF_D2 576
#define BF_D3 704
#define BF_D4 832
#define BF_AI 896
#define BF_AO 1088

// ---------------- input canonicalization (sniff fused) ----------------
// mode 0: fp32 -> fb[dst+i]
// mode 2: split weight swizzle from [K,dout=p0]: idx=((k>>3)*dout+n)*8+(k&7); lo at dst+n+idx
// mode 3: split weight transpose+swizzle from [rows,64]: k=i&63, n=i>>6, dout=p1; lo at dst+n+idx
struct CvtEnt { const void* src; int n; int dst; int mode; int p0; int p1; };
struct CvtTab { CvtEnt e[21]; };

__global__ void k_convert(CvtTab tab, float* __restrict__ fb, bf16* __restrict__ hb,
                          int* __restrict__ flagp, const unsigned short* __restrict__ xb) {
    __shared__ int wsum[4];
    // inline dtype sniff: every block computes the flag from x's first 1KB
    unsigned short wv = xb[threadIdx.x * 2];
    int ex = (wv >> 7) & 0xFF;
    int mn = wv & 0x7F;
    int weird = (ex >= 134) || (ex != 0 && ex <= 90) || (ex == 0 && mn != 0);
    unsigned long long bal = __ballot(weird);
    if ((threadIdx.x & 63) == 0) wsum[threadIdx.x >> 6] = (int)__popcll(bal);
    __syncthreads();
    int fl = ((wsum[0] + wsum[1]) + (wsum[2] + wsum[3])) >= 32 ? 1 : 0;   // 1 => fp32
    if (blockIdx.x == 0 && threadIdx.x == 0) *flagp = fl;

    int i = blockIdx.x * blockDim.x + threadIdx.x;
#pragma unroll 1
    for (int t = 0; t < 21; t++) {
        int n = tab.e[t].n;
        if (i < n) {
            float v = fl ? ((const float*)tab.e[t].src)[i]
                         : b2f(((const bf16*)tab.e[t].src)[i]);
            int mode = tab.e[t].mode, dst = tab.e[t].dst;
            if (mode == 0) {
                fb[dst + i] = v;
            } else {
                int idx;
                if (mode == 2) {
                    int dout = tab.e[t].p0;
                    int r = i / dout, c = i - r * dout;
                    idx = ((r >> 3) * dout + c) * 8 + (r & 7);
                } else {
                    int r = i >> 6, c = i & 63;       // r = n_eff, c = k_eff
                    idx = ((c >> 3) * tab.e[t].p1 + r) * 8 + (c & 7);
                }
                bf16 hv = __float2bfloat16(v);
                hb[dst + idx] = hv;
                hb[dst + n + idx] = __float2bfloat16(v - b2f(hv));
            }
            return;
        }
        i -= n;
    }
}

// ---------------- CSR construction ----------------
__global__ void k_zero_int(int* __restrict__ p, int n) {
    int i = blockIdx.x * blockDim.x + threadIdx.x;
    if (i < n) p[i] = 0;
}

__global__ void k_count(const int* __restrict__ ei, int E, int* __restrict__ cnt) {
    int e = blockIdx.x * blockDim.x + threadIdx.x;
    if (e < E) atomicAdd(&cnt[ei[E + e]], 1);
}

__global__ void k_scan(const int* __restrict__ cnt, int* __restrict__ rowptr,
                       int* __restrict__ fill, float* __restrict__ dis) {
    __shared__ int sums[256];
    int t = threadIdx.x;
    int base = t * 32;
    int s = 0;
#pragma unroll
    for (int i = 0; i < 32; i++) s += cnt[base + i];
    sums[t] = s;
    __syncthreads();
    for (int off = 1; off < 256; off <<= 1) {
        int v = (t >= off) ? sums[t - off] : 0;
        __syncthreads();
        sums[t] += v;
        __syncthreads();
    }
    int run = (t == 0) ? 0 : sums[t - 1];
#pragma unroll
    for (int i = 0; i < 32; i++) {
        int idx = base + i;
        rowptr[idx] = run;
        fill[idx] = run;
        dis[idx] = rsqrtf((float)(cnt[idx] + 1));
        run += cnt[idx];
    }
    if (t == 255) rowptr[8192] = run;
}

__global__ void k_scatter(const int* __restrict__ ei, int E,
                          int* __restrict__ fill, int* __restrict__ ssrc,
                          const float* __restrict__ dis, float* __restrict__ dsrc) {
    int e = blockIdx.x * blockDim.x + threadIdx.x;
    if (e < E) {
        int s = ei[e];
        int pos = atomicAdd(&fill[ei[E + e]], 1);
        ssrc[pos] = s;
        dsrc[pos] = dis[s];
    }
}

// ---------------- MFMA GEMM: fp32 A (in-register hi/lo split) x split-bf16 W ----------------
// 3 MFMAs/tile: ah*wh + al*wh + ah*wl  (al*wl ~ 2^-18, dropped).
// OMODE: 0 -> fp32 out (+bias if given); 1 -> fp32 out + bias + relu;
//        2 -> qkv: Q (scaled, [8192,64]) | K [8192,64] | VT [64,8192]
template<int K, int DOUT, int OMODE>
__global__ void __launch_bounds__(128) k_mgemm(const float* __restrict__ A,
                                               const bf16* __restrict__ Wb,
                                               const float* __restrict__ bias,
                                               float* __restrict__ outF,
                                               bf16* __restrict__ outH) {
    constexpr int NCT = DOUT / 32, NKS = K / 32;
    constexpr int WPL = K * DOUT;
    int w = threadIdx.x >> 6, lane = threadIdx.x & 63;
    int lo = lane & 15, g = lane >> 4;
    int wg = blockIdx.x * 2 + w;           // [0,1024)
    int r0 = (wg >> 1) * 16;
    int c0 = (wg & 1) * (DOUT / 2);
    const f32x4_t Z = {0.f, 0.f, 0.f, 0.f};
    f32x4_t acc[NCT];
#pragma unroll
    for (int ct = 0; ct < NCT; ct++) acc[ct] = Z;
#pragma unroll
    for (int kk = 0; kk < NKS; kk++) {
        const float* ap = A + (size_t)(r0 + lo) * K + kk * 32 + g * 8;
        float4 x0 = *(const float4*)ap;
        float4 x1 = *(const float4*)(ap + 4);
        union { unsigned u[4]; bf16x8_t v; } ah, al;
        ah.u[0] = pk2(x0.x, x0.y);
        ah.u[1] = pk2(x0.z, x0.w);
        ah.u[2] = pk2(x1.x, x1.y);
        ah.u[3] = pk2(x1.z, x1.w);
        al.u[0] = pk2(x0.x - lo16f(ah.u[0]), x0.y - hi16f(ah.u[0]));
        al.u[1] = pk2(x0.z - lo16f(ah.u[1]), x0.w - hi16f(ah.u[1]));
        al.u[2] = pk2(x1.x - lo16f(ah.u[2]), x1.y - hi16f(ah.u[2]));
        al.u[3] = pk2(x1.z - lo16f(ah.u[3]), x1.w - hi16f(ah.u[3]));
#pragma unroll
        for (int ct = 0; ct < NCT; ct++) {
            size_t wi = (size_t)((kk * 4 + g) * DOUT + c0 + ct * 16 + lo) * 8;
            bf16x8_t wh = *(const bf16x8_t*)(Wb + wi);
            bf16x8_t wl = *(const bf16x8_t*)(Wb + WPL + wi);
            acc[ct] = __builtin_amdgcn_mfma_f32_16x16x32_bf16(ah.v, wh, acc[ct], 0, 0, 0);
            acc[ct] = __builtin_amdgcn_mfma_f32_16x16x32_bf16(al.v, wh, acc[ct], 0, 0, 0);
            acc[ct] = __builtin_amdgcn_mfma_f32_16x16x32_bf16(ah.v, wl, acc[ct], 0, 0, 0);
        }
    }
#pragma unroll
    for (int ct = 0; ct < NCT; ct++) {
        int n = c0 + ct * 16 + lo;
        float bs = (OMODE != 2 && bias) ? bias[n] : (OMODE == 2 ? bias[n] : 0.f);
#pragma unroll
        for (int r = 0; r < 4; r++) {
            float v = acc[ct][r] + bs;
            int node = r0 + 4 * g + r;
            if (OMODE == 0) {
                outF[(size_t)node * DOUT + n] = v;
            } else if (OMODE == 1) {
                outF[(size_t)node * DOUT + n] = fmaxf(v, 0.f);
            } else {
                if (n < 64) {
                    outH[(size_t)node * 64 + n] = __float2bfloat16(v * QSCALE);
                } else if (n < 128) {
                    outH[524288 + (size_t)node * 64 + (n - 64)] = __float2bfloat16(v);
                } else {
                    outH[1048576 + (size_t)(n - 128) * 8192 + node] = __float2bfloat16(v);
                }
            }
        }
    }
}

// ---------------- GCN aggregation v4: 8 parallel edge streams per node ----------------
// 512-thr blocks. DOUT=128: LPR=32, 2 grp/wave, 4 waves/node, 2 nodes/block (grid 4096).
// DOUT=64 : LPR=16, 4 grp/wave, 2 waves/node, 4 nodes/block (grid 2048).
template<int DOUT>
__global__ void __launch_bounds__(512) k_agg(const float* __restrict__ hd,
                      const int* __restrict__ rowptr,
                      const int* __restrict__ ssrc, const float* __restrict__ dsrc,
                      const float* __restrict__ dis,
                      const float* __restrict__ bias, const float* __restrict__ resid,
                      float* __restrict__ outF, void* __restrict__ outAny, int outOff,
                      const int* __restrict__ flagp, int relu) {
    constexpr int LPR = DOUT / 4;
    constexpr int GPW = 64 / LPR;
    constexpr int NST = 8;
    constexpr int WPN = NST / GPW;
    constexpr int NPB = 8 / WPN;
    __shared__ float red[NPB][NST][DOUT];

    int w = threadIdx.x >> 6;
    int lane = threadIdx.x & 63;
    int g = lane / LPR;
    int fl4 = (lane % LPR) * 4;
    int nl = w / WPN;
    int s = (w % WPN) * GPW + g;
    int node = blockIdx.x * NPB + nl;

    float di = dis[node];
    int e0 = rowptr[node], e1 = rowptr[node + 1];
    float4 acc = {0.f, 0.f, 0.f, 0.f};
    int e = e0 + s;
    for (; e + NST < e1; e += 2 * NST) {
        int s0 = ssrc[e], s1 = ssrc[e + NST];
        float w0 = dsrc[e] * di, w1 = dsrc[e + NST] * di;
        float4 v0 = *(const float4*)(hd + (size_t)s0 * DOUT + fl4);
        float4 v1 = *(const float4*)(hd + (size_t)s1 * DOUT + fl4);
        acc.x += v0.x * w0; acc.y += v0.y * w0; acc.z += v0.z * w0; acc.w += v0.w * w0;
        acc.x += v1.x * w1; acc.y += v1.y * w1; acc.z += v1.z * w1; acc.w += v1.w * w1;
    }
    for (; e < e1; e += NST) {
        int sv = ssrc[e];
        float wgt = dsrc[e] * di;
        float4 v = *(const float4*)(hd + (size_t)sv * DOUT + fl4);
        acc.x += v.x * wgt; acc.y += v.y * wgt; acc.z += v.z * wgt; acc.w += v.w * wgt;
    }
    *(float4*)&red[nl][s][fl4] = acc;
    __syncthreads();

    int tid = threadIdx.x;
    if (tid < NPB * DOUT) {
        int nl2 = tid / DOUT;
        int f = tid % DOUT;
        int node2 = blockIdx.x * NPB + nl2;
        float di2 = dis[node2];
        float a = hd[(size_t)node2 * DOUT + f] * (di2 * di2);
        a += ((red[nl2][0][f] + red[nl2][1][f]) + (red[nl2][2][f] + red[nl2][3][f]))
           + ((red[nl2][4][f] + red[nl2][5][f]) + (red[nl2][6][f] + red[nl2][7][f]));
        if (bias) a += bias[f];
        if (relu) a = fmaxf(a, 0.f);
        if (resid) a += resid[(size_t)node2 * DOUT + f];
        size_t o = (size_t)node2 * DOUT + f;
        if (outF) outF[o] = a;
        if (outAny) {
            if (*flagp) ((float*)outAny)[(size_t)outOff + o] = a;
            else        ((bf16*)outAny)[(size_t)outOff + o] = __float2bfloat16(a);
        }
    }
}

// ---------------- MFMA flash attention v4 (R9-proven) + cvt_pk ----------------
__global__ void __launch_bounds__(512)
k_flash(const bf16* __restrict__ Qb, const bf16* __restrict__ Kb,
        const bf16* __restrict__ VT, float* __restrict__ Bo) {
    __shared__ unsigned short plds[8][2][16][40];
    __shared__ float redo[8][2][16][16];
    __shared__ float redl[8][2][16];
    int w = threadIdx.x >> 6;
    int lane = threadIdx.x & 63;
    int lo = lane & 15;
    int g = lane >> 4;
    int qt = blockIdx.x & 255;
    int h = blockIdx.x >> 8;
    int q0 = qt * 32;
    int m0base = w * 1024;

    const f32x4_t Z = {0.f, 0.f, 0.f, 0.f};
    bf16x8_t zf;
#pragma unroll
    for (int i = 0; i < 8; i++) zf[i] = 0;

    bf16x8_t qf[2];
#pragma unroll
    for (int s = 0; s < 2; s++) {
        if (g < 2) qf[s] = *(const bf16x8_t*)(Qb + (size_t)(q0 + s * 16 + lo) * 64 + h * 16 + g * 8);
        else       qf[s] = zf;
    }

    f32x4_t oacc[2] = {Z, Z};
    float lr[2] = {0.f, 0.f};
    const bf16* kbase = Kb + h * 16 + g * 8;
    const bf16* vbase = VT + (size_t)(h * 16 + lo) * 8192;

    for (int t = 0; t < 32; t++) {
        int m0 = m0base + t * 32;
        bf16x8_t kf0 = zf, kf1 = zf;
        if (g < 2) {
            kf0 = *(const bf16x8_t*)(kbase + (size_t)m0 * 64);
            kf1 = *(const bf16x8_t*)(kbase + (size_t)(m0 + 16) * 64);
        }
        bf16x8_t vt = *(const bf16x8_t*)(vbase + m0 + 8 * g);
#pragma unroll
        for (int s = 0; s < 2; s++) {
            f32x4_t s0 = __builtin_amdgcn_mfma_f32_16x16x32_bf16(kf0, qf[s], Z, 0, 0, 0);
            f32x4_t s1 = __builtin_amdgcn_mfma_f32_16x16x32_bf16(kf1, qf[s], Z, 0, 0, 0);
            float p0 = __builtin_amdgcn_exp2f(s0[0]);
            float p1 = __builtin_amdgcn_exp2f(s0[1]);
            float p2 = __builtin_amdgcn_exp2f(s0[2]);
            float p3 = __builtin_amdgcn_exp2f(s0[3]);
            float p4 = __builtin_amdgcn_exp2f(s1[0]);
            float p5 = __builtin_amdgcn_exp2f(s1[1]);
            float p6 = __builtin_amdgcn_exp2f(s1[2]);
            float p7 = __builtin_amdgcn_exp2f(s1[3]);
            lr[s] += (((p0 + p1) + (p2 + p3)) + ((p4 + p5) + (p6 + p7)));
            unsigned* dst0 = (unsigned*)&plds[w][s][lo][4 * g];
            dst0[0] = pk2(p0, p1);
            dst0[1] = pk2(p2, p3);
            unsigned* dst1 = (unsigned*)&plds[w][s][lo][16 + 4 * g];
            dst1[0] = pk2(p4, p5);
            dst1[1] = pk2(p6, p7);
            bf16x8_t pf = *(const bf16x8_t*)&plds[w][s][lo][8 * g];
            oacc[s] = __builtin_amdgcn_mfma_f32_16x16x32_bf16(vt, pf, oacc[s], 0, 0, 0);
        }
    }
#pragma unroll
    for (int s = 0; s < 2; s++) {
        float l = lr[s];
        l += __shfl_xor(l, 16);
        l += __shfl_xor(l, 32);
        *(f32x4_t*)&redo[w][s][lo][4 * g] = oacc[s];
        if (g == 0) redl[w][s][lo] = l;
    }
    __syncthreads();
    int tid = threadIdx.x;
    int s2 = tid >> 8, q2 = (tid >> 4) & 15, d2 = tid & 15;
    float o = 0.f, l = 0.f;
#pragma unroll
    for (int ww = 0; ww < 8; ww++) {
        o += redo[ww][s2][q2][d2];
        l += redl[ww][s2][q2];
    }
    Bo[(size_t)(q0 + s2 * 16 + q2) * 64 + h * 16 + d2] = o / l;
}

// ---------------- launch ----------------
extern "C" void kernel_launch(void* const* d_in, const int* in_sizes, int n_in,
                              void* d_out, int out_size, void* d_ws, size_t ws_size,
                              hipStream_t stream) {
    int E = in_sizes[1] / 2;
    const int* ei = (const int*)d_in[1];

    int*   ib = (int*)d_ws;
    float* fb = (float*)d_ws;
    int* cnt    = ib;
    int* rowptr = ib + 8192;
    int* fill   = ib + 16448;
    int* ssrc   = ib + 24640;
    int* flagp  = ib + 286784;
    float* dis  = fb + OFF_DIS;
    float* Bias = fb + OFF_BIAS;
    bf16*  Wb   = (bf16*)(fb + OFF_WB);
    float* dsrc = fb + OFF_DSRC;
    float* HD   = fb + OFF_HD;
    float* XA   = fb + OFF_HD;    // 64-wide staging (first half of HD)
    float* HA   = fb + OFF_HA;
    float* HB   = fb + OFF_HB;
    float* Xbuf = fb + OFF_HB;    // X [8192,64] lives here until agg_e2 overwrites
    float* Hz   = fb + OFF_HZ;
    float* Bo   = fb + OFF_BO;
    float* ZA   = fb + OFF_ZA;
    bf16*  Qkv  = (bf16*)(fb + OFF_QKV);   // Qb | Kb(+524288) | VT(+1048576)

    dim3 b512(512), b256(256), b128(128);
    int eb = (E + 255) / 256;

    CvtTab tab;
    auto ent = [&](int i, const void* s, int n, int dst, int mode, int p0, int p1) {
        tab.e[i] = CvtEnt{s, n, dst, mode, p0, p1};
    };
    ent(0,  d_in[0],  524288, OFF_HB, 0, 0, 0);   // x -> HB region (dead by agg_e2)
    ent(1,  d_in[2],  8192,  HS_E1, 2, 128, 0);
    ent(2,  d_in[3],  128,   OFF_BIAS + BF_E1, 0, 0, 0);
    ent(3,  d_in[4],  16384, HS_E2, 2, 128, 0);
    ent(4,  d_in[5],  128,   OFF_BIAS + BF_E2, 0, 0, 0);
    ent(5,  d_in[6],  16384, HS_E3, 2, 128, 0);
    ent(6,  d_in[7],  128,   OFF_BIAS + BF_E3, 0, 0, 0);
    ent(7,  d_in[8],  8192,  HS_E4, 2, 64, 0);
    ent(8,  d_in[9],  64,    OFF_BIAS + BF_E4, 0, 0, 0);
    ent(9,  d_in[10], 8192,  HS_D1, 2, 128, 0);
    ent(10, d_in[11], 128,   OFF_BIAS + BF_D1, 0, 0, 0);
    ent(11, d_in[12], 16384, HS_D2, 2, 128, 0);
    ent(12, d_in[13], 128,   OFF_BIAS + BF_D2, 0, 0, 0);
    ent(13, d_in[14], 16384, HS_D3, 2, 128, 0);
    ent(14, d_in[15], 128,   OFF_BIAS + BF_D3, 0, 0, 0);
    ent(15, d_in[16], 8192,  HS_D4, 2, 64, 0);
    ent(16, d_in[17], 64,    OFF_BIAS + BF_D4, 0, 0, 0);
    ent(17, d_in[18], 12288, HS_AI, 3, 0, 192);
    ent(18, d_in[19], 192,   OFF_BIAS + BF_AI, 0, 0, 0);
    ent(19, d_in[20], 4096,  HS_AO, 3, 0, 64);
    ent(20, d_in[21], 64,    OFF_BIAS + BF_AO, 0, 0, 0);
    k_convert<<<dim3(2501), b256, 0, stream>>>(tab, fb, Wb, flagp,
                                               (const unsigned short*)d_in[0]);

    k_zero_int<<<dim3(32), b256, 0, stream>>>(cnt, 8192);
    k_count<<<dim3(eb), b256, 0, stream>>>(ei, E, cnt);
    k_scan<<<dim3(1), b256, 0, stream>>>(cnt, rowptr, fill, dis);
    k_scatter<<<dim3(eb), b256, 0, stream>>>(ei, E, fill, ssrc, dis, dsrc);

    dim3 g512(512), g1024(1024), g2048(2048), g4096(4096);

    // encoder. e1 reassociated: h1 = relu((A.x)@W1 + b1)
    k_agg<64><<<g2048, b512, 0, stream>>>(Xbuf, rowptr, ssrc, dsrc, dis, nullptr, nullptr,
                                          XA, nullptr, 0, flagp, 0);
    k_mgemm<64, 128, 1><<<g512, b128, 0, stream>>>(XA, Wb + HS_E1, Bias + BF_E1, HA, nullptr);
    k_mgemm<128, 128, 0><<<g512, b128, 0, stream>>>(HA, Wb + HS_E2, nullptr, HD, nullptr);
    k_agg<128><<<g4096, b512, 0, stream>>>(HD, rowptr, ssrc, dsrc, dis, Bias + BF_E2, HA,
                                           HB, nullptr, 0, flagp, 1);
    k_mgemm<128, 128, 0><<<g512, b128, 0, stream>>>(HB, Wb + HS_E3, nullptr, HD, nullptr);
    k_agg<128><<<g4096, b512, 0, stream>>>(HD, rowptr, ssrc, dsrc, dis, Bias + BF_E3, HB,
                                           HA, nullptr, 0, flagp, 1);
    k_mgemm<128, 64, 0><<<g512, b128, 0, stream>>>(HA, Wb + HS_E4, nullptr, HD, nullptr);
    k_agg<64><<<g2048, b512, 0, stream>>>(HD, rowptr, ssrc, dsrc, dis, Bias + BF_E4, nullptr,
                                          Hz, d_out, 524288, flagp, 0);

    // attention: qkv projection (Q scaled, V transposed); flash writes Bo directly
    k_mgemm<64, 192, 2><<<g512, b128, 0, stream>>>(Hz, Wb + HS_AI, Bias + BF_AI, nullptr, Qkv);
    k_flash<<<g1024, b512, 0, stream>>>(Qkv, Qkv + 524288, Qkv + 1048576, Bo);
    k_mgemm<64, 64, 0><<<g512, b128, 0, stream>>>(Bo, Wb + HS_AO, Bias + BF_AO, ZA, nullptr);

    // decoder. d1 reassociated: g1 = relu((A.za)@W1 + b1)
    k_agg<64><<<g2048, b512, 0, stream>>>(ZA, rowptr, ssrc, dsrc, dis, nullptr, nullptr,
                                          XA, nullptr, 0, flagp, 0);
    k_mgemm<64, 128, 1><<<g512, b128, 0, stream>>>(XA, Wb + HS_D1, Bias + BF_D1, HA, nullptr);
    k_mgemm<128, 128, 0><<<g512, b128, 0, stream>>>(HA, Wb + HS_D2, nullptr, HD, nullptr);
    k_agg<128><<<g4096, b512, 0, stream>>>(HD, rowptr, ssrc, dsrc, dis, Bias + BF_D2, HA,
                                           HB, nullptr, 0, flagp, 1);
    k_mgemm<128, 128, 0><<<g512, b128, 0, stream>>>(HB, Wb + HS_D3, nullptr, HD, nullptr);
    k_agg<128><<<g4096, b512, 0, stream>>>(HD, rowptr, ssrc, dsrc, dis, Bias + BF_D3, HB,
                                           HA, nullptr, 0, flagp, 1);
    k_mgemm<128, 64, 0><<<g512, b128, 0, stream>>>(HA, Wb + HS_D4, nullptr, HD, nullptr);
    k_agg<64><<<g2048, b512, 0, stream>>>(HD, rowptr, ssrc, dsrc, dis, Bias + BF_D4, nullptr,
                                          nullptr, d_out, 0, flagp, 0);
}

// Round 12
// 371.301 us; speedup vs baseline: 3.3494x; 1.0244x over previous
//
#include <hip/hip_runtime.h>
#include <hip/hip_bf16.h>

using bf16 = __hip_bfloat16;

typedef __attribute__((ext_vector_type(8))) short bf16x8_t;   // 8 bf16 in 4 VGPRs
typedef __attribute__((ext_vector_type(4))) float f32x4_t;

static __device__ __forceinline__ float b2f(bf16 v) { return __bfloat162float(v); }

// pack two fp32 -> 2 bf16 (RNE) via v_cvt_pk_bf16_f32
static __device__ __forceinline__ unsigned pk2(float a, float b) {
    __hip_bfloat162 h = __float22bfloat162_rn(make_float2(a, b));
    return *reinterpret_cast<unsigned*>(&h);
}
static __device__ __forceinline__ float lo16f(unsigned u) { return __uint_as_float(u << 16); }
static __device__ __forceinline__ float hi16f(unsigned u) { return __uint_as_float(u & 0xFFFF0000u); }

// log2(e)/4 : folds 1/sqrt(DH) and exp->exp2. Applied at qkv GEMM output (fp32).
#define QSCALE 0.36067376022224085f

// ---------------- workspace layout (float offsets) ----------------
// ints: cnt[0,8192) rowptr[8192,16385) fill[16448,24640) ssrc[24640,286784) flag ib[286784]
#define OFF_DIS  286848
#define OFF_BIAS 295040   /* 1152 fp32 */
#define OFF_WB   296192   /* bf16 weights (split hi+lo), 229376 shorts = 114688 floats */
#define OFF_DSRC 410880   /* fp32 edge weights [262144] */
#define OFF_HD   935168   /* bf16 gemm staging [8192,128] = 524288 f; XA fp32 at +524288 */
#define OFF_HA   1983744  /* fp32 act [8192,128] */
#define OFF_HB   3032320  /* fp32 act [8192,128]; X [8192,64] lives in first half early */
#define OFF_HZ   4080896  /* fp32 z [8192,64] */
#define OFF_BO   4605184  /* fp32 attention out [8192,64] */
#define OFF_ZA   5129472  /* fp32 za [8192,64] */
#define OFF_QKV  5653760  /* bf16: Qb[8192*64] | Kb[8192*64] | VT[64*8192] = 786432 f slots */
// total 6440192 floats = 25.76 MB

// weight short-offsets (relative to OFF_WB as bf16*), each region hi plane then lo plane
#define HS_E1 0
#define HS_E2 16384
#define HS_E3 49152
#define HS_E4 81920
#define HS_D1 98304
#define HS_D2 114688
#define HS_D3 147456
#define HS_D4 180224
#define HS_AI 196608
#define HS_AO 221184

// bias fp32 offsets (relative to OFF_BIAS)
#define BF_E1 0
#define BF_E2 128
#define BF_E3 256
#define BF_E4 384
#define BF_D1 448
#define BF_D2 576
#define BF_D3 704
#define BF_D4 832
#define BF_AI 896
#define BF_AO 1088

// ---------------- input canonicalization (sniff fused) ----------------
struct CvtEnt { const void* src; int n; int dst; int mode; int p0; int p1; };
struct CvtTab { CvtEnt e[21]; };

__global__ void k_convert(CvtTab tab, float* __restrict__ fb, bf16* __restrict__ hb,
                          int* __restrict__ flagp, const unsigned short* __restrict__ xb) {
    __shared__ int wsum[4];
    unsigned short wv = xb[threadIdx.x * 2];
    int ex = (wv >> 7) & 0xFF;
    int mn = wv & 0x7F;
    int weird = (ex >= 134) || (ex != 0 && ex <= 90) || (ex == 0 && mn != 0);
    unsigned long long bal = __ballot(weird);
    if ((threadIdx.x & 63) == 0) wsum[threadIdx.x >> 6] = (int)__popcll(bal);
    __syncthreads();
    int fl = ((wsum[0] + wsum[1]) + (wsum[2] + wsum[3])) >= 32 ? 1 : 0;   // 1 => fp32
    if (blockIdx.x == 0 && threadIdx.x == 0) *flagp = fl;

    int i = blockIdx.x * blockDim.x + threadIdx.x;
#pragma unroll 1
    for (int t = 0; t < 21; t++) {
        int n = tab.e[t].n;
        if (i < n) {
            float v = fl ? ((const float*)tab.e[t].src)[i]
                         : b2f(((const bf16*)tab.e[t].src)[i]);
            int mode = tab.e[t].mode, dst = tab.e[t].dst;
            if (mode == 0) {
                fb[dst + i] = v;
            } else {
                int idx;
                if (mode == 2) {
                    int dout = tab.e[t].p0;
                    int r = i / dout, c = i - r * dout;
                    idx = ((r >> 3) * dout + c) * 8 + (r & 7);
                } else {
                    int r = i >> 6, c = i & 63;       // r = n_eff, c = k_eff
                    idx = ((c >> 3) * tab.e[t].p1 + r) * 8 + (c & 7);
                }
                bf16 hv = __float2bfloat16(v);
                hb[dst + idx] = hv;
                hb[dst + n + idx] = __float2bfloat16(v - b2f(hv));
            }
            return;
        }
        i -= n;
    }
}

// ---------------- CSR construction ----------------
__global__ void k_count(const int* __restrict__ ei, int E, int* __restrict__ cnt) {
    int e = blockIdx.x * blockDim.x + threadIdx.x;
    if (e < E) atomicAdd(&cnt[ei[E + e]], 1);
}

__global__ void k_scan(const int* __restrict__ cnt, int* __restrict__ rowptr,
                       int* __restrict__ fill, float* __restrict__ dis) {
    __shared__ int sums[256];
    int t = threadIdx.x;
    int base = t * 32;
    int s = 0;
#pragma unroll
    for (int i = 0; i < 32; i++) s += cnt[base + i];
    sums[t] = s;
    __syncthreads();
    for (int off = 1; off < 256; off <<= 1) {
        int v = (t >= off) ? sums[t - off] : 0;
        __syncthreads();
        sums[t] += v;
        __syncthreads();
    }
    int run = (t == 0) ? 0 : sums[t - 1];
#pragma unroll
    for (int i = 0; i < 32; i++) {
        int idx = base + i;
        rowptr[idx] = run;
        fill[idx] = run;
        dis[idx] = rsqrtf((float)(cnt[idx] + 1));
        run += cnt[idx];
    }
    if (t == 255) rowptr[8192] = run;
}

__global__ void k_scatter(const int* __restrict__ ei, int E,
                          int* __restrict__ fill, int* __restrict__ ssrc,
                          const float* __restrict__ dis, float* __restrict__ dsrc) {
    int e = blockIdx.x * blockDim.x + threadIdx.x;
    if (e < E) {
        int s = ei[e];
        int pos = atomicAdd(&fill[ei[E + e]], 1);
        ssrc[pos] = s;
        dsrc[pos] = dis[s];
    }
}

// ---------------- MFMA GEMM: fp32 A (in-register hi/lo split) x split-bf16 W ----------------
// Wave tile 16 rows x 32 cols -> 8 waves/CU. 3 MFMAs/tile (ah*wh + al*wh + ah*wl).
// OMODE: 0 -> fp32 out + bias; 1 -> fp32 out + bias + relu; 3 -> bf16 plain out (agg staging);
//        2 -> qkv: Q (scaled, [8192,64]) | K [8192,64] | VT [64,8192]
template<int K, int DOUT, int OMODE>
__global__ void __launch_bounds__(128) k_mgemm(const float* __restrict__ A,
                                               const bf16* __restrict__ Wb,
                                               const float* __restrict__ bias,
                                               float* __restrict__ outF,
                                               bf16* __restrict__ outH) {
    constexpr int PIECES = DOUT / 32, NKS = K / 32;
    constexpr int WPL = K * DOUT;
    int w = threadIdx.x >> 6, lane = threadIdx.x & 63;
    int lo = lane & 15, g = lane >> 4;
    int wg = blockIdx.x * 2 + w;
    int r0 = (wg / PIECES) * 16;
    int c0 = (wg % PIECES) * 32;
    const f32x4_t Z = {0.f, 0.f, 0.f, 0.f};
    f32x4_t acc[2] = {Z, Z};
#pragma unroll
    for (int kk = 0; kk < NKS; kk++) {
        const float* ap = A + (size_t)(r0 + lo) * K + kk * 32 + g * 8;
        float4 x0 = *(const float4*)ap;
        float4 x1 = *(const float4*)(ap + 4);
        union { unsigned u[4]; bf16x8_t v; } ah, al;
        ah.u[0] = pk2(x0.x, x0.y);
        ah.u[1] = pk2(x0.z, x0.w);
        ah.u[2] = pk2(x1.x, x1.y);
        ah.u[3] = pk2(x1.z, x1.w);
        al.u[0] = pk2(x0.x - lo16f(ah.u[0]), x0.y - hi16f(ah.u[0]));
        al.u[1] = pk2(x0.z - lo16f(ah.u[1]), x0.w - hi16f(ah.u[1]));
        al.u[2] = pk2(x1.x - lo16f(ah.u[2]), x1.y - hi16f(ah.u[2]));
        al.u[3] = pk2(x1.z - lo16f(ah.u[3]), x1.w - hi16f(ah.u[3]));
#pragma unroll
        for (int ct = 0; ct < 2; ct++) {
            size_t wi = (size_t)((kk * 4 + g) * DOUT + c0 + ct * 16 + lo) * 8;
            bf16x8_t wh = *(const bf16x8_t*)(Wb + wi);
            bf16x8_t wl = *(const bf16x8_t*)(Wb + WPL + wi);
            acc[ct] = __builtin_amdgcn_mfma_f32_16x16x32_bf16(ah.v, wh, acc[ct], 0, 0, 0);
            acc[ct] = __builtin_amdgcn_mfma_f32_16x16x32_bf16(al.v, wh, acc[ct], 0, 0, 0);
            acc[ct] = __builtin_amdgcn_mfma_f32_16x16x32_bf16(ah.v, wl, acc[ct], 0, 0, 0);
        }
    }
#pragma unroll
    for (int ct = 0; ct < 2; ct++) {
        int n = c0 + ct * 16 + lo;
        float bs = ((OMODE == 0 || OMODE == 1 || OMODE == 2) && bias) ? bias[n] : 0.f;
#pragma unroll
        for (int r = 0; r < 4; r++) {
            float v = acc[ct][r] + bs;
            int node = r0 + 4 * g + r;
            if (OMODE == 0) {
                outF[(size_t)node * DOUT + n] = v;
            } else if (OMODE == 1) {
                outF[(size_t)node * DOUT + n] = fmaxf(v, 0.f);
            } else if (OMODE == 3) {
                outH[(size_t)node * DOUT + n] = __float2bfloat16(v);
            } else {
                if (n < 64) {
                    outH[(size_t)node * 64 + n] = __float2bfloat16(v * QSCALE);
                } else if (n < 128) {
                    outH[524288 + (size_t)node * 64 + (n - 64)] = __float2bfloat16(v);
                } else {
                    outH[1048576 + (size_t)(n - 128) * 8192 + node] = __float2bfloat16(v);
                }
            }
        }
    }
}

// ---------------- GCN aggregation: 8 edge streams, fp32 or bf16 gather ----------------
// 512-thr blocks. DOUT=128: 2 nodes/block (grid 4096); DOUT=64: 4 nodes/block (grid 2048).
template<int DOUT, int BF>
__global__ void __launch_bounds__(512) k_agg(const void* __restrict__ hdv,
                      const int* __restrict__ rowptr,
                      const int* __restrict__ ssrc, const float* __restrict__ dsrc,
                      const float* __restrict__ dis,
                      const float* __restrict__ bias, const float* __restrict__ resid,
                      float* __restrict__ outF, void* __restrict__ outAny, int outOff,
                      const int* __restrict__ flagp, int relu) {
    constexpr int LPR = DOUT / 4;
    constexpr int GPW = 64 / LPR;
    constexpr int NST = 8;
    constexpr int WPN = NST / GPW;
    constexpr int NPB = 8 / WPN;
    __shared__ float red[NPB][NST][DOUT];

    int w = threadIdx.x >> 6;
    int lane = threadIdx.x & 63;
    int g = lane / LPR;
    int fl4 = (lane % LPR) * 4;
    int nl = w / WPN;
    int s = (w % WPN) * GPW + g;
    int node = blockIdx.x * NPB + nl;

    float di = dis[node];
    int e0 = rowptr[node], e1 = rowptr[node + 1];
    float4 acc = {0.f, 0.f, 0.f, 0.f};
    for (int e = e0 + s; e < e1; e += NST) {
        int sv = ssrc[e];
        float wgt = dsrc[e] * di;
        float4 v;
        if (BF) {
            uint2 u = *(const uint2*)((const bf16*)hdv + (size_t)sv * DOUT + fl4);
            v.x = lo16f(u.x); v.y = hi16f(u.x); v.z = lo16f(u.y); v.w = hi16f(u.y);
        } else {
            v = *(const float4*)((const float*)hdv + (size_t)sv * DOUT + fl4);
        }
        acc.x += v.x * wgt; acc.y += v.y * wgt; acc.z += v.z * wgt; acc.w += v.w * wgt;
    }
    *(float4*)&red[nl][s][fl4] = acc;
    __syncthreads();

    int tid = threadIdx.x;
    if (tid < NPB * DOUT) {
        int nl2 = tid / DOUT;
        int f = tid % DOUT;
        int node2 = blockIdx.x * NPB + nl2;
        float di2 = dis[node2];
        float self = BF ? b2f(((const bf16*)hdv)[(size_t)node2 * DOUT + f])
                        : ((const float*)hdv)[(size_t)node2 * DOUT + f];
        float a = self * (di2 * di2);
        a += ((red[nl2][0][f] + red[nl2][1][f]) + (red[nl2][2][f] + red[nl2][3][f]))
           + ((red[nl2][4][f] + red[nl2][5][f]) + (red[nl2][6][f] + red[nl2][7][f]));
        if (bias) a += bias[f];
        if (relu) a = fmaxf(a, 0.f);
        if (resid) a += resid[(size_t)node2 * DOUT + f];
        size_t o = (size_t)node2 * DOUT + f;
        if (outF) outF[o] = a;
        if (outAny) {
            if (*flagp) ((float*)outAny)[(size_t)outOff + o] = a;
            else        ((bf16*)outAny)[(size_t)outOff + o] = __float2bfloat16(a);
        }
    }
}

// ---------------- MFMA flash attention (R11-proven) ----------------
__global__ void __launch_bounds__(512)
k_flash(const bf16* __restrict__ Qb, const bf16* __restrict__ Kb,
        const bf16* __restrict__ VT, float* __restrict__ Bo) {
    __shared__ unsigned short plds[8][2][16][40];
    __shared__ float redo[8][2][16][16];
    __shared__ float redl[8][2][16];
    int w = threadIdx.x >> 6;
    int lane = threadIdx.x & 63;
    int lo = lane & 15;
    int g = lane >> 4;
    int qt = blockIdx.x & 255;
    int h = blockIdx.x >> 8;
    int q0 = qt * 32;
    int m0base = w * 1024;

    const f32x4_t Z = {0.f, 0.f, 0.f, 0.f};
    bf16x8_t zf;
#pragma unroll
    for (int i = 0; i < 8; i++) zf[i] = 0;

    bf16x8_t qf[2];
#pragma unroll
    for (int s = 0; s < 2; s++) {
        if (g < 2) qf[s] = *(const bf16x8_t*)(Qb + (size_t)(q0 + s * 16 + lo) * 64 + h * 16 + g * 8);
        else       qf[s] = zf;
    }

    f32x4_t oacc[2] = {Z, Z};
    float lr[2] = {0.f, 0.f};
    const bf16* kbase = Kb + h * 16 + g * 8;
    const bf16* vbase = VT + (size_t)(h * 16 + lo) * 8192;

    for (int t = 0; t < 32; t++) {
        int m0 = m0base + t * 32;
        bf16x8_t kf0 = zf, kf1 = zf;
        if (g < 2) {
            kf0 = *(const bf16x8_t*)(kbase + (size_t)m0 * 64);
            kf1 = *(const bf16x8_t*)(kbase + (size_t)(m0 + 16) * 64);
        }
        bf16x8_t vt = *(const bf16x8_t*)(vbase + m0 + 8 * g);
#pragma unroll
        for (int s = 0; s < 2; s++) {
            f32x4_t s0 = __builtin_amdgcn_mfma_f32_16x16x32_bf16(kf0, qf[s], Z, 0, 0, 0);
            f32x4_t s1 = __builtin_amdgcn_mfma_f32_16x16x32_bf16(kf1, qf[s], Z, 0, 0, 0);
            float p0 = __builtin_amdgcn_exp2f(s0[0]);
            float p1 = __builtin_amdgcn_exp2f(s0[1]);
            float p2 = __builtin_amdgcn_exp2f(s0[2]);
            float p3 = __builtin_amdgcn_exp2f(s0[3]);
            float p4 = __builtin_amdgcn_exp2f(s1[0]);
            float p5 = __builtin_amdgcn_exp2f(s1[1]);
            float p6 = __builtin_amdgcn_exp2f(s1[2]);
            float p7 = __builtin_amdgcn_exp2f(s1[3]);
            lr[s] += (((p0 + p1) + (p2 + p3)) + ((p4 + p5) + (p6 + p7)));
            unsigned* dst0 = (unsigned*)&plds[w][s][lo][4 * g];
            dst0[0] = pk2(p0, p1);
            dst0[1] = pk2(p2, p3);
            unsigned* dst1 = (unsigned*)&plds[w][s][lo][16 + 4 * g];
            dst1[0] = pk2(p4, p5);
            dst1[1] = pk2(p6, p7);
            bf16x8_t pf = *(const bf16x8_t*)&plds[w][s][lo][8 * g];
            oacc[s] = __builtin_amdgcn_mfma_f32_16x16x32_bf16(vt, pf, oacc[s], 0, 0, 0);
        }
    }
#pragma unroll
    for (int s = 0; s < 2; s++) {
        float l = lr[s];
        l += __shfl_xor(l, 16);
        l += __shfl_xor(l, 32);
        *(f32x4_t*)&redo[w][s][lo][4 * g] = oacc[s];
        if (g == 0) redl[w][s][lo] = l;
    }
    __syncthreads();
    int tid = threadIdx.x;
    int s2 = tid >> 8, q2 = (tid >> 4) & 15, d2 = tid & 15;
    float o = 0.f, l = 0.f;
#pragma unroll
    for (int ww = 0; ww < 8; ww++) {
        o += redo[ww][s2][q2][d2];
        l += redl[ww][s2][q2];
    }
    Bo[(size_t)(q0 + s2 * 16 + q2) * 64 + h * 16 + d2] = o / l;
}

// ---------------- launch ----------------
extern "C" void kernel_launch(void* const* d_in, const int* in_sizes, int n_in,
                              void* d_out, int out_size, void* d_ws, size_t ws_size,
                              hipStream_t stream) {
    int E = in_sizes[1] / 2;
    const int* ei = (const int*)d_in[1];

    int*   ib = (int*)d_ws;
    float* fb = (float*)d_ws;
    int* cnt    = ib;
    int* rowptr = ib + 8192;
    int* fill   = ib + 16448;
    int* ssrc   = ib + 24640;
    int* flagp  = ib + 286784;
    float* dis  = fb + OFF_DIS;
    float* Bias = fb + OFF_BIAS;
    bf16*  Wb   = (bf16*)(fb + OFF_WB);
    float* dsrc = fb + OFF_DSRC;
    bf16*  HDb  = (bf16*)(fb + OFF_HD);     // bf16 staging [8192,128]
    float* XA   = fb + OFF_HD + 524288;     // fp32 64-wide staging
    float* HA   = fb + OFF_HA;
    float* HB   = fb + OFF_HB;
    float* Xbuf = fb + OFF_HB;    // X [8192,64] lives here until agg_e2 overwrites
    float* Hz   = fb + OFF_HZ;
    float* Bo   = fb + OFF_BO;
    float* ZA   = fb + OFF_ZA;
    bf16*  Qkv  = (bf16*)(fb + OFF_QKV);   // Qb | Kb(+524288) | VT(+1048576)

    dim3 b512(512), b256(256), b128(128);
    int eb = (E + 255) / 256;

    CvtTab tab;
    auto ent = [&](int i, const void* s, int n, int dst, int mode, int p0, int p1) {
        tab.e[i] = CvtEnt{s, n, dst, mode, p0, p1};
    };
    ent(0,  d_in[0],  524288, OFF_HB, 0, 0, 0);   // x -> HB region (dead by agg_e2)
    ent(1,  d_in[2],  8192,  HS_E1, 2, 128, 0);
    ent(2,  d_in[3],  128,   OFF_BIAS + BF_E1, 0, 0, 0);
    ent(3,  d_in[4],  16384, HS_E2, 2, 128, 0);
    ent(4,  d_in[5],  128,   OFF_BIAS + BF_E2, 0, 0, 0);
    ent(5,  d_in[6],  16384, HS_E3, 2, 128, 0);
    ent(6,  d_in[7],  128,   OFF_BIAS + BF_E3, 0, 0, 0);
    ent(7,  d_in[8],  8192,  HS_E4, 2, 64, 0);
    ent(8,  d_in[9],  64,    OFF_BIAS + BF_E4, 0, 0, 0);
    ent(9,  d_in[10], 8192,  HS_D1, 2, 128, 0);
    ent(10, d_in[11], 128,   OFF_BIAS + BF_D1, 0, 0, 0);
    ent(11, d_in[12], 16384, HS_D2, 2, 128, 0);
    ent(12, d_in[13], 128,   OFF_BIAS + BF_D2, 0, 0, 0);
    ent(13, d_in[14], 16384, HS_D3, 2, 128, 0);
    ent(14, d_in[15], 128,   OFF_BIAS + BF_D3, 0, 0, 0);
    ent(15, d_in[16], 8192,  HS_D4, 2, 64, 0);
    ent(16, d_in[17], 64,    OFF_BIAS + BF_D4, 0, 0, 0);
    ent(17, d_in[18], 12288, HS_AI, 3, 0, 192);
    ent(18, d_in[19], 192,   OFF_BIAS + BF_AI, 0, 0, 0);
    ent(19, d_in[20], 4096,  HS_AO, 3, 0, 64);
    ent(20, d_in[21], 64,    OFF_BIAS + BF_AO, 0, 0, 0);
    k_convert<<<dim3(2501), b256, 0, stream>>>(tab, fb, Wb, flagp,
                                               (const unsigned short*)d_in[0]);

    hipMemsetAsync(cnt, 0, 8192 * sizeof(int), stream);
    k_count<<<dim3(eb), b256, 0, stream>>>(ei, E, cnt);
    k_scan<<<dim3(1), b256, 0, stream>>>(cnt, rowptr, fill, dis);
    k_scatter<<<dim3(eb), b256, 0, stream>>>(ei, E, fill, ssrc, dis, dsrc);

    dim3 g2048(2048), g4096(4096), g1024(1024);
    dim3 gm128(1024), gm64(512), gm192(1536);   // mgemm grids: waves = 512*(DOUT/32)/2 blocks

    // encoder. e1 reassociated: h1 = relu((A.x)@W1 + b1)
    k_agg<64, 0><<<g2048, b512, 0, stream>>>(Xbuf, rowptr, ssrc, dsrc, dis, nullptr, nullptr,
                                             XA, nullptr, 0, flagp, 0);
    k_mgemm<64, 128, 1><<<gm128, b128, 0, stream>>>(XA, Wb + HS_E1, Bias + BF_E1, HA, nullptr);
    k_mgemm<128, 128, 3><<<gm128, b128, 0, stream>>>(HA, Wb + HS_E2, nullptr, nullptr, HDb);
    k_agg<128, 1><<<g4096, b512, 0, stream>>>(HDb, rowptr, ssrc, dsrc, dis, Bias + BF_E2, HA,
                                              HB, nullptr, 0, flagp, 1);
    k_mgemm<128, 128, 3><<<gm128, b128, 0, stream>>>(HB, Wb + HS_E3, nullptr, nullptr, HDb);
    k_agg<128, 1><<<g4096, b512, 0, stream>>>(HDb, rowptr, ssrc, dsrc, dis, Bias + BF_E3, HB,
                                              HA, nullptr, 0, flagp, 1);
    k_mgemm<128, 64, 3><<<gm64, b128, 0, stream>>>(HA, Wb + HS_E4, nullptr, nullptr, HDb);
    k_agg<64, 1><<<g2048, b512, 0, stream>>>(HDb, rowptr, ssrc, dsrc, dis, Bias + BF_E4, nullptr,
                                             Hz, d_out, 524288, flagp, 0);

    // attention: qkv projection (Q scaled, V transposed); flash writes Bo directly
    k_mgemm<64, 192, 2><<<gm192, b128, 0, stream>>>(Hz, Wb + HS_AI, Bias + BF_AI, nullptr, Qkv);
    k_flash<<<g1024, b512, 0, stream>>>(Qkv, Qkv + 524288, Qkv + 1048576, Bo);
    k_mgemm<64, 64, 0><<<gm64, b128, 0, stream>>>(Bo, Wb + HS_AO, Bias + BF_AO, ZA, nullptr);

    // decoder. d1 reassociated: g1 = relu((A.za)@W1 + b1)
    k_agg<64, 0><<<g2048, b512, 0, stream>>>(ZA, rowptr, ssrc, dsrc, dis, nullptr, nullptr,
                                             XA, nullptr, 0, flagp, 0);
    k_mgemm<64, 128, 1><<<gm128, b128, 0, stream>>>(XA, Wb + HS_D1, Bias + BF_D1, HA, nullptr);
    k_mgemm<128, 128, 3><<<gm128, b128, 0, stream>>>(HA, Wb + HS_D2, nullptr, nullptr, HDb);
    k_agg<128, 1><<<g4096, b512, 0, stream>>>(HDb, rowptr, ssrc, dsrc, dis, Bias + BF_D2, HA,
                                              HB, nullptr, 0, flagp, 1);
    k_mgemm<128, 128, 3><<<gm128, b128, 0, stream>>>(HB, Wb + HS_D3, nullptr, nullptr, HDb);
    k_agg<128, 1><<<g4096, b512, 0, stream>>>(HDb, rowptr, ssrc, dsrc, dis, Bias + BF_D3, HB,
                                              HA, nullptr, 0, flagp, 1);
    k_mgemm<128, 64, 3><<<gm64, b128, 0, stream>>>(HA, Wb + HS_D4, nullptr, nullptr, HDb);
    k_agg<64, 1><<<g2048, b512, 0, stream>>>(HDb, rowptr, ssrc, dsrc, dis, Bias + BF_D4, nullptr,
                                             nullptr, d_out, 0, flagp, 0);
}

// Round 13
// 315.295 us; speedup vs baseline: 3.9444x; 1.1776x over previous
//
#include <hip/hip_runtime.h>
#include <hip/hip_bf16.h>

using bf16 = __hip_bfloat16;

typedef __attribute__((ext_vector_type(8))) short bf16x8_t;   // 8 bf16 in 4 VGPRs
typedef __attribute__((ext_vector_type(4))) float f32x4_t;

static __device__ __forceinline__ float b2f(bf16 v) { return __bfloat162float(v); }

// pack two fp32 -> 2 bf16 (RNE) via v_cvt_pk_bf16_f32
static __device__ __forceinline__ unsigned pk2(float a, float b) {
    __hip_bfloat162 h = __float22bfloat162_rn(make_float2(a, b));
    return *reinterpret_cast<unsigned*>(&h);
}
static __device__ __forceinline__ float lo16f(unsigned u) { return __uint_as_float(u << 16); }
static __device__ __forceinline__ float hi16f(unsigned u) { return __uint_as_float(u & 0xFFFF0000u); }

// log2(e)/4 : folds 1/sqrt(DH) and exp->exp2. Applied at qkv GEMM output (fp32).
#define QSCALE 0.36067376022224085f

// ---------------- workspace layout (float offsets) ----------------
// ints: cnt[0,8192) rowptr[8192,16385) fill[16448,24640) ssrc[24640,286784) flag ib[286784]
#define OFF_DIS  286848
#define OFF_BIAS 295040   /* 1152 fp32 */
#define OFF_WB   296192   /* bf16 weights (split hi+lo), 229376 shorts = 114688 floats */
#define OFF_DSRC 410880   /* fp32 edge weights [262144] */
#define OFF_X    935168   /* fp32 x [8192,64] */
#define OFF_HA   1983744  /* fp32 act [8192,128] */
#define OFF_HB   3032320  /* fp32 act [8192,128] */
#define OFF_HZ   4080896  /* fp32 z [8192,64] */
#define OFF_BO   4605184  /* fp32 attention out [8192,64] */
#define OFF_ZA   5129472  /* fp32 za [8192,64] */
#define OFF_QKV  5653760  /* bf16: Qb[8192*64] | Kb[8192*64] | VT[64*8192] = 786432 f slots */
// total 6440192 floats = 25.76 MB

// weight short-offsets (relative to OFF_WB as bf16*), each region hi plane then lo plane
#define HS_E1 0
#define HS_E2 16384
#define HS_E3 49152
#define HS_E4 81920
#define HS_D1 98304
#define HS_D2 114688
#define HS_D3 147456
#define HS_D4 180224
#define HS_AI 196608
#define HS_AO 221184

// bias fp32 offsets (relative to OFF_BIAS)
#define BF_E1 0
#define BF_E2 128
#define BF_E3 256
#define BF_E4 384
#define BF_D1 448
#define BF_D2 576
#define BF_D3 704
#define BF_D4 832
#define BF_AI 896
#define BF_AO 1088

// ---------------- input canonicalization (sniff fused) ----------------
struct CvtEnt { const void* src; int n; int dst; int mode; int p0; int p1; };
struct CvtTab { CvtEnt e[21]; };

__global__ void k_convert(CvtTab tab, float* __restrict__ fb, bf16* __restrict__ hb,
                          int* __restrict__ flagp, const unsigned short* __restrict__ xb) {
    __shared__ int wsum[4];
    unsigned short wv = xb[threadIdx.x * 2];
    int ex = (wv >> 7) & 0xFF;
    int mn = wv & 0x7F;
    int weird = (ex >= 134) || (ex != 0 && ex <= 90) || (ex == 0 && mn != 0);
    unsigned long long bal = __ballot(weird);
    if ((threadIdx.x & 63) == 0) wsum[threadIdx.x >> 6] = (int)__popcll(bal);
    __syncthreads();
    int fl = ((wsum[0] + wsum[1]) + (wsum[2] + wsum[3])) >= 32 ? 1 : 0;   // 1 => fp32
    if (blockIdx.x == 0 && threadIdx.x == 0) *flagp = fl;

    int i = blockIdx.x * blockDim.x + threadIdx.x;
#pragma unroll 1
    for (int t = 0; t < 21; t++) {
        int n = tab.e[t].n;
        if (i < n) {
            float v = fl ? ((const float*)tab.e[t].src)[i]
                         : b2f(((const bf16*)tab.e[t].src)[i]);
            int mode = tab.e[t].mode, dst = tab.e[t].dst;
            if (mode == 0) {
                fb[dst + i] = v;
            } else {
                int idx;
                if (mode == 2) {
                    int dout = tab.e[t].p0;
                    int r = i / dout, c = i - r * dout;
                    idx = ((r >> 3) * dout + c) * 8 + (r & 7);
                } else {
                    int r = i >> 6, c = i & 63;       // r = n_eff, c = k_eff
                    idx = ((c >> 3) * tab.e[t].p1 + r) * 8 + (c & 7);
                }
                bf16 hv = __float2bfloat16(v);
                hb[dst + idx] = hv;
                hb[dst + n + idx] = __float2bfloat16(v - b2f(hv));
            }
            return;
        }
        i -= n;
    }
}

// ---------------- CSR construction ----------------
__global__ void k_count(const int* __restrict__ ei, int E, int* __restrict__ cnt) {
    int e = blockIdx.x * blockDim.x + threadIdx.x;
    if (e < E) atomicAdd(&cnt[ei[E + e]], 1);
}

__global__ void k_scan(const int* __restrict__ cnt, int* __restrict__ rowptr,
                       int* __restrict__ fill, float* __restrict__ dis) {
    __shared__ int sums[256];
    int t = threadIdx.x;
    int base = t * 32;
    int s = 0;
#pragma unroll
    for (int i = 0; i < 32; i++) s += cnt[base + i];
    sums[t] = s;
    __syncthreads();
    for (int off = 1; off < 256; off <<= 1) {
        int v = (t >= off) ? sums[t - off] : 0;
        __syncthreads();
        sums[t] += v;
        __syncthreads();
    }
    int run = (t == 0) ? 0 : sums[t - 1];
#pragma unroll
    for (int i = 0; i < 32; i++) {
        int idx = base + i;
        rowptr[idx] = run;
        fill[idx] = run;
        dis[idx] = rsqrtf((float)(cnt[idx] + 1));
        run += cnt[idx];
    }
    if (t == 255) rowptr[8192] = run;
}

__global__ void k_scatter(const int* __restrict__ ei, int E,
                          int* __restrict__ fill, int* __restrict__ ssrc,
                          const float* __restrict__ dis, float* __restrict__ dsrc) {
    int e = blockIdx.x * blockDim.x + threadIdx.x;
    if (e < E) {
        int s = ei[e];
        int pos = atomicAdd(&fill[ei[E + e]], 1);
        ssrc[pos] = s;
        dsrc[pos] = dis[s];
    }
}

// ---------------- FUSED GCN layer: agg(H) in LDS -> MFMA @ W -> bias/relu/resid ----------
// Reassociation agg(H@W) == agg(H)@W is exact in real arithmetic.
// Block = 16 nodes, 512 threads. Agg: groups of K/4 lanes gather float4 rows;
// SPN streams/node. Gemm: wave w -> 16-col tile; A from LDS (stride = K+4 floats:
// 16B-aligned, bank offset 4 -> 2-way aliasing = free). 3 MFMAs/tile hi/lo split.
template<int K, int DOUT, int RELU>
__global__ void __launch_bounds__(512)
k_fused(const float* __restrict__ H, const int* __restrict__ rowptr,
        const int* __restrict__ ssrc, const float* __restrict__ dsrc,
        const float* __restrict__ dis, const bf16* __restrict__ Wb,
        const float* __restrict__ bias, const float* __restrict__ resid,
        float* __restrict__ outF, void* __restrict__ outAny, int outOff,
        const int* __restrict__ flagp) {
    constexpr int LPR = K / 4;          // lanes per row-gather group
    constexpr int NG  = 512 / LPR;      // gather groups
    constexpr int SPN = NG / 16;        // edge streams per node (1 or 2)
    constexpr int PADK = K + 4;
    constexpr int WPL = K * DOUT;
    __shared__ float Hs[SPN][16][PADK];

    int tid = threadIdx.x;
    int gp = tid / LPR;
    int li = tid - gp * LPR;
    int fl4 = li * 4;
    int nl = gp / SPN;
    int st = gp - nl * SPN;
    int node = blockIdx.x * 16 + nl;

    float di = dis[node];
    int e0 = rowptr[node], e1 = rowptr[node + 1];
    float4 acc = {0.f, 0.f, 0.f, 0.f};
    if (st == 0) {
        float dii = di * di;
        float4 sv = *(const float4*)(H + (size_t)node * K + fl4);
        acc.x = sv.x * dii; acc.y = sv.y * dii; acc.z = sv.z * dii; acc.w = sv.w * dii;
    }
    int e = e0 + st;
    for (; e + 3 * SPN < e1; e += 4 * SPN) {
        int s0 = ssrc[e], s1 = ssrc[e + SPN], s2 = ssrc[e + 2 * SPN], s3 = ssrc[e + 3 * SPN];
        float w0 = dsrc[e] * di, w1 = dsrc[e + SPN] * di;
        float w2 = dsrc[e + 2 * SPN] * di, w3 = dsrc[e + 3 * SPN] * di;
        float4 v0 = *(const float4*)(H + (size_t)s0 * K + fl4);
        float4 v1 = *(const float4*)(H + (size_t)s1 * K + fl4);
        float4 v2 = *(const float4*)(H + (size_t)s2 * K + fl4);
        float4 v3 = *(const float4*)(H + (size_t)s3 * K + fl4);
        acc.x += v0.x * w0; acc.y += v0.y * w0; acc.z += v0.z * w0; acc.w += v0.w * w0;
        acc.x += v1.x * w1; acc.y += v1.y * w1; acc.z += v1.z * w1; acc.w += v1.w * w1;
        acc.x += v2.x * w2; acc.y += v2.y * w2; acc.z += v2.z * w2; acc.w += v2.w * w2;
        acc.x += v3.x * w3; acc.y += v3.y * w3; acc.z += v3.z * w3; acc.w += v3.w * w3;
    }
    for (; e < e1; e += SPN) {
        int sv = ssrc[e];
        float wgt = dsrc[e] * di;
        float4 v = *(const float4*)(H + (size_t)sv * K + fl4);
        acc.x += v.x * wgt; acc.y += v.y * wgt; acc.z += v.z * wgt; acc.w += v.w * wgt;
    }
    *(float4*)&Hs[st][nl][fl4] = acc;
    __syncthreads();

    int w = tid >> 6, lane = tid & 63;
    int lo = lane & 15, g = lane >> 4;
    constexpr int NCT = DOUT / 16;
    if (w < NCT) {
        const f32x4_t Z = {0.f, 0.f, 0.f, 0.f};
        f32x4_t a = Z;
        int c0 = w * 16;
#pragma unroll
        for (int kk = 0; kk < K / 32; kk++) {
            int ko = kk * 32 + g * 8;
            float4 x0 = *(const float4*)&Hs[0][lo][ko];
            float4 x1 = *(const float4*)&Hs[0][lo][ko + 4];
            if (SPN == 2) {
                float4 y0 = *(const float4*)&Hs[1][lo][ko];
                float4 y1 = *(const float4*)&Hs[1][lo][ko + 4];
                x0.x += y0.x; x0.y += y0.y; x0.z += y0.z; x0.w += y0.w;
                x1.x += y1.x; x1.y += y1.y; x1.z += y1.z; x1.w += y1.w;
            }
            union { unsigned u[4]; bf16x8_t v; } ah, al;
            ah.u[0] = pk2(x0.x, x0.y);
            ah.u[1] = pk2(x0.z, x0.w);
            ah.u[2] = pk2(x1.x, x1.y);
            ah.u[3] = pk2(x1.z, x1.w);
            al.u[0] = pk2(x0.x - lo16f(ah.u[0]), x0.y - hi16f(ah.u[0]));
            al.u[1] = pk2(x0.z - lo16f(ah.u[1]), x0.w - hi16f(ah.u[1]));
            al.u[2] = pk2(x1.x - lo16f(ah.u[2]), x1.y - hi16f(ah.u[2]));
            al.u[3] = pk2(x1.z - lo16f(ah.u[3]), x1.w - hi16f(ah.u[3]));
            size_t wi = (size_t)((kk * 4 + g) * DOUT + c0 + lo) * 8;
            bf16x8_t wh = *(const bf16x8_t*)(Wb + wi);
            bf16x8_t wl = *(const bf16x8_t*)(Wb + WPL + wi);
            a = __builtin_amdgcn_mfma_f32_16x16x32_bf16(ah.v, wh, a, 0, 0, 0);
            a = __builtin_amdgcn_mfma_f32_16x16x32_bf16(al.v, wh, a, 0, 0, 0);
            a = __builtin_amdgcn_mfma_f32_16x16x32_bf16(ah.v, wl, a, 0, 0, 0);
        }
        float bs = bias[c0 + lo];
        int col = c0 + lo;
#pragma unroll
        for (int r = 0; r < 4; r++) {
            float v = a[r] + bs;
            if (RELU) v = fmaxf(v, 0.f);
            int gnode = blockIdx.x * 16 + 4 * g + r;
            size_t o = (size_t)gnode * DOUT + col;
            if (resid) v += resid[o];
            if (outF) outF[o] = v;
            if (outAny) {
                if (*flagp) ((float*)outAny)[(size_t)outOff + o] = v;
                else        ((bf16*)outAny)[(size_t)outOff + o] = __float2bfloat16(v);
            }
        }
    }
}

// ---------------- MFMA GEMM (standalone, for attention projections) ----------------
// OMODE: 0 -> fp32 out + bias; 2 -> qkv: Q (scaled, [8192,64]) | K [8192,64] | VT [64,8192]
template<int K, int DOUT, int OMODE>
__global__ void __launch_bounds__(128) k_mgemm(const float* __restrict__ A,
                                               const bf16* __restrict__ Wb,
                                               const float* __restrict__ bias,
                                               float* __restrict__ outF,
                                               bf16* __restrict__ outH) {
    constexpr int PIECES = DOUT / 32, NKS = K / 32;
    constexpr int WPL = K * DOUT;
    int w = threadIdx.x >> 6, lane = threadIdx.x & 63;
    int lo = lane & 15, g = lane >> 4;
    int wg = blockIdx.x * 2 + w;
    int r0 = (wg / PIECES) * 16;
    int c0 = (wg % PIECES) * 32;
    const f32x4_t Z = {0.f, 0.f, 0.f, 0.f};
    f32x4_t acc[2] = {Z, Z};
#pragma unroll
    for (int kk = 0; kk < NKS; kk++) {
        const float* ap = A + (size_t)(r0 + lo) * K + kk * 32 + g * 8;
        float4 x0 = *(const float4*)ap;
        float4 x1 = *(const float4*)(ap + 4);
        union { unsigned u[4]; bf16x8_t v; } ah, al;
        ah.u[0] = pk2(x0.x, x0.y);
        ah.u[1] = pk2(x0.z, x0.w);
        ah.u[2] = pk2(x1.x, x1.y);
        ah.u[3] = pk2(x1.z, x1.w);
        al.u[0] = pk2(x0.x - lo16f(ah.u[0]), x0.y - hi16f(ah.u[0]));
        al.u[1] = pk2(x0.z - lo16f(ah.u[1]), x0.w - hi16f(ah.u[1]));
        al.u[2] = pk2(x1.x - lo16f(ah.u[2]), x1.y - hi16f(ah.u[2]));
        al.u[3] = pk2(x1.z - lo16f(ah.u[3]), x1.w - hi16f(ah.u[3]));
#pragma unroll
        for (int ct = 0; ct < 2; ct++) {
            size_t wi = (size_t)((kk * 4 + g) * DOUT + c0 + ct * 16 + lo) * 8;
            bf16x8_t wh = *(const bf16x8_t*)(Wb + wi);
            bf16x8_t wl = *(const bf16x8_t*)(Wb + WPL + wi);
            acc[ct] = __builtin_amdgcn_mfma_f32_16x16x32_bf16(ah.v, wh, acc[ct], 0, 0, 0);
            acc[ct] = __builtin_amdgcn_mfma_f32_16x16x32_bf16(al.v, wh, acc[ct], 0, 0, 0);
            acc[ct] = __builtin_amdgcn_mfma_f32_16x16x32_bf16(ah.v, wl, acc[ct], 0, 0, 0);
        }
    }
#pragma unroll
    for (int ct = 0; ct < 2; ct++) {
        int n = c0 + ct * 16 + lo;
        float bs = bias ? bias[n] : 0.f;
#pragma unroll
        for (int r = 0; r < 4; r++) {
            float v = acc[ct][r] + bs;
            int node = r0 + 4 * g + r;
            if (OMODE == 0) {
                outF[(size_t)node * DOUT + n] = v;
            } else {
                if (n < 64) {
                    outH[(size_t)node * 64 + n] = __float2bfloat16(v * QSCALE);
                } else if (n < 128) {
                    outH[524288 + (size_t)node * 64 + (n - 64)] = __float2bfloat16(v);
                } else {
                    outH[1048576 + (size_t)(n - 128) * 8192 + node] = __float2bfloat16(v);
                }
            }
        }
    }
}

// ---------------- MFMA flash attention (R11-proven) ----------------
__global__ void __launch_bounds__(512)
k_flash(const bf16* __restrict__ Qb, const bf16* __restrict__ Kb,
        const bf16* __restrict__ VT, float* __restrict__ Bo) {
    __shared__ unsigned short plds[8][2][16][40];
    __shared__ float redo[8][2][16][16];
    __shared__ float redl[8][2][16];
    int w = threadIdx.x >> 6;
    int lane = threadIdx.x & 63;
    int lo = lane & 15;
    int g = lane >> 4;
    int qt = blockIdx.x & 255;
    int h = blockIdx.x >> 8;
    int q0 = qt * 32;
    int m0base = w * 1024;

    const f32x4_t Z = {0.f, 0.f, 0.f, 0.f};
    bf16x8_t zf;
#pragma unroll
    for (int i = 0; i < 8; i++) zf[i] = 0;

    bf16x8_t qf[2];
#pragma unroll
    for (int s = 0; s < 2; s++) {
        if (g < 2) qf[s] = *(const bf16x8_t*)(Qb + (size_t)(q0 + s * 16 + lo) * 64 + h * 16 + g * 8);
        else       qf[s] = zf;
    }

    f32x4_t oacc[2] = {Z, Z};
    float lr[2] = {0.f, 0.f};
    const bf16* kbase = Kb + h * 16 + g * 8;
    const bf16* vbase = VT + (size_t)(h * 16 + lo) * 8192;

    for (int t = 0; t < 32; t++) {
        int m0 = m0base + t * 32;
        bf16x8_t kf0 = zf, kf1 = zf;
        if (g < 2) {
            kf0 = *(const bf16x8_t*)(kbase + (size_t)m0 * 64);
            kf1 = *(const bf16x8_t*)(kbase + (size_t)(m0 + 16) * 64);
        }
        bf16x8_t vt = *(const bf16x8_t*)(vbase + m0 + 8 * g);
#pragma unroll
        for (int s = 0; s < 2; s++) {
            f32x4_t s0 = __builtin_amdgcn_mfma_f32_16x16x32_bf16(kf0, qf[s], Z, 0, 0, 0);
            f32x4_t s1 = __builtin_amdgcn_mfma_f32_16x16x32_bf16(kf1, qf[s], Z, 0, 0, 0);
            float p0 = __builtin_amdgcn_exp2f(s0[0]);
            float p1 = __builtin_amdgcn_exp2f(s0[1]);
            float p2 = __builtin_amdgcn_exp2f(s0[2]);
            float p3 = __builtin_amdgcn_exp2f(s0[3]);
            float p4 = __builtin_amdgcn_exp2f(s1[0]);
            float p5 = __builtin_amdgcn_exp2f(s1[1]);
            float p6 = __builtin_amdgcn_exp2f(s1[2]);
            float p7 = __builtin_amdgcn_exp2f(s1[3]);
            lr[s] += (((p0 + p1) + (p2 + p3)) + ((p4 + p5) + (p6 + p7)));
            unsigned* dst0 = (unsigned*)&plds[w][s][lo][4 * g];
            dst0[0] = pk2(p0, p1);
            dst0[1] = pk2(p2, p3);
            unsigned* dst1 = (unsigned*)&plds[w][s][lo][16 + 4 * g];
            dst1[0] = pk2(p4, p5);
            dst1[1] = pk2(p6, p7);
            bf16x8_t pf = *(const bf16x8_t*)&plds[w][s][lo][8 * g];
            oacc[s] = __builtin_amdgcn_mfma_f32_16x16x32_bf16(vt, pf, oacc[s], 0, 0, 0);
        }
    }
#pragma unroll
    for (int s = 0; s < 2; s++) {
        float l = lr[s];
        l += __shfl_xor(l, 16);
        l += __shfl_xor(l, 32);
        *(f32x4_t*)&redo[w][s][lo][4 * g] = oacc[s];
        if (g == 0) redl[w][s][lo] = l;
    }
    __syncthreads();
    int tid = threadIdx.x;
    int s2 = tid >> 8, q2 = (tid >> 4) & 15, d2 = tid & 15;
    float o = 0.f, l = 0.f;
#pragma unroll
    for (int ww = 0; ww < 8; ww++) {
        o += redo[ww][s2][q2][d2];
        l += redl[ww][s2][q2];
    }
    Bo[(size_t)(q0 + s2 * 16 + q2) * 64 + h * 16 + d2] = o / l;
}

// ---------------- launch ----------------
extern "C" void kernel_launch(void* const* d_in, const int* in_sizes, int n_in,
                              void* d_out, int out_size, void* d_ws, size_t ws_size,
                              hipStream_t stream) {
    int E = in_sizes[1] / 2;
    const int* ei = (const int*)d_in[1];

    int*   ib = (int*)d_ws;
    float* fb = (float*)d_ws;
    int* cnt    = ib;
    int* rowptr = ib + 8192;
    int* fill   = ib + 16448;
    int* ssrc   = ib + 24640;
    int* flagp  = ib + 286784;
    float* dis  = fb + OFF_DIS;
    float* Bias = fb + OFF_BIAS;
    bf16*  Wb   = (bf16*)(fb + OFF_WB);
    float* dsrc = fb + OFF_DSRC;
    float* X    = fb + OFF_X;
    float* HA   = fb + OFF_HA;
    float* HB   = fb + OFF_HB;
    float* Hz   = fb + OFF_HZ;
    float* Bo   = fb + OFF_BO;
    float* ZA   = fb + OFF_ZA;
    bf16*  Qkv  = (bf16*)(fb + OFF_QKV);   // Qb | Kb(+524288) | VT(+1048576)

    dim3 b512(512), b256(256), b128(128);
    int eb = (E + 255) / 256;

    CvtTab tab;
    auto ent = [&](int i, const void* s, int n, int dst, int mode, int p0, int p1) {
        tab.e[i] = CvtEnt{s, n, dst, mode, p0, p1};
    };
    ent(0,  d_in[0],  524288, OFF_X, 0, 0, 0);
    ent(1,  d_in[2],  8192,  HS_E1, 2, 128, 0);
    ent(2,  d_in[3],  128,   OFF_BIAS + BF_E1, 0, 0, 0);
    ent(3,  d_in[4],  16384, HS_E2, 2, 128, 0);
    ent(4,  d_in[5],  128,   OFF_BIAS + BF_E2, 0, 0, 0);
    ent(5,  d_in[6],  16384, HS_E3, 2, 128, 0);
    ent(6,  d_in[7],  128,   OFF_BIAS + BF_E3, 0, 0, 0);
    ent(7,  d_in[8],  8192,  HS_E4, 2, 64, 0);
    ent(8,  d_in[9],  64,    OFF_BIAS + BF_E4, 0, 0, 0);
    ent(9,  d_in[10], 8192,  HS_D1, 2, 128, 0);
    ent(10, d_in[11], 128,   OFF_BIAS + BF_D1, 0, 0, 0);
    ent(11, d_in[12], 16384, HS_D2, 2, 128, 0);
    ent(12, d_in[13], 128,   OFF_BIAS + BF_D2, 0, 0, 0);
    ent(13, d_in[14], 16384, HS_D3, 2, 128, 0);
    ent(14, d_in[15], 128,   OFF_BIAS + BF_D3, 0, 0, 0);
    ent(15, d_in[16], 8192,  HS_D4, 2, 64, 0);
    ent(16, d_in[17], 64,    OFF_BIAS + BF_D4, 0, 0, 0);
    ent(17, d_in[18], 12288, HS_AI, 3, 0, 192);
    ent(18, d_in[19], 192,   OFF_BIAS + BF_AI, 0, 0, 0);
    ent(19, d_in[20], 4096,  HS_AO, 3, 0, 64);
    ent(20, d_in[21], 64,    OFF_BIAS + BF_AO, 0, 0, 0);
    k_convert<<<dim3(2501), b256, 0, stream>>>(tab, fb, Wb, flagp,
                                               (const unsigned short*)d_in[0]);

    hipMemsetAsync(cnt, 0, 8192 * sizeof(int), stream);
    k_count<<<dim3(eb), b256, 0, stream>>>(ei, E, cnt);
    k_scan<<<dim3(1), b256, 0, stream>>>(cnt, rowptr, fill, dis);
    k_scatter<<<dim3(eb), b256, 0, stream>>>(ei, E, fill, ssrc, dis, dsrc);

    dim3 g512(512), g1024(1024);
    dim3 gm64(512), gm192(1536);

    // encoder (all layers fused agg->gemm; reassociated, exact)
    k_fused<64, 128, 1><<<g512, b512, 0, stream>>>(X, rowptr, ssrc, dsrc, dis,
        Wb + HS_E1, Bias + BF_E1, nullptr, HA, nullptr, 0, flagp);
    k_fused<128, 128, 1><<<g512, b512, 0, stream>>>(HA, rowptr, ssrc, dsrc, dis,
        Wb + HS_E2, Bias + BF_E2, HA, HB, nullptr, 0, flagp);
    k_fused<128, 128, 1><<<g512, b512, 0, stream>>>(HB, rowptr, ssrc, dsrc, dis,
        Wb + HS_E3, Bias + BF_E3, HB, HA, nullptr, 0, flagp);
    k_fused<128, 64, 0><<<g512, b512, 0, stream>>>(HA, rowptr, ssrc, dsrc, dis,
        Wb + HS_E4, Bias + BF_E4, nullptr, Hz, d_out, 524288, flagp);

    // attention
    k_mgemm<64, 192, 2><<<gm192, b128, 0, stream>>>(Hz, Wb + HS_AI, Bias + BF_AI, nullptr, Qkv);
    k_flash<<<g1024, b512, 0, stream>>>(Qkv, Qkv + 524288, Qkv + 1048576, Bo);
    k_mgemm<64, 64, 0><<<gm64, b128, 0, stream>>>(Bo, Wb + HS_AO, Bias + BF_AO, ZA, nullptr);

    // decoder
    k_fused<64, 128, 1><<<g512, b512, 0, stream>>>(ZA, rowptr, ssrc, dsrc, dis,
        Wb + HS_D1, Bias + BF_D1, nullptr, HA, nullptr, 0, flagp);
    k_fused<128, 128, 1><<<g512, b512, 0, stream>>>(HA, rowptr, ssrc, dsrc, dis,
        Wb + HS_D2, Bias + BF_D2, HA, HB, nullptr, 0, flagp);
    k_fused<128, 128, 1><<<g512, b512, 0, stream>>>(HB, rowptr, ssrc, dsrc, dis,
        Wb + HS_D3, Bias + BF_D3, HB, HA, nullptr, 0, flagp);
    k_fused<128, 64, 0><<<g512, b512, 0, stream>>>(HA, rowptr, ssrc, dsrc, dis,
        Wb + HS_D4, Bias + BF_D4, nullptr, nullptr, d_out, 0, flagp);
}

// Round 14
// 308.399 us; speedup vs baseline: 4.0326x; 1.0224x over previous
//
#include <hip/hip_runtime.h>
#include <hip/hip_bf16.h>

using bf16 = __hip_bfloat16;

typedef __attribute__((ext_vector_type(8))) short bf16x8_t;   // 8 bf16 in 4 VGPRs
typedef __attribute__((ext_vector_type(4))) float f32x4_t;

static __device__ __forceinline__ float b2f(bf16 v) { return __bfloat162float(v); }

// pack two fp32 -> 2 bf16 (RNE) via v_cvt_pk_bf16_f32
static __device__ __forceinline__ unsigned pk2(float a, float b) {
    __hip_bfloat162 h = __float22bfloat162_rn(make_float2(a, b));
    return *reinterpret_cast<unsigned*>(&h);
}
static __device__ __forceinline__ float lo16f(unsigned u) { return __uint_as_float(u << 16); }
static __device__ __forceinline__ float hi16f(unsigned u) { return __uint_as_float(u & 0xFFFF0000u); }

// log2(e)/4 : folds 1/sqrt(DH) and exp->exp2. Applied at qkv GEMM output (fp32).
#define QSCALE 0.36067376022224085f

// ---------------- workspace layout (float offsets) ----------------
// ints: cnt[0,8192) rowptr[8192,16385) fill[16448,24640) ssrc[24640,286784) flag ib[286784]
#define OFF_DIS  286848
#define OFF_BIAS 295040   /* 1152 fp32 */
#define OFF_WB   296192   /* bf16 weights (split hi+lo), 229376 shorts = 114688 floats */
#define OFF_DSRC 410880   /* fp32 edge weights [262144] */
#define OFF_X    935168   /* fp32 x [8192,64] */
#define OFF_HA   1983744  /* fp32 act [8192,128] */
#define OFF_HB   3032320  /* fp32 act [8192,128] */
#define OFF_HZ   4080896  /* fp32 z [8192,64] */
#define OFF_BO   4605184  /* fp32 attention out [8192,64] */
#define OFF_ZA   5129472  /* fp32 za [8192,64] */
#define OFF_QKV  5653760  /* bf16: Qb[8192*64] | Kb[8192*64] | VT[64*8192] = 786432 f slots */
// total 6440192 floats = 25.76 MB

// weight short-offsets (relative to OFF_WB as bf16*), each region hi plane then lo plane
#define HS_E1 0
#define HS_E2 16384
#define HS_E3 49152
#define HS_E4 81920
#define HS_D1 98304
#define HS_D2 114688
#define HS_D3 147456
#define HS_D4 180224
#define HS_AI 196608
#define HS_AO 221184

// bias fp32 offsets (relative to OFF_BIAS)
#define BF_E1 0
#define BF_E2 128
#define BF_E3 256
#define BF_E4 384
#define BF_D1 448
#define BF_D2 576
#define BF_D3 704
#define BF_D4 832
#define BF_AI 896
#define BF_AO 1088

// ---------------- input canonicalization (sniff + edge-count fused) ----------------
struct CvtEnt { const void* src; int n; int dst; int mode; int p0; int p1; };
struct CvtTab { CvtEnt e[21]; };

__global__ void k_convert(CvtTab tab, float* __restrict__ fb, bf16* __restrict__ hb,
                          int* __restrict__ flagp, const unsigned short* __restrict__ xb,
                          const int* __restrict__ ei, int E, int* __restrict__ cnt) {
    __shared__ int wsum[4];
    unsigned short wv = xb[threadIdx.x * 2];
    int ex = (wv >> 7) & 0xFF;
    int mn = wv & 0x7F;
    int weird = (ex >= 134) || (ex != 0 && ex <= 90) || (ex == 0 && mn != 0);
    unsigned long long bal = __ballot(weird);
    if ((threadIdx.x & 63) == 0) wsum[threadIdx.x >> 6] = (int)__popcll(bal);
    __syncthreads();
    int fl = ((wsum[0] + wsum[1]) + (wsum[2] + wsum[3])) >= 32 ? 1 : 0;   // 1 => fp32
    if (blockIdx.x == 0 && threadIdx.x == 0) *flagp = fl;

    int gi = blockIdx.x * blockDim.x + threadIdx.x;
    if (gi < E) atomicAdd(&cnt[ei[E + gi]], 1);   // fused degree count

    int i = gi;
#pragma unroll 1
    for (int t = 0; t < 21; t++) {
        int n = tab.e[t].n;
        if (i < n) {
            float v = fl ? ((const float*)tab.e[t].src)[i]
                         : b2f(((const bf16*)tab.e[t].src)[i]);
            int mode = tab.e[t].mode, dst = tab.e[t].dst;
            if (mode == 0) {
                fb[dst + i] = v;
            } else {
                int idx;
                if (mode == 2) {
                    int dout = tab.e[t].p0;
                    int r = i / dout, c = i - r * dout;
                    idx = ((r >> 3) * dout + c) * 8 + (r & 7);
                } else {
                    int r = i >> 6, c = i & 63;       // r = n_eff, c = k_eff
                    idx = ((c >> 3) * tab.e[t].p1 + r) * 8 + (c & 7);
                }
                bf16 hv = __float2bfloat16(v);
                hb[dst + idx] = hv;
                hb[dst + n + idx] = __float2bfloat16(v - b2f(hv));
            }
            return;
        }
        i -= n;
    }
}

// ---------------- CSR construction ----------------
__global__ void k_scan(const int* __restrict__ cnt, int* __restrict__ rowptr,
                       int* __restrict__ fill, float* __restrict__ dis) {
    __shared__ int sums[256];
    int t = threadIdx.x;
    int base = t * 32;
    int s = 0;
#pragma unroll
    for (int i = 0; i < 32; i++) s += cnt[base + i];
    sums[t] = s;
    __syncthreads();
    for (int off = 1; off < 256; off <<= 1) {
        int v = (t >= off) ? sums[t - off] : 0;
        __syncthreads();
        sums[t] += v;
        __syncthreads();
    }
    int run = (t == 0) ? 0 : sums[t - 1];
#pragma unroll
    for (int i = 0; i < 32; i++) {
        int idx = base + i;
        rowptr[idx] = run;
        fill[idx] = run;
        dis[idx] = rsqrtf((float)(cnt[idx] + 1));
        run += cnt[idx];
    }
    if (t == 255) rowptr[8192] = run;
}

__global__ void k_scatter(const int* __restrict__ ei, int E,
                          int* __restrict__ fill, int* __restrict__ ssrc,
                          const float* __restrict__ dis, float* __restrict__ dsrc) {
    int e = blockIdx.x * blockDim.x + threadIdx.x;
    if (e < E) {
        int s = ei[e];
        int pos = atomicAdd(&fill[ei[E + e]], 1);
        ssrc[pos] = s;
        dsrc[pos] = dis[s];
    }
}

// ---------------- FUSED GCN layer: agg(H) in LDS -> MFMA @ W -> bias/relu/resid ----------
// Block = 16 nodes, BS threads (1024 for K=128 -> 2 edge streams/node; 512 for K=64).
// Gather: groups of K/4 lanes fetch float4 rows, SPN=2 streams/node, unroll 4.
// Gemm: wave w<NCT -> 16-col tile; A = Hs[0]+Hs[1] from LDS (stride K+4: 16B-aligned,
// 2-way bank aliasing = free). 3 MFMAs/tile hi/lo split.
template<int K, int DOUT, int RELU, int BS>
__global__ void __launch_bounds__(BS)
k_fused(const float* __restrict__ H, const int* __restrict__ rowptr,
        const int* __restrict__ ssrc, const float* __restrict__ dsrc,
        const float* __restrict__ dis, const bf16* __restrict__ Wb,
        const float* __restrict__ bias, const float* __restrict__ resid,
        float* __restrict__ outF, void* __restrict__ outAny, int outOff,
        const int* __restrict__ flagp) {
    constexpr int LPR = K / 4;          // lanes per row-gather group
    constexpr int NG  = BS / LPR;       // gather groups
    constexpr int SPN = NG / 16;        // edge streams per node (2 in both configs)
    constexpr int PADK = K + 4;
    constexpr int WPL = K * DOUT;
    __shared__ float Hs[SPN][16][PADK];

    int tid = threadIdx.x;
    int gp = tid / LPR;
    int li = tid - gp * LPR;
    int fl4 = li * 4;
    int nl = gp / SPN;
    int st = gp - nl * SPN;
    int node = blockIdx.x * 16 + nl;

    float di = dis[node];
    int e0 = rowptr[node], e1 = rowptr[node + 1];
    float4 acc = {0.f, 0.f, 0.f, 0.f};
    if (st == 0) {
        float dii = di * di;
        float4 sv = *(const float4*)(H + (size_t)node * K + fl4);
        acc.x = sv.x * dii; acc.y = sv.y * dii; acc.z = sv.z * dii; acc.w = sv.w * dii;
    }
    int e = e0 + st;
    for (; e + 3 * SPN < e1; e += 4 * SPN) {
        int s0 = ssrc[e], s1 = ssrc[e + SPN], s2 = ssrc[e + 2 * SPN], s3 = ssrc[e + 3 * SPN];
        float w0 = dsrc[e] * di, w1 = dsrc[e + SPN] * di;
        float w2 = dsrc[e + 2 * SPN] * di, w3 = dsrc[e + 3 * SPN] * di;
        float4 v0 = *(const float4*)(H + (size_t)s0 * K + fl4);
        float4 v1 = *(const float4*)(H + (size_t)s1 * K + fl4);
        float4 v2 = *(const float4*)(H + (size_t)s2 * K + fl4);
        float4 v3 = *(const float4*)(H + (size_t)s3 * K + fl4);
        acc.x += v0.x * w0; acc.y += v0.y * w0; acc.z += v0.z * w0; acc.w += v0.w * w0;
        acc.x += v1.x * w1; acc.y += v1.y * w1; acc.z += v1.z * w1; acc.w += v1.w * w1;
        acc.x += v2.x * w2; acc.y += v2.y * w2; acc.z += v2.z * w2; acc.w += v2.w * w2;
        acc.x += v3.x * w3; acc.y += v3.y * w3; acc.z += v3.z * w3; acc.w += v3.w * w3;
    }
    for (; e < e1; e += SPN) {
        int sv = ssrc[e];
        float wgt = dsrc[e] * di;
        float4 v = *(const float4*)(H + (size_t)sv * K + fl4);
        acc.x += v.x * wgt; acc.y += v.y * wgt; acc.z += v.z * wgt; acc.w += v.w * wgt;
    }
    *(float4*)&Hs[st][nl][fl4] = acc;
    __syncthreads();

    int w = tid >> 6, lane = tid & 63;
    int lo = lane & 15, g = lane >> 4;
    constexpr int NCT = DOUT / 16;
    if (w < NCT) {
        const f32x4_t Z = {0.f, 0.f, 0.f, 0.f};
        f32x4_t a = Z;
        int c0 = w * 16;
#pragma unroll
        for (int kk = 0; kk < K / 32; kk++) {
            int ko = kk * 32 + g * 8;
            float4 x0 = *(const float4*)&Hs[0][lo][ko];
            float4 x1 = *(const float4*)&Hs[0][lo][ko + 4];
            float4 y0 = *(const float4*)&Hs[1][lo][ko];
            float4 y1 = *(const float4*)&Hs[1][lo][ko + 4];
            x0.x += y0.x; x0.y += y0.y; x0.z += y0.z; x0.w += y0.w;
            x1.x += y1.x; x1.y += y1.y; x1.z += y1.z; x1.w += y1.w;
            union { unsigned u[4]; bf16x8_t v; } ah, al;
            ah.u[0] = pk2(x0.x, x0.y);
            ah.u[1] = pk2(x0.z, x0.w);
            ah.u[2] = pk2(x1.x, x1.y);
            ah.u[3] = pk2(x1.z, x1.w);
            al.u[0] = pk2(x0.x - lo16f(ah.u[0]), x0.y - hi16f(ah.u[0]));
            al.u[1] = pk2(x0.z - lo16f(ah.u[1]), x0.w - hi16f(ah.u[1]));
            al.u[2] = pk2(x1.x - lo16f(ah.u[2]), x1.y - hi16f(ah.u[2]));
            al.u[3] = pk2(x1.z - lo16f(ah.u[3]), x1.w - hi16f(ah.u[3]));
            size_t wi = (size_t)((kk * 4 + g) * DOUT + c0 + lo) * 8;
            bf16x8_t wh = *(const bf16x8_t*)(Wb + wi);
            bf16x8_t wl = *(const bf16x8_t*)(Wb + WPL + wi);
            a = __builtin_amdgcn_mfma_f32_16x16x32_bf16(ah.v, wh, a, 0, 0, 0);
            a = __builtin_amdgcn_mfma_f32_16x16x32_bf16(al.v, wh, a, 0, 0, 0);
            a = __builtin_amdgcn_mfma_f32_16x16x32_bf16(ah.v, wl, a, 0, 0, 0);
        }
        float bs = bias[c0 + lo];
        int col = c0 + lo;
#pragma unroll
        for (int r = 0; r < 4; r++) {
            float v = a[r] + bs;
            if (RELU) v = fmaxf(v, 0.f);
            int gnode = blockIdx.x * 16 + 4 * g + r;
            size_t o = (size_t)gnode * DOUT + col;
            if (resid) v += resid[o];
            if (outF) outF[o] = v;
            if (outAny) {
                if (*flagp) ((float*)outAny)[(size_t)outOff + o] = v;
                else        ((bf16*)outAny)[(size_t)outOff + o] = __float2bfloat16(v);
            }
        }
    }
}

// ---------------- MFMA GEMM (standalone, for attention projections) ----------------
// OMODE: 0 -> fp32 out + bias; 2 -> qkv: Q (scaled, [8192,64]) | K [8192,64] | VT [64,8192]
template<int K, int DOUT, int OMODE>
__global__ void __launch_bounds__(128) k_mgemm(const float* __restrict__ A,
                                               const bf16* __restrict__ Wb,
                                               const float* __restrict__ bias,
                                               float* __restrict__ outF,
                                               bf16* __restrict__ outH) {
    constexpr int PIECES = DOUT / 32, NKS = K / 32;
    constexpr int WPL = K * DOUT;
    int w = threadIdx.x >> 6, lane = threadIdx.x & 63;
    int lo = lane & 15, g = lane >> 4;
    int wg = blockIdx.x * 2 + w;
    int r0 = (wg / PIECES) * 16;
    int c0 = (wg % PIECES) * 32;
    const f32x4_t Z = {0.f, 0.f, 0.f, 0.f};
    f32x4_t acc[2] = {Z, Z};
#pragma unroll
    for (int kk = 0; kk < NKS; kk++) {
        const float* ap = A + (size_t)(r0 + lo) * K + kk * 32 + g * 8;
        float4 x0 = *(const float4*)ap;
        float4 x1 = *(const float4*)(ap + 4);
        union { unsigned u[4]; bf16x8_t v; } ah, al;
        ah.u[0] = pk2(x0.x, x0.y);
        ah.u[1] = pk2(x0.z, x0.w);
        ah.u[2] = pk2(x1.x, x1.y);
        ah.u[3] = pk2(x1.z, x1.w);
        al.u[0] = pk2(x0.x - lo16f(ah.u[0]), x0.y - hi16f(ah.u[0]));
        al.u[1] = pk2(x0.z - lo16f(ah.u[1]), x0.w - hi16f(ah.u[1]));
        al.u[2] = pk2(x1.x - lo16f(ah.u[2]), x1.y - hi16f(ah.u[2]));
        al.u[3] = pk2(x1.z - lo16f(ah.u[3]), x1.w - hi16f(ah.u[3]));
#pragma unroll
        for (int ct = 0; ct < 2; ct++) {
            size_t wi = (size_t)((kk * 4 + g) * DOUT + c0 + ct * 16 + lo) * 8;
            bf16x8_t wh = *(const bf16x8_t*)(Wb + wi);
            bf16x8_t wl = *(const bf16x8_t*)(Wb + WPL + wi);
            acc[ct] = __builtin_amdgcn_mfma_f32_16x16x32_bf16(ah.v, wh, acc[ct], 0, 0, 0);
            acc[ct] = __builtin_amdgcn_mfma_f32_16x16x32_bf16(al.v, wh, acc[ct], 0, 0, 0);
            acc[ct] = __builtin_amdgcn_mfma_f32_16x16x32_bf16(ah.v, wl, acc[ct], 0, 0, 0);
        }
    }
#pragma unroll
    for (int ct = 0; ct < 2; ct++) {
        int n = c0 + ct * 16 + lo;
        float bs = bias ? bias[n] : 0.f;
#pragma unroll
        for (int r = 0; r < 4; r++) {
            float v = acc[ct][r] + bs;
            int node = r0 + 4 * g + r;
            if (OMODE == 0) {
                outF[(size_t)node * DOUT + n] = v;
            } else {
                if (n < 64) {
                    outH[(size_t)node * 64 + n] = __float2bfloat16(v * QSCALE);
                } else if (n < 128) {
                    outH[524288 + (size_t)node * 64 + (n - 64)] = __float2bfloat16(v);
                } else {
                    outH[1048576 + (size_t)(n - 128) * 8192 + node] = __float2bfloat16(v);
                }
            }
        }
    }
}

// ---------------- MFMA flash attention (R11-proven) ----------------
__global__ void __launch_bounds__(512)
k_flash(const bf16* __restrict__ Qb, const bf16* __restrict__ Kb,
        const bf16* __restrict__ VT, float* __restrict__ Bo) {
    __shared__ unsigned short plds[8][2][16][40];
    __shared__ float redo[8][2][16][16];
    __shared__ float redl[8][2][16];
    int w = threadIdx.x >> 6;
    int lane = threadIdx.x & 63;
    int lo = lane & 15;
    int g = lane >> 4;
    int qt = blockIdx.x & 255;
    int h = blockIdx.x >> 8;
    int q0 = qt * 32;
    int m0base = w * 1024;

    const f32x4_t Z = {0.f, 0.f, 0.f, 0.f};
    bf16x8_t zf;
#pragma unroll
    for (int i = 0; i < 8; i++) zf[i] = 0;

    bf16x8_t qf[2];
#pragma unroll
    for (int s = 0; s < 2; s++) {
        if (g < 2) qf[s] = *(const bf16x8_t*)(Qb + (size_t)(q0 + s * 16 + lo) * 64 + h * 16 + g * 8);
        else       qf[s] = zf;
    }

    f32x4_t oacc[2] = {Z, Z};
    float lr[2] = {0.f, 0.f};
    const bf16* kbase = Kb + h * 16 + g * 8;
    const bf16* vbase = VT + (size_t)(h * 16 + lo) * 8192;

    for (int t = 0; t < 32; t++) {
        int m0 = m0base + t * 32;
        bf16x8_t kf0 = zf, kf1 = zf;
        if (g < 2) {
            kf0 = *(const bf16x8_t*)(kbase + (size_t)m0 * 64);
            kf1 = *(const bf16x8_t*)(kbase + (size_t)(m0 + 16) * 64);
        }
        bf16x8_t vt = *(const bf16x8_t*)(vbase + m0 + 8 * g);
#pragma unroll
        for (int s = 0; s < 2; s++) {
            f32x4_t s0 = __builtin_amdgcn_mfma_f32_16x16x32_bf16(kf0, qf[s], Z, 0, 0, 0);
            f32x4_t s1 = __builtin_amdgcn_mfma_f32_16x16x32_bf16(kf1, qf[s], Z, 0, 0, 0);
            float p0 = __builtin_amdgcn_exp2f(s0[0]);
            float p1 = __builtin_amdgcn_exp2f(s0[1]);
            float p2 = __builtin_amdgcn_exp2f(s0[2]);
            float p3 = __builtin_amdgcn_exp2f(s0[3]);
            float p4 = __builtin_amdgcn_exp2f(s1[0]);
            float p5 = __builtin_amdgcn_exp2f(s1[1]);
            float p6 = __builtin_amdgcn_exp2f(s1[2]);
            float p7 = __builtin_amdgcn_exp2f(s1[3]);
            lr[s] += (((p0 + p1) + (p2 + p3)) + ((p4 + p5) + (p6 + p7)));
            unsigned* dst0 = (unsigned*)&plds[w][s][lo][4 * g];
            dst0[0] = pk2(p0, p1);
            dst0[1] = pk2(p2, p3);
            unsigned* dst1 = (unsigned*)&plds[w][s][lo][16 + 4 * g];
            dst1[0] = pk2(p4, p5);
            dst1[1] = pk2(p6, p7);
            bf16x8_t pf = *(const bf16x8_t*)&plds[w][s][lo][8 * g];
            oacc[s] = __builtin_amdgcn_mfma_f32_16x16x32_bf16(vt, pf, oacc[s], 0, 0, 0);
        }
    }
#pragma unroll
    for (int s = 0; s < 2; s++) {
        float l = lr[s];
        l += __shfl_xor(l, 16);
        l += __shfl_xor(l, 32);
        *(f32x4_t*)&redo[w][s][lo][4 * g] = oacc[s];
        if (g == 0) redl[w][s][lo] = l;
    }
    __syncthreads();
    int tid = threadIdx.x;
    int s2 = tid >> 8, q2 = (tid >> 4) & 15, d2 = tid & 15;
    float o = 0.f, l = 0.f;
#pragma unroll
    for (int ww = 0; ww < 8; ww++) {
        o += redo[ww][s2][q2][d2];
        l += redl[ww][s2][q2];
    }
    Bo[(size_t)(q0 + s2 * 16 + q2) * 64 + h * 16 + d2] = o / l;
}

// ---------------- launch ----------------
extern "C" void kernel_launch(void* const* d_in, const int* in_sizes, int n_in,
                              void* d_out, int out_size, void* d_ws, size_t ws_size,
                              hipStream_t stream) {
    int E = in_sizes[1] / 2;
    const int* ei = (const int*)d_in[1];

    int*   ib = (int*)d_ws;
    float* fb = (float*)d_ws;
    int* cnt    = ib;
    int* rowptr = ib + 8192;
    int* fill   = ib + 16448;
    int* ssrc   = ib + 24640;
    int* flagp  = ib + 286784;
    float* dis  = fb + OFF_DIS;
    float* Bias = fb + OFF_BIAS;
    bf16*  Wb   = (bf16*)(fb + OFF_WB);
    float* dsrc = fb + OFF_DSRC;
    float* X    = fb + OFF_X;
    float* HA   = fb + OFF_HA;
    float* HB   = fb + OFF_HB;
    float* Hz   = fb + OFF_HZ;
    float* Bo   = fb + OFF_BO;
    float* ZA   = fb + OFF_ZA;
    bf16*  Qkv  = (bf16*)(fb + OFF_QKV);   // Qb | Kb(+524288) | VT(+1048576)

    dim3 b1024(1024), b512(512), b256(256), b128(128);
    int eb = (E + 255) / 256;

    CvtTab tab;
    auto ent = [&](int i, const void* s, int n, int dst, int mode, int p0, int p1) {
        tab.e[i] = CvtEnt{s, n, dst, mode, p0, p1};
    };
    ent(0,  d_in[0],  524288, OFF_X, 0, 0, 0);
    ent(1,  d_in[2],  8192,  HS_E1, 2, 128, 0);
    ent(2,  d_in[3],  128,   OFF_BIAS + BF_E1, 0, 0, 0);
    ent(3,  d_in[4],  16384, HS_E2, 2, 128, 0);
    ent(4,  d_in[5],  128,   OFF_BIAS + BF_E2, 0, 0, 0);
    ent(5,  d_in[6],  16384, HS_E3, 2, 128, 0);
    ent(6,  d_in[7],  128,   OFF_BIAS + BF_E3, 0, 0, 0);
    ent(7,  d_in[8],  8192,  HS_E4, 2, 64, 0);
    ent(8,  d_in[9],  64,    OFF_BIAS + BF_E4, 0, 0, 0);
    ent(9,  d_in[10], 8192,  HS_D1, 2, 128, 0);
    ent(10, d_in[11], 128,   OFF_BIAS + BF_D1, 0, 0, 0);
    ent(11, d_in[12], 16384, HS_D2, 2, 128, 0);
    ent(12, d_in[13], 128,   OFF_BIAS + BF_D2, 0, 0, 0);
    ent(13, d_in[14], 16384, HS_D3, 2, 128, 0);
    ent(14, d_in[15], 128,   OFF_BIAS + BF_D3, 0, 0, 0);
    ent(15, d_in[16], 8192,  HS_D4, 2, 64, 0);
    ent(16, d_in[17], 64,    OFF_BIAS + BF_D4, 0, 0, 0);
    ent(17, d_in[18], 12288, HS_AI, 3, 0, 192);
    ent(18, d_in[19], 192,   OFF_BIAS + BF_AI, 0, 0, 0);
    ent(19, d_in[20], 4096,  HS_AO, 3, 0, 64);
    ent(20, d_in[21], 64,    OFF_BIAS + BF_AO, 0, 0, 0);

    hipMemsetAsync(cnt, 0, 8192 * sizeof(int), stream);
    k_convert<<<dim3(2501), b256, 0, stream>>>(tab, fb, Wb, flagp,
                                               (const unsigned short*)d_in[0], ei, E, cnt);
    k_scan<<<dim3(1), b256, 0, stream>>>(cnt, rowptr, fill, dis);
    k_scatter<<<dim3(eb), b256, 0, stream>>>(ei, E, fill, ssrc, dis, dsrc);

    dim3 g512(512), g1024(1024);
    dim3 gm64(512), gm192(1536);

    // encoder (fused agg->gemm layers; 1024-thr blocks for K=128 -> 2 streams/node)
    k_fused<64, 128, 1, 512><<<g512, b512, 0, stream>>>(X, rowptr, ssrc, dsrc, dis,
        Wb + HS_E1, Bias + BF_E1, nullptr, HA, nullptr, 0, flagp);
    k_fused<128, 128, 1, 1024><<<g512, b1024, 0, stream>>>(HA, rowptr, ssrc, dsrc, dis,
        Wb + HS_E2, Bias + BF_E2, HA, HB, nullptr, 0, flagp);
    k_fused<128, 128, 1, 1024><<<g512, b1024, 0, stream>>>(HB, rowptr, ssrc, dsrc, dis,
        Wb + HS_E3, Bias + BF_E3, HB, HA, nullptr, 0, flagp);
    k_fused<128, 64, 0, 1024><<<g512, b1024, 0, stream>>>(HA, rowptr, ssrc, dsrc, dis,
        Wb + HS_E4, Bias + BF_E4, nullptr, Hz, d_out, 524288, flagp);

    // attention
    k_mgemm<64, 192, 2><<<gm192, b128, 0, stream>>>(Hz, Wb + HS_AI, Bias + BF_AI, nullptr, Qkv);
    k_flash<<<g1024, b512, 0, stream>>>(Qkv, Qkv + 524288, Qkv + 1048576, Bo);
    k_mgemm<64, 64, 0><<<gm64, b128, 0, stream>>>(Bo, Wb + HS_AO, Bias + BF_AO, ZA, nullptr);

    // decoder
    k_fused<64, 128, 1, 512><<<g512, b512, 0, stream>>>(ZA, rowptr, ssrc, dsrc, dis,
        Wb + HS_D1, Bias + BF_D1, nullptr, HA, nullptr, 0, flagp);
    k_fused<128, 128, 1, 1024><<<g512, b1024, 0, stream>>>(HA, rowptr, ssrc, dsrc, dis,
        Wb + HS_D2, Bias + BF_D2, HA, HB, nullptr, 0, flagp);
    k_fused<128, 128, 1, 1024><<<g512, b1024, 0, stream>>>(HB, rowptr, ssrc, dsrc, dis,
        Wb + HS_D3, Bias + BF_D3, HB, HA, nullptr, 0, flagp);
    k_fused<128, 64, 0, 1024><<<g512, b1024, 0, stream>>>(HA, rowptr, ssrc, dsrc, dis,
        Wb + HS_D4, Bias + BF_D4, nullptr, nullptr, d_out, 0, flagp);
}

// Round 16
// 300.520 us; speedup vs baseline: 4.1383x; 1.0262x over previous
//
#include <hip/hip_runtime.h>
#include <hip/hip_bf16.h>

using bf16 = __hip_bfloat16;

typedef __attribute__((ext_vector_type(8))) short bf16x8_t;   // 8 bf16 in 4 VGPRs
typedef __attribute__((ext_vector_type(4))) float f32x4_t;

static __device__ __forceinline__ float b2f(bf16 v) { return __bfloat162float(v); }

// pack two fp32 -> 2 bf16 (RNE) via v_cvt_pk_bf16_f32
static __device__ __forceinline__ unsigned pk2(float a, float b) {
    __hip_bfloat162 h = __float22bfloat162_rn(make_float2(a, b));
    return *reinterpret_cast<unsigned*>(&h);
}
static __device__ __forceinline__ float lo16f(unsigned u) { return __uint_as_float(u << 16); }
static __device__ __forceinline__ float hi16f(unsigned u) { return __uint_as_float(u & 0xFFFF0000u); }

// log2(e)/4 : folds 1/sqrt(DH) and exp->exp2. Applied at qkv output (fp32).
#define QSCALE 0.36067376022224085f

// ---------------- workspace layout (float offsets) ----------------
// ints: cnt[0,8192) rowptr[8192,16385) fill[16448,24640) ssrc[24640,286784) flag ib[286784]
#define OFF_DIS  286848
#define OFF_BIAS 295040   /* 1152 fp32 */
#define OFF_WB   296192   /* bf16 weights (split hi+lo), 229376 shorts = 114688 floats */
#define OFF_DSRC 410880   /* fp32 edge weights [262144] */
#define OFF_X    935168   /* fp32 x [8192,64] */
#define OFF_HA   1983744  /* fp32 act [8192,128] */
#define OFF_HB   3032320  /* fp32 act [8192,128] */
#define OFF_BO   4605184  /* fp32 attention out [8192,64] */
#define OFF_QKV  5653760  /* bf16: Qb[8192*64] | Kb[8192*64] | VT[64*8192] = 786432 f slots */
// total 6440192 floats = 25.76 MB

// weight short-offsets (relative to OFF_WB as bf16*), each region hi plane then lo plane
#define HS_E1 0
#define HS_E2 16384
#define HS_E3 49152
#define HS_E4 81920
#define HS_D1 98304
#define HS_D2 114688
#define HS_D3 147456
#define HS_D4 180224
#define HS_AI 196608
#define HS_AO 221184

// bias fp32 offsets (relative to OFF_BIAS)
#define BF_E1 0
#define BF_E2 128
#define BF_E3 256
#define BF_E4 384
#define BF_D1 448
#define BF_D2 576
#define BF_D3 704
#define BF_D4 832
#define BF_AI 896
#define BF_AO 1088

// ---------------- input canonicalization (sniff + edge-count fused) ----------------
struct CvtEnt { const void* src; int n; int dst; int mode; int p0; int p1; };
struct CvtTab { CvtEnt e[21]; };

__global__ void k_convert(CvtTab tab, float* __restrict__ fb, bf16* __restrict__ hb,
                          int* __restrict__ flagp, const unsigned short* __restrict__ xb,
                          const int* __restrict__ ei, int E, int* __restrict__ cnt) {
    __shared__ int wsum[4];
    unsigned short wv = xb[threadIdx.x * 2];
    int ex = (wv >> 7) & 0xFF;
    int mn = wv & 0x7F;
    int weird = (ex >= 134) || (ex != 0 && ex <= 90) || (ex == 0 && mn != 0);
    unsigned long long bal = __ballot(weird);
    if ((threadIdx.x & 63) == 0) wsum[threadIdx.x >> 6] = (int)__popcll(bal);
    __syncthreads();
    int fl = ((wsum[0] + wsum[1]) + (wsum[2] + wsum[3])) >= 32 ? 1 : 0;   // 1 => fp32
    if (blockIdx.x == 0 && threadIdx.x == 0) *flagp = fl;

    int gi = blockIdx.x * blockDim.x + threadIdx.x;
    if (gi < E) atomicAdd(&cnt[ei[E + gi]], 1);   // fused degree count

    int i = gi;
#pragma unroll 1
    for (int t = 0; t < 21; t++) {
        int n = tab.e[t].n;
        if (i < n) {
            float v = fl ? ((const float*)tab.e[t].src)[i]
                         : b2f(((const bf16*)tab.e[t].src)[i]);
            int mode = tab.e[t].mode, dst = tab.e[t].dst;
            if (mode == 0) {
                fb[dst + i] = v;
            } else {
                int idx;
                if (mode == 2) {
                    int dout = tab.e[t].p0;
                    int r = i / dout, c = i - r * dout;
                    idx = ((r >> 3) * dout + c) * 8 + (r & 7);
                } else {
                    int r = i >> 6, c = i & 63;       // r = n_eff, c = k_eff
                    idx = ((c >> 3) * tab.e[t].p1 + r) * 8 + (c & 7);
                }
                bf16 hv = __float2bfloat16(v);
                hb[dst + idx] = hv;
                hb[dst + n + idx] = __float2bfloat16(v - b2f(hv));
            }
            return;
        }
        i -= n;
    }
}

// ---------------- CSR construction ----------------
__global__ void k_scan(const int* __restrict__ cnt, int* __restrict__ rowptr,
                       int* __restrict__ fill, float* __restrict__ dis) {
    __shared__ int sums[256];
    int t = threadIdx.x;
    int base = t * 32;
    int s = 0;
#pragma unroll
    for (int i = 0; i < 32; i++) s += cnt[base + i];
    sums[t] = s;
    __syncthreads();
    for (int off = 1; off < 256; off <<= 1) {
        int v = (t >= off) ? sums[t - off] : 0;
        __syncthreads();
        sums[t] += v;
        __syncthreads();
    }
    int run = (t == 0) ? 0 : sums[t - 1];
#pragma unroll
    for (int i = 0; i < 32; i++) {
        int idx = base + i;
        rowptr[idx] = run;
        fill[idx] = run;
        dis[idx] = rsqrtf((float)(cnt[idx] + 1));
        run += cnt[idx];
    }
    if (t == 255) rowptr[8192] = run;
}

__global__ void k_scatter(const int* __restrict__ ei, int E,
                          int* __restrict__ fill, int* __restrict__ ssrc,
                          const float* __restrict__ dis, float* __restrict__ dsrc) {
    int e = blockIdx.x * blockDim.x + threadIdx.x;
    if (e < E) {
        int s = ei[e];
        int pos = atomicAdd(&fill[ei[E + e]], 1);
        ssrc[pos] = s;
        dsrc[pos] = dis[s];
    }
}

// ---------------- shared helpers for fused kernels ----------------
// MFMA stage: A-tile (16 x K fp32, from two LDS buffers summed or one) x split W.
// Returns acc for wave's 16-col tile starting at c0.
template<int K, int DOUT>
static __device__ __forceinline__ f32x4_t mfma_stage(const float* HsA, const float* HsB,
                                                     int strideF, const bf16* Wb,
                                                     int c0, int lo, int g) {
    constexpr int WPL = K * DOUT;
    const f32x4_t Z = {0.f, 0.f, 0.f, 0.f};
    f32x4_t a = Z;
#pragma unroll
    for (int kk = 0; kk < K / 32; kk++) {
        int ko = kk * 32 + g * 8;
        const float* pa = HsA + lo * strideF + ko;
        float4 x0 = *(const float4*)pa;
        float4 x1 = *(const float4*)(pa + 4);
        if (HsB) {
            const float* pb = HsB + lo * strideF + ko;
            float4 y0 = *(const float4*)pb;
            float4 y1 = *(const float4*)(pb + 4);
            x0.x += y0.x; x0.y += y0.y; x0.z += y0.z; x0.w += y0.w;
            x1.x += y1.x; x1.y += y1.y; x1.z += y1.z; x1.w += y1.w;
        }
        union { unsigned u[4]; bf16x8_t v; } ah, al;
        ah.u[0] = pk2(x0.x, x0.y);
        ah.u[1] = pk2(x0.z, x0.w);
        ah.u[2] = pk2(x1.x, x1.y);
        ah.u[3] = pk2(x1.z, x1.w);
        al.u[0] = pk2(x0.x - lo16f(ah.u[0]), x0.y - hi16f(ah.u[0]));
        al.u[1] = pk2(x0.z - lo16f(ah.u[1]), x0.w - hi16f(ah.u[1]));
        al.u[2] = pk2(x1.x - lo16f(ah.u[2]), x1.y - hi16f(ah.u[2]));
        al.u[3] = pk2(x1.z - lo16f(ah.u[3]), x1.w - hi16f(ah.u[3]));
        size_t wi = (size_t)((kk * 4 + g) * DOUT + c0 + lo) * 8;
        bf16x8_t wh = *(const bf16x8_t*)(Wb + wi);
        bf16x8_t wl = *(const bf16x8_t*)(Wb + WPL + wi);
        a = __builtin_amdgcn_mfma_f32_16x16x32_bf16(ah.v, wh, a, 0, 0, 0);
        a = __builtin_amdgcn_mfma_f32_16x16x32_bf16(al.v, wh, a, 0, 0, 0);
        a = __builtin_amdgcn_mfma_f32_16x16x32_bf16(ah.v, wl, a, 0, 0, 0);
    }
    return a;
}

// ---------------- FUSED GCN layer: agg(H) in LDS -> MFMA @ W -> bias/relu/resid ----------
template<int K, int DOUT, int RELU, int BS>
__global__ void __launch_bounds__(BS)
k_fused(const float* __restrict__ H, const int* __restrict__ rowptr,
        const int* __restrict__ ssrc, const float* __restrict__ dsrc,
        const float* __restrict__ dis, const bf16* __restrict__ Wb,
        const float* __restrict__ bias, const float* __restrict__ resid,
        float* __restrict__ outF, void* __restrict__ outAny, int outOff,
        const int* __restrict__ flagp) {
    constexpr int LPR = K / 4;
    constexpr int SPN = (BS / LPR) / 16;
    constexpr int PADK = K + 4;
    __shared__ float Hs[SPN][16][PADK];

    int tid = threadIdx.x;
    int gp = tid / LPR;
    int li = tid - gp * LPR;
    int fl4 = li * 4;
    int nl = gp / SPN;
    int st = gp - nl * SPN;
    int node = blockIdx.x * 16 + nl;

    float di = dis[node];
    int e0 = rowptr[node], e1 = rowptr[node + 1];
    float4 acc = {0.f, 0.f, 0.f, 0.f};
    if (st == 0) {
        float dii = di * di;
        float4 sv = *(const float4*)(H + (size_t)node * K + fl4);
        acc.x = sv.x * dii; acc.y = sv.y * dii; acc.z = sv.z * dii; acc.w = sv.w * dii;
    }
    int e = e0 + st;
    for (; e + 3 * SPN < e1; e += 4 * SPN) {
        int s0 = ssrc[e], s1 = ssrc[e + SPN], s2 = ssrc[e + 2 * SPN], s3 = ssrc[e + 3 * SPN];
        float w0 = dsrc[e] * di, w1 = dsrc[e + SPN] * di;
        float w2 = dsrc[e + 2 * SPN] * di, w3 = dsrc[e + 3 * SPN] * di;
        float4 v0 = *(const float4*)(H + (size_t)s0 * K + fl4);
        float4 v1 = *(const float4*)(H + (size_t)s1 * K + fl4);
        float4 v2 = *(const float4*)(H + (size_t)s2 * K + fl4);
        float4 v3 = *(const float4*)(H + (size_t)s3 * K + fl4);
        acc.x += v0.x * w0; acc.y += v0.y * w0; acc.z += v0.z * w0; acc.w += v0.w * w0;
        acc.x += v1.x * w1; acc.y += v1.y * w1; acc.z += v1.z * w1; acc.w += v1.w * w1;
        acc.x += v2.x * w2; acc.y += v2.y * w2; acc.z += v2.z * w2; acc.w += v2.w * w2;
        acc.x += v3.x * w3; acc.y += v3.y * w3; acc.z += v3.z * w3; acc.w += v3.w * w3;
    }
    for (; e < e1; e += SPN) {
        int sv = ssrc[e];
        float wgt = dsrc[e] * di;
        float4 v = *(const float4*)(H + (size_t)sv * K + fl4);
        acc.x += v.x * wgt; acc.y += v.y * wgt; acc.z += v.z * wgt; acc.w += v.w * wgt;
    }
    *(float4*)&Hs[st][nl][fl4] = acc;
    __syncthreads();

    int w = tid >> 6, lane = tid & 63;
    int lo = lane & 15, g = lane >> 4;
    if (w < DOUT / 16) {
        int c0 = w * 16;
        f32x4_t a = mfma_stage<K, DOUT>(&Hs[0][0][0], SPN == 2 ? &Hs[1][0][0] : nullptr,
                                        PADK, Wb, c0, lo, g);
        float bs = bias[c0 + lo];
        int col = c0 + lo;
#pragma unroll
        for (int r = 0; r < 4; r++) {
            float v = a[r] + bs;
            if (RELU) v = fmaxf(v, 0.f);
            int gnode = blockIdx.x * 16 + 4 * g + r;
            size_t o = (size_t)gnode * DOUT + col;
            if (resid) v += resid[o];
            if (outF) outF[o] = v;
            if (outAny) {
                if (*flagp) ((float*)outAny)[(size_t)outOff + o] = v;
                else        ((bf16*)outAny)[(size_t)outOff + o] = __float2bfloat16(v);
            }
        }
    }
}

// ---------------- FUSED e4 + qkv: agg(h3)@We4+be4 = z -> d_out; then z@Wai+bai -> Qkv ----
__global__ void __launch_bounds__(1024)
k_fused_qkv(const float* __restrict__ H, const int* __restrict__ rowptr,
            const int* __restrict__ ssrc, const float* __restrict__ dsrc,
            const float* __restrict__ dis, const bf16* __restrict__ We4,
            const float* __restrict__ be4, const bf16* __restrict__ Wai,
            const float* __restrict__ bai, void* __restrict__ outAny, int outOff,
            const int* __restrict__ flagp, bf16* __restrict__ Qkv) {
    constexpr int K = 128, SPN = 2, PADK = 132;
    __shared__ float Hs[SPN][16][PADK];
    __shared__ float zt[16][68];

    int tid = threadIdx.x;
    int gp = tid >> 5;              // LPR=32
    int li = tid & 31;
    int fl4 = li * 4;
    int nl = gp >> 1;
    int st = gp & 1;
    int node = blockIdx.x * 16 + nl;

    float di = dis[node];
    int e0 = rowptr[node], e1 = rowptr[node + 1];
    float4 acc = {0.f, 0.f, 0.f, 0.f};
    if (st == 0) {
        float dii = di * di;
        float4 sv = *(const float4*)(H + (size_t)node * K + fl4);
        acc.x = sv.x * dii; acc.y = sv.y * dii; acc.z = sv.z * dii; acc.w = sv.w * dii;
    }
    int e = e0 + st;
    for (; e + 3 * SPN < e1; e += 4 * SPN) {
        int s0 = ssrc[e], s1 = ssrc[e + SPN], s2 = ssrc[e + 2 * SPN], s3 = ssrc[e + 3 * SPN];
        float w0 = dsrc[e] * di, w1 = dsrc[e + SPN] * di;
        float w2 = dsrc[e + 2 * SPN] * di, w3 = dsrc[e + 3 * SPN] * di;
        float4 v0 = *(const float4*)(H + (size_t)s0 * K + fl4);
        float4 v1 = *(const float4*)(H + (size_t)s1 * K + fl4);
        float4 v2 = *(const float4*)(H + (size_t)s2 * K + fl4);
        float4 v3 = *(const float4*)(H + (size_t)s3 * K + fl4);
        acc.x += v0.x * w0; acc.y += v0.y * w0; acc.z += v0.z * w0; acc.w += v0.w * w0;
        acc.x += v1.x * w1; acc.y += v1.y * w1; acc.z += v1.z * w1; acc.w += v1.w * w1;
        acc.x += v2.x * w2; acc.y += v2.y * w2; acc.z += v2.z * w2; acc.w += v2.w * w2;
        acc.x += v3.x * w3; acc.y += v3.y * w3; acc.z += v3.z * w3; acc.w += v3.w * w3;
    }
    for (; e < e1; e += SPN) {
        int sv = ssrc[e];
        float wgt = dsrc[e] * di;
        float4 v = *(const float4*)(H + (size_t)sv * K + fl4);
        acc.x += v.x * wgt; acc.y += v.y * wgt; acc.z += v.z * wgt; acc.w += v.w * wgt;
    }
    *(float4*)&Hs[st][nl][fl4] = acc;
    __syncthreads();

    int w = tid >> 6, lane = tid & 63;
    int lo = lane & 15, g = lane >> 4;
    if (w < 4) {   // stage 1: z = agg(h3) @ We4 + be4  (DOUT=64)
        int c0 = w * 16;
        f32x4_t a = mfma_stage<128, 64>(&Hs[0][0][0], &Hs[1][0][0], PADK, We4, c0, lo, g);
        float bs = be4[c0 + lo];
        int col = c0 + lo;
#pragma unroll
        for (int r = 0; r < 4; r++) {
            float v = a[r] + bs;
            int row = 4 * g + r;
            zt[row][col] = v;
            int gnode = blockIdx.x * 16 + row;
            size_t o = (size_t)gnode * 64 + col;
            if (*flagp) ((float*)outAny)[(size_t)outOff + o] = v;
            else        ((bf16*)outAny)[(size_t)outOff + o] = __float2bfloat16(v);
        }
    }
    __syncthreads();
    if (w < 12) {  // stage 2: qkv = z @ Wai + bai  (K=64, DOUT=192)
        int c0 = w * 16;
        f32x4_t a = mfma_stage<64, 192>(&zt[0][0], nullptr, 68, Wai, c0, lo, g);
        int n = c0 + lo;
        float bs = bai[n];
#pragma unroll
        for (int r = 0; r < 4; r++) {
            float v = a[r] + bs;
            int node2 = blockIdx.x * 16 + 4 * g + r;
            if (n < 64) {
                Qkv[(size_t)node2 * 64 + n] = __float2bfloat16(v * QSCALE);
            } else if (n < 128) {
                Qkv[524288 + (size_t)node2 * 64 + (n - 64)] = __float2bfloat16(v);
            } else {
                Qkv[1048576 + (size_t)(n - 128) * 8192 + node2] = __float2bfloat16(v);
            }
        }
    }
}

// ---------------- FUSED out-proj + d1: agg(za) = agg(Bo)@Wao + c*bao; g1 = relu(.@Wd1+bd1) ----
__global__ void __launch_bounds__(512)
k_fused_d1(const float* __restrict__ Bo, const int* __restrict__ rowptr,
           const int* __restrict__ ssrc, const float* __restrict__ dsrc,
           const float* __restrict__ dis, const bf16* __restrict__ Wao,
           const float* __restrict__ bao, const bf16* __restrict__ Wd1,
           const float* __restrict__ bd1, float* __restrict__ outF) {
    constexpr int K = 64, SPN = 2, PADK = 68;
    __shared__ float Hs[SPN][16][PADK];
    __shared__ float zt[16][68];
    __shared__ float wsumL[16][2];
    __shared__ float carr[16];

    int tid = threadIdx.x;
    int gp = tid >> 4;              // LPR=16
    int li = tid & 15;
    int fl4 = li * 4;
    int nl = gp >> 1;
    int st = gp & 1;
    int node = blockIdx.x * 16 + nl;

    float di = dis[node];
    int e0 = rowptr[node], e1 = rowptr[node + 1];
    float4 acc = {0.f, 0.f, 0.f, 0.f};
    float ws = 0.f;
    if (st == 0) {
        float dii = di * di;
        float4 sv = *(const float4*)(Bo + (size_t)node * K + fl4);
        acc.x = sv.x * dii; acc.y = sv.y * dii; acc.z = sv.z * dii; acc.w = sv.w * dii;
    }
    int e = e0 + st;
    for (; e + 3 * SPN < e1; e += 4 * SPN) {
        int s0 = ssrc[e], s1 = ssrc[e + SPN], s2 = ssrc[e + 2 * SPN], s3 = ssrc[e + 3 * SPN];
        float w0 = dsrc[e] * di, w1 = dsrc[e + SPN] * di;
        float w2 = dsrc[e + 2 * SPN] * di, w3 = dsrc[e + 3 * SPN] * di;
        ws += ((w0 + w1) + (w2 + w3));
        float4 v0 = *(const float4*)(Bo + (size_t)s0 * K + fl4);
        float4 v1 = *(const float4*)(Bo + (size_t)s1 * K + fl4);
        float4 v2 = *(const float4*)(Bo + (size_t)s2 * K + fl4);
        float4 v3 = *(const float4*)(Bo + (size_t)s3 * K + fl4);
        acc.x += v0.x * w0; acc.y += v0.y * w0; acc.z += v0.z * w0; acc.w += v0.w * w0;
        acc.x += v1.x * w1; acc.y += v1.y * w1; acc.z += v1.z * w1; acc.w += v1.w * w1;
        acc.x += v2.x * w2; acc.y += v2.y * w2; acc.z += v2.z * w2; acc.w += v2.w * w2;
        acc.x += v3.x * w3; acc.y += v3.y * w3; acc.z += v3.z * w3; acc.w += v3.w * w3;
    }
    for (; e < e1; e += SPN) {
        int sv = ssrc[e];
        float wgt = dsrc[e] * di;
        ws += wgt;
        float4 v = *(const float4*)(Bo + (size_t)sv * K + fl4);
        acc.x += v.x * wgt; acc.y += v.y * wgt; acc.z += v.z * wgt; acc.w += v.w * wgt;
    }
    *(float4*)&Hs[st][nl][fl4] = acc;
    if (li == 0) wsumL[nl][st] = ws;
    __syncthreads();
    if (tid < 16) {
        float d2 = dis[blockIdx.x * 16 + tid];
        carr[tid] = d2 * d2 + wsumL[tid][0] + wsumL[tid][1];
    }
    __syncthreads();

    int w = tid >> 6, lane = tid & 63;
    int lo = lane & 15, g = lane >> 4;
    if (w < 4) {   // stage 1: za = agg(Bo) @ Wao + c*bao  (DOUT=64)
        int c0 = w * 16;
        f32x4_t a = mfma_stage<64, 64>(&Hs[0][0][0], &Hs[1][0][0], PADK, Wao, c0, lo, g);
        int col = c0 + lo;
        float bs = bao[col];
#pragma unroll
        for (int r = 0; r < 4; r++) {
            int row = 4 * g + r;
            zt[row][col] = a[r] + carr[row] * bs;
        }
    }
    __syncthreads();
    // stage 2: g1 = relu(za @ Wd1 + bd1)  (K=64, DOUT=128)
    {
        int c0 = w * 16;
        f32x4_t a = mfma_stage<64, 128>(&zt[0][0], nullptr, 68, Wd1, c0, lo, g);
        int col = c0 + lo;
        float bs = bd1[col];
#pragma unroll
        for (int r = 0; r < 4; r++) {
            float v = fmaxf(a[r] + bs, 0.f);
            int gnode = blockIdx.x * 16 + 4 * g + r;
            outF[(size_t)gnode * 128 + col] = v;
        }
    }
}

// ---------------- MFMA flash attention (R11-proven, unroll 2) ----------------
__global__ void __launch_bounds__(512)
k_flash(const bf16* __restrict__ Qb, const bf16* __restrict__ Kb,
        const bf16* __restrict__ VT, float* __restrict__ Bo) {
    __shared__ unsigned short plds[8][2][16][40];
    __shared__ float redo[8][2][16][16];
    __shared__ float redl[8][2][16];
    int w = threadIdx.x >> 6;
    int lane = threadIdx.x & 63;
    int lo = lane & 15;
    int g = lane >> 4;
    int qt = blockIdx.x & 255;
    int h = blockIdx.x >> 8;
    int q0 = qt * 32;
    int m0base = w * 1024;

    const f32x4_t Z = {0.f, 0.f, 0.f, 0.f};
    bf16x8_t zf;
#pragma unroll
    for (int i = 0; i < 8; i++) zf[i] = 0;

    bf16x8_t qf[2];
#pragma unroll
    for (int s = 0; s < 2; s++) {
        if (g < 2) qf[s] = *(const bf16x8_t*)(Qb + (size_t)(q0 + s * 16 + lo) * 64 + h * 16 + g * 8);
        else       qf[s] = zf;
    }

    f32x4_t oacc[2] = {Z, Z};
    float lr[2] = {0.f, 0.f};
    const bf16* kbase = Kb + h * 16 + g * 8;
    const bf16* vbase = VT + (size_t)(h * 16 + lo) * 8192;

#pragma unroll 2
    for (int t = 0; t < 32; t++) {
        int m0 = m0base + t * 32;
        bf16x8_t kf0 = zf, kf1 = zf;
        if (g < 2) {
            kf0 = *(const bf16x8_t*)(kbase + (size_t)m0 * 64);
            kf1 = *(const bf16x8_t*)(kbase + (size_t)(m0 + 16) * 64);
        }
        bf16x8_t vt = *(const bf16x8_t*)(vbase + m0 + 8 * g);
#pragma unroll
        for (int s = 0; s < 2; s++) {
            f32x4_t s0 = __builtin_amdgcn_mfma_f32_16x16x32_bf16(kf0, qf[s], Z, 0, 0, 0);
            f32x4_t s1 = __builtin_amdgcn_mfma_f32_16x16x32_bf16(kf1, qf[s], Z, 0, 0, 0);
            float p0 = __builtin_amdgcn_exp2f(s0[0]);
            float p1 = __builtin_amdgcn_exp2f(s0[1]);
            float p2 = __builtin_amdgcn_exp2f(s0[2]);
            float p3 = __builtin_amdgcn_exp2f(s0[3]);
            float p4 = __builtin_amdgcn_exp2f(s1[0]);
            float p5 = __builtin_amdgcn_exp2f(s1[1]);
            float p6 = __builtin_amdgcn_exp2f(s1[2]);
            float p7 = __builtin_amdgcn_exp2f(s1[3]);
            lr[s] += (((p0 + p1) + (p2 + p3)) + ((p4 + p5) + (p6 + p7)));
            unsigned* dst0 = (unsigned*)&plds[w][s][lo][4 * g];
            dst0[0] = pk2(p0, p1);
            dst0[1] = pk2(p2, p3);
            unsigned* dst1 = (unsigned*)&plds[w][s][lo][16 + 4 * g];
            dst1[0] = pk2(p4, p5);
            dst1[1] = pk2(p6, p7);
            bf16x8_t pf = *(const bf16x8_t*)&plds[w][s][lo][8 * g];
            oacc[s] = __builtin_amdgcn_mfma_f32_16x16x32_bf16(vt, pf, oacc[s], 0, 0, 0);
        }
    }
#pragma unroll
    for (int s = 0; s < 2; s++) {
        float l = lr[s];
        l += __shfl_xor(l, 16);
        l += __shfl_xor(l, 32);
        *(f32x4_t*)&redo[w][s][lo][4 * g] = oacc[s];
        if (g == 0) redl[w][s][lo] = l;
    }
    __syncthreads();
    int tid = threadIdx.x;
    int s2 = tid >> 8, q2 = (tid >> 4) & 15, d2 = tid & 15;
    float o = 0.f, l = 0.f;
#pragma unroll
    for (int ww = 0; ww < 8; ww++) {
        o += redo[ww][s2][q2][d2];
        l += redl[ww][s2][q2];
    }
    Bo[(size_t)(q0 + s2 * 16 + q2) * 64 + h * 16 + d2] = o / l;
}

// ---------------- launch ----------------
extern "C" void kernel_launch(void* const* d_in, const int* in_sizes, int n_in,
                              void* d_out, int out_size, void* d_ws, size_t ws_size,
                              hipStream_t stream) {
    int E = in_sizes[1] / 2;
    const int* ei = (const int*)d_in[1];

    int*   ib = (int*)d_ws;
    float* fb = (float*)d_ws;
    int* cnt    = ib;
    int* rowptr = ib + 8192;
    int* fill   = ib + 16448;
    int* ssrc   = ib + 24640;
    int* flagp  = ib + 286784;
    float* dis  = fb + OFF_DIS;
    float* Bias = fb + OFF_BIAS;
    bf16*  Wb   = (bf16*)(fb + OFF_WB);
    float* dsrc = fb + OFF_DSRC;
    float* X    = fb + OFF_X;
    float* HA   = fb + OFF_HA;
    float* HB   = fb + OFF_HB;
    float* Bo   = fb + OFF_BO;
    bf16*  Qkv  = (bf16*)(fb + OFF_QKV);   // Qb | Kb(+524288) | VT(+1048576)

    dim3 b1024(1024), b512(512), b256(256);
    int eb = (E + 255) / 256;

    CvtTab tab;
    auto ent = [&](int i, const void* s, int n, int dst, int mode, int p0, int p1) {
        tab.e[i] = CvtEnt{s, n, dst, mode, p0, p1};
    };
    ent(0,  d_in[0],  524288, OFF_X, 0, 0, 0);
    ent(1,  d_in[2],  8192,  HS_E1, 2, 128, 0);
    ent(2,  d_in[3],  128,   OFF_BIAS + BF_E1, 0, 0, 0);
    ent(3,  d_in[4],  16384, HS_E2, 2, 128, 0);
    ent(4,  d_in[5],  128,   OFF_BIAS + BF_E2, 0, 0, 0);
    ent(5,  d_in[6],  16384, HS_E3, 2, 128, 0);
    ent(6,  d_in[7],  128,   OFF_BIAS + BF_E3, 0, 0, 0);
    ent(7,  d_in[8],  8192,  HS_E4, 2, 64, 0);
    ent(8,  d_in[9],  64,    OFF_BIAS + BF_E4, 0, 0, 0);
    ent(9,  d_in[10], 8192,  HS_D1, 2, 128, 0);
    ent(10, d_in[11], 128,   OFF_BIAS + BF_D1, 0, 0, 0);
    ent(11, d_in[12], 16384, HS_D2, 2, 128, 0);
    ent(12, d_in[13], 128,   OFF_BIAS + BF_D2, 0, 0, 0);
    ent(13, d_in[14], 16384, HS_D3, 2, 128, 0);
    ent(14, d_in[15], 128,   OFF_BIAS + BF_D3, 0, 0, 0);
    ent(15, d_in[16], 8192,  HS_D4, 2, 64, 0);
    ent(16, d_in[17], 64,    OFF_BIAS + BF_D4, 0, 0, 0);
    ent(17, d_in[18], 12288, HS_AI, 3, 0, 192);
    ent(18, d_in[19], 192,   OFF_BIAS + BF_AI, 0, 0, 0);
    ent(19, d_in[20], 4096,  HS_AO, 3, 0, 64);
    ent(20, d_in[21], 64,    OFF_BIAS + BF_AO, 0, 0, 0);

    hipMemsetAsync(cnt, 0, 8192 * sizeof(int), stream);
    k_convert<<<dim3(2501), b256, 0, stream>>>(tab, fb, Wb, flagp,
                                               (const unsigned short*)d_in[0], ei, E, cnt);
    k_scan<<<dim3(1), b256, 0, stream>>>(cnt, rowptr, fill, dis);
    k_scatter<<<dim3(eb), b256, 0, stream>>>(ei, E, fill, ssrc, dis, dsrc);

    dim3 g512(512), g1024(1024);

    // encoder
    k_fused<64, 128, 1, 512><<<g512, b512, 0, stream>>>(X, rowptr, ssrc, dsrc, dis,
        Wb + HS_E1, Bias + BF_E1, nullptr, HA, nullptr, 0, flagp);
    k_fused<128, 128, 1, 1024><<<g512, b1024, 0, stream>>>(HA, rowptr, ssrc, dsrc, dis,
        Wb + HS_E2, Bias + BF_E2, HA, HB, nullptr, 0, flagp);
    k_fused<128, 128, 1, 1024><<<g512, b1024, 0, stream>>>(HB, rowptr, ssrc, dsrc, dis,
        Wb + HS_E3, Bias + BF_E3, HB, HA, nullptr, 0, flagp);
    // e4 + qkv projection fused (z -> d_out[524288:], qkv -> Qkv)
    k_fused_qkv<<<g512, b1024, 0, stream>>>(HA, rowptr, ssrc, dsrc, dis,
        Wb + HS_E4, Bias + BF_E4, Wb + HS_AI, Bias + BF_AI, d_out, 524288, flagp, Qkv);

    // attention
    k_flash<<<g1024, b512, 0, stream>>>(Qkv, Qkv + 524288, Qkv + 1048576, Bo);

    // decoder: out-proj + d1 fused (agg(za) = agg(Bo)@Wao + c*bao)
    k_fused_d1<<<g512, b512, 0, stream>>>(Bo, rowptr, ssrc, dsrc, dis,
        Wb + HS_AO, Bias + BF_AO, Wb + HS_D1, Bias + BF_D1, HA);
    k_fused<128, 128, 1, 1024><<<g512, b1024, 0, stream>>>(HA, rowptr, ssrc, dsrc, dis,
        Wb + HS_D2, Bias + BF_D2, HA, HB, nullptr, 0, flagp);
    k_fused<128, 128, 1, 1024><<<g512, b1024, 0, stream>>>(HB, rowptr, ssrc, dsrc, dis,
        Wb + HS_D3, Bias + BF_D3, HB, HA, nullptr, 0, flagp);
    k_fused<128, 64, 0, 1024><<<g512, b1024, 0, stream>>>(HA, rowptr, ssrc, dsrc, dis,
        Wb + HS_D4, Bias + BF_D4, nullptr, nullptr, d_out, 0, flagp);
}

// Round 17
// 287.084 us; speedup vs baseline: 4.3320x; 1.0468x over previous
//
#include <hip/hip_runtime.h>
#include <hip/hip_bf16.h>

using bf16 = __hip_bfloat16;

typedef __attribute__((ext_vector_type(8))) short bf16x8_t;   // 8 bf16 in 4 VGPRs
typedef __attribute__((ext_vector_type(4))) float f32x4_t;

static __device__ __forceinline__ float b2f(bf16 v) { return __bfloat162float(v); }

// pack two fp32 -> 2 bf16 (RNE) via v_cvt_pk_bf16_f32
static __device__ __forceinline__ unsigned pk2(float a, float b) {
    __hip_bfloat162 h = __float22bfloat162_rn(make_float2(a, b));
    return *reinterpret_cast<unsigned*>(&h);
}
static __device__ __forceinline__ float lo16f(unsigned u) { return __uint_as_float(u << 16); }
static __device__ __forceinline__ float hi16f(unsigned u) { return __uint_as_float(u & 0xFFFF0000u); }

// log2(e)/4 : folds 1/sqrt(DH) and exp->exp2. Applied at qkv output (fp32).
#define QSCALE 0.36067376022224085f

// ---------------- workspace layout (float offsets) ----------------
// ints: cnt[0,8192) rowptr[8192,16385) fill[16448,24640) ssrc[24640,286784) flag ib[286784]
#define OFF_DIS  286848
#define OFF_BIAS 295040   /* 1152 fp32 */
#define OFF_WB   296192   /* bf16 weights (split hi+lo), 229376 shorts = 114688 floats */
#define OFF_DSRC 410880   /* fp32 edge weights [262144] */
#define OFF_X    935168   /* bf16 x [8192,64] */
#define OFF_HA   1983744  /* bf16 act [8192,128] */
#define OFF_HB   3032320  /* bf16 act [8192,128] */
#define OFF_BO   4605184  /* fp32 attention out [8192,64] */
#define OFF_QKV  5653760  /* bf16: Qb[8192*64] | Kb[8192*64] | VT[64*8192] = 786432 f slots */
// total 6440192 floats = 25.76 MB

// weight short-offsets (relative to OFF_WB as bf16*), each region hi plane then lo plane
#define HS_E1 0
#define HS_E2 16384
#define HS_E3 49152
#define HS_E4 81920
#define HS_D1 98304
#define HS_D2 114688
#define HS_D3 147456
#define HS_D4 180224
#define HS_AI 196608
#define HS_AO 221184
#define HS_X  1277952   /* = 2*(OFF_X - OFF_WB), plain bf16 x */

// bias fp32 offsets (relative to OFF_BIAS)
#define BF_E1 0
#define BF_E2 128
#define BF_E3 256
#define BF_E4 384
#define BF_D1 448
#define BF_D2 576
#define BF_D3 704
#define BF_D4 832
#define BF_AI 896
#define BF_AO 1088

// ---------------- input canonicalization (sniff + edge-count fused) ----------------
// mode 0: fp32 -> fb[dst+i]
// mode 2: split weight swizzle from [K,dout=p0]; lo at dst+n+idx
// mode 3: split weight transpose+swizzle from [rows,64]; lo at dst+n+idx
// mode 4: plain bf16 -> hb[dst+i]
struct CvtEnt { const void* src; int n; int dst; int mode; int p0; int p1; };
struct CvtTab { CvtEnt e[21]; };

__global__ void k_convert(CvtTab tab, float* __restrict__ fb, bf16* __restrict__ hb,
                          int* __restrict__ flagp, const unsigned short* __restrict__ xb,
                          const int* __restrict__ ei, int E, int* __restrict__ cnt) {
    __shared__ int wsum[4];
    unsigned short wv = xb[threadIdx.x * 2];
    int ex = (wv >> 7) & 0xFF;
    int mn = wv & 0x7F;
    int weird = (ex >= 134) || (ex != 0 && ex <= 90) || (ex == 0 && mn != 0);
    unsigned long long bal = __ballot(weird);
    if ((threadIdx.x & 63) == 0) wsum[threadIdx.x >> 6] = (int)__popcll(bal);
    __syncthreads();
    int fl = ((wsum[0] + wsum[1]) + (wsum[2] + wsum[3])) >= 32 ? 1 : 0;   // 1 => fp32
    if (blockIdx.x == 0 && threadIdx.x == 0) *flagp = fl;

    int gi = blockIdx.x * blockDim.x + threadIdx.x;
    if (gi < E) atomicAdd(&cnt[ei[E + gi]], 1);   // fused degree count

    int i = gi;
#pragma unroll 1
    for (int t = 0; t < 21; t++) {
        int n = tab.e[t].n;
        if (i < n) {
            float v = fl ? ((const float*)tab.e[t].src)[i]
                         : b2f(((const bf16*)tab.e[t].src)[i]);
            int mode = tab.e[t].mode, dst = tab.e[t].dst;
            if (mode == 0) {
                fb[dst + i] = v;
            } else if (mode == 4) {
                hb[dst + i] = __float2bfloat16(v);
            } else {
                int idx;
                if (mode == 2) {
                    int dout = tab.e[t].p0;
                    int r = i / dout, c = i - r * dout;
                    idx = ((r >> 3) * dout + c) * 8 + (r & 7);
                } else {
                    int r = i >> 6, c = i & 63;       // r = n_eff, c = k_eff
                    idx = ((c >> 3) * tab.e[t].p1 + r) * 8 + (c & 7);
                }
                bf16 hv = __float2bfloat16(v);
                hb[dst + idx] = hv;
                hb[dst + n + idx] = __float2bfloat16(v - b2f(hv));
            }
            return;
        }
        i -= n;
    }
}

// ---------------- CSR construction ----------------
__global__ void k_scan(const int* __restrict__ cnt, int* __restrict__ rowptr,
                       int* __restrict__ fill, float* __restrict__ dis) {
    __shared__ int sums[256];
    int t = threadIdx.x;
    int base = t * 32;
    int s = 0;
#pragma unroll
    for (int i = 0; i < 32; i++) s += cnt[base + i];
    sums[t] = s;
    __syncthreads();
    for (int off = 1; off < 256; off <<= 1) {
        int v = (t >= off) ? sums[t - off] : 0;
        __syncthreads();
        sums[t] += v;
        __syncthreads();
    }
    int run = (t == 0) ? 0 : sums[t - 1];
#pragma unroll
    for (int i = 0; i < 32; i++) {
        int idx = base + i;
        rowptr[idx] = run;
        fill[idx] = run;
        dis[idx] = rsqrtf((float)(cnt[idx] + 1));
        run += cnt[idx];
    }
    if (t == 255) rowptr[8192] = run;
}

__global__ void k_scatter(const int* __restrict__ ei, int E,
                          int* __restrict__ fill, int* __restrict__ ssrc,
                          const float* __restrict__ dis, float* __restrict__ dsrc) {
    int e = blockIdx.x * blockDim.x + threadIdx.x;
    if (e < E) {
        int s = ei[e];
        int pos = atomicAdd(&fill[ei[E + e]], 1);
        ssrc[pos] = s;
        dsrc[pos] = dis[s];
    }
}

// ---------------- shared helpers ----------------
// gather one row (float4 slice at feature offset fl4) from fp32 or bf16 matrix
template<int K, int GBF>
static __device__ __forceinline__ float4 grow(const void* H, int row, int fl4) {
    if (GBF) {
        uint2 u = *(const uint2*)((const bf16*)H + (size_t)row * K + fl4);
        float4 v;
        v.x = lo16f(u.x); v.y = hi16f(u.x); v.z = lo16f(u.y); v.w = hi16f(u.y);
        return v;
    }
    return *(const float4*)((const float*)H + (size_t)row * K + fl4);
}

// MFMA stage: A-tile (16 x K fp32, from two LDS buffers summed or one) x split W.
template<int K, int DOUT>
static __device__ __forceinline__ f32x4_t mfma_stage(const float* HsA, const float* HsB,
                                                     int strideF, const bf16* Wb,
                                                     int c0, int lo, int g) {
    constexpr int WPL = K * DOUT;
    const f32x4_t Z = {0.f, 0.f, 0.f, 0.f};
    f32x4_t a = Z;
#pragma unroll
    for (int kk = 0; kk < K / 32; kk++) {
        int ko = kk * 32 + g * 8;
        const float* pa = HsA + lo * strideF + ko;
        float4 x0 = *(const float4*)pa;
        float4 x1 = *(const float4*)(pa + 4);
        if (HsB) {
            const float* pb = HsB + lo * strideF + ko;
            float4 y0 = *(const float4*)pb;
            float4 y1 = *(const float4*)(pb + 4);
            x0.x += y0.x; x0.y += y0.y; x0.z += y0.z; x0.w += y0.w;
            x1.x += y1.x; x1.y += y1.y; x1.z += y1.z; x1.w += y1.w;
        }
        union { unsigned u[4]; bf16x8_t v; } ah, al;
        ah.u[0] = pk2(x0.x, x0.y);
        ah.u[1] = pk2(x0.z, x0.w);
        ah.u[2] = pk2(x1.x, x1.y);
        ah.u[3] = pk2(x1.z, x1.w);
        al.u[0] = pk2(x0.x - lo16f(ah.u[0]), x0.y - hi16f(ah.u[0]));
        al.u[1] = pk2(x0.z - lo16f(ah.u[1]), x0.w - hi16f(ah.u[1]));
        al.u[2] = pk2(x1.x - lo16f(ah.u[2]), x1.y - hi16f(ah.u[2]));
        al.u[3] = pk2(x1.z - lo16f(ah.u[3]), x1.w - hi16f(ah.u[3]));
        size_t wi = (size_t)((kk * 4 + g) * DOUT + c0 + lo) * 8;
        bf16x8_t wh = *(const bf16x8_t*)(Wb + wi);
        bf16x8_t wl = *(const bf16x8_t*)(Wb + WPL + wi);
        a = __builtin_amdgcn_mfma_f32_16x16x32_bf16(ah.v, wh, a, 0, 0, 0);
        a = __builtin_amdgcn_mfma_f32_16x16x32_bf16(al.v, wh, a, 0, 0, 0);
        a = __builtin_amdgcn_mfma_f32_16x16x32_bf16(ah.v, wl, a, 0, 0, 0);
    }
    return a;
}

// ---------------- FUSED GCN layer: agg(H) in LDS -> MFMA @ W -> bias/relu/resid ----------
// GBF: gather/resid dtype (1 = bf16). outB: plain bf16 activation out.
template<int K, int DOUT, int RELU, int BS, int GBF>
__global__ void __launch_bounds__(BS)
k_fused(const void* __restrict__ H, const int* __restrict__ rowptr,
        const int* __restrict__ ssrc, const float* __restrict__ dsrc,
        const float* __restrict__ dis, const bf16* __restrict__ Wb,
        const float* __restrict__ bias, const bf16* __restrict__ residB,
        bf16* __restrict__ outB, void* __restrict__ outAny, int outOff,
        const int* __restrict__ flagp) {
    constexpr int LPR = K / 4;
    constexpr int SPN = (BS / LPR) / 16;
    constexpr int PADK = K + 4;
    __shared__ float Hs[SPN][16][PADK];

    int tid = threadIdx.x;
    int gp = tid / LPR;
    int li = tid - gp * LPR;
    int fl4 = li * 4;
    int nl = gp / SPN;
    int st = gp - nl * SPN;
    int node = blockIdx.x * 16 + nl;

    float di = dis[node];
    int e0 = rowptr[node], e1 = rowptr[node + 1];
    float4 acc = {0.f, 0.f, 0.f, 0.f};
    if (st == 0) {
        float dii = di * di;
        float4 sv = grow<K, GBF>(H, node, fl4);
        acc.x = sv.x * dii; acc.y = sv.y * dii; acc.z = sv.z * dii; acc.w = sv.w * dii;
    }
    int e = e0 + st;
    for (; e + 3 * SPN < e1; e += 4 * SPN) {
        int s0 = ssrc[e], s1 = ssrc[e + SPN], s2 = ssrc[e + 2 * SPN], s3 = ssrc[e + 3 * SPN];
        float w0 = dsrc[e] * di, w1 = dsrc[e + SPN] * di;
        float w2 = dsrc[e + 2 * SPN] * di, w3 = dsrc[e + 3 * SPN] * di;
        float4 v0 = grow<K, GBF>(H, s0, fl4);
        float4 v1 = grow<K, GBF>(H, s1, fl4);
        float4 v2 = grow<K, GBF>(H, s2, fl4);
        float4 v3 = grow<K, GBF>(H, s3, fl4);
        acc.x += v0.x * w0; acc.y += v0.y * w0; acc.z += v0.z * w0; acc.w += v0.w * w0;
        acc.x += v1.x * w1; acc.y += v1.y * w1; acc.z += v1.z * w1; acc.w += v1.w * w1;
        acc.x += v2.x * w2; acc.y += v2.y * w2; acc.z += v2.z * w2; acc.w += v2.w * w2;
        acc.x += v3.x * w3; acc.y += v3.y * w3; acc.z += v3.z * w3; acc.w += v3.w * w3;
    }
    for (; e < e1; e += SPN) {
        int sv = ssrc[e];
        float wgt = dsrc[e] * di;
        float4 v = grow<K, GBF>(H, sv, fl4);
        acc.x += v.x * wgt; acc.y += v.y * wgt; acc.z += v.z * wgt; acc.w += v.w * wgt;
    }
    *(float4*)&Hs[st][nl][fl4] = acc;
    __syncthreads();

    int w = tid >> 6, lane = tid & 63;
    int lo = lane & 15, g = lane >> 4;
    if (w < DOUT / 16) {
        int c0 = w * 16;
        f32x4_t a = mfma_stage<K, DOUT>(&Hs[0][0][0], SPN == 2 ? &Hs[1][0][0] : nullptr,
                                        PADK, Wb, c0, lo, g);
        float bs = bias[c0 + lo];
        int col = c0 + lo;
#pragma unroll
        for (int r = 0; r < 4; r++) {
            float v = a[r] + bs;
            if (RELU) v = fmaxf(v, 0.f);
            int gnode = blockIdx.x * 16 + 4 * g + r;
            size_t o = (size_t)gnode * DOUT + col;
            if (residB) v += b2f(residB[o]);
            if (outB) outB[o] = __float2bfloat16(v);
            if (outAny) {
                if (*flagp) ((float*)outAny)[(size_t)outOff + o] = v;
                else        ((bf16*)outAny)[(size_t)outOff + o] = __float2bfloat16(v);
            }
        }
    }
}

// ---------------- FUSED e4 + qkv: agg(h3)@We4+be4 = z -> d_out; then z@Wai+bai -> Qkv ----
__global__ void __launch_bounds__(1024)
k_fused_qkv(const bf16* __restrict__ H, const int* __restrict__ rowptr,
            const int* __restrict__ ssrc, const float* __restrict__ dsrc,
            const float* __restrict__ dis, const bf16* __restrict__ We4,
            const float* __restrict__ be4, const bf16* __restrict__ Wai,
            const float* __restrict__ bai, void* __restrict__ outAny, int outOff,
            const int* __restrict__ flagp, bf16* __restrict__ Qkv) {
    constexpr int K = 128, SPN = 2, PADK = 132;
    __shared__ float Hs[SPN][16][PADK];
    __shared__ float zt[16][68];

    int tid = threadIdx.x;
    int gp = tid >> 5;              // LPR=32
    int li = tid & 31;
    int fl4 = li * 4;
    int nl = gp >> 1;
    int st = gp & 1;
    int node = blockIdx.x * 16 + nl;

    float di = dis[node];
    int e0 = rowptr[node], e1 = rowptr[node + 1];
    float4 acc = {0.f, 0.f, 0.f, 0.f};
    if (st == 0) {
        float dii = di * di;
        float4 sv = grow<128, 1>(H, node, fl4);
        acc.x = sv.x * dii; acc.y = sv.y * dii; acc.z = sv.z * dii; acc.w = sv.w * dii;
    }
    int e = e0 + st;
    for (; e + 3 * SPN < e1; e += 4 * SPN) {
        int s0 = ssrc[e], s1 = ssrc[e + SPN], s2 = ssrc[e + 2 * SPN], s3 = ssrc[e + 3 * SPN];
        float w0 = dsrc[e] * di, w1 = dsrc[e + SPN] * di;
        float w2 = dsrc[e + 2 * SPN] * di, w3 = dsrc[e + 3 * SPN] * di;
        float4 v0 = grow<128, 1>(H, s0, fl4);
        float4 v1 = grow<128, 1>(H, s1, fl4);
        float4 v2 = grow<128, 1>(H, s2, fl4);
        float4 v3 = grow<128, 1>(H, s3, fl4);
        acc.x += v0.x * w0; acc.y += v0.y * w0; acc.z += v0.z * w0; acc.w += v0.w * w0;
        acc.x += v1.x * w1; acc.y += v1.y * w1; acc.z += v1.z * w1; acc.w += v1.w * w1;
        acc.x += v2.x * w2; acc.y += v2.y * w2; acc.z += v2.z * w2; acc.w += v2.w * w2;
        acc.x += v3.x * w3; acc.y += v3.y * w3; acc.z += v3.z * w3; acc.w += v3.w * w3;
    }
    for (; e < e1; e += SPN) {
        int sv = ssrc[e];
        float wgt = dsrc[e] * di;
        float4 v = grow<128, 1>(H, sv, fl4);
        acc.x += v.x * wgt; acc.y += v.y * wgt; acc.z += v.z * wgt; acc.w += v.w * wgt;
    }
    *(float4*)&Hs[st][nl][fl4] = acc;
    __syncthreads();

    int w = tid >> 6, lane = tid & 63;
    int lo = lane & 15, g = lane >> 4;
    if (w < 4) {   // stage 1: z = agg(h3) @ We4 + be4  (DOUT=64)
        int c0 = w * 16;
        f32x4_t a = mfma_stage<128, 64>(&Hs[0][0][0], &Hs[1][0][0], PADK, We4, c0, lo, g);
        float bs = be4[c0 + lo];
        int col = c0 + lo;
#pragma unroll
        for (int r = 0; r < 4; r++) {
            float v = a[r] + bs;
            int row = 4 * g + r;
            zt[row][col] = v;
            int gnode = blockIdx.x * 16 + row;
            size_t o = (size_t)gnode * 64 + col;
            if (*flagp) ((float*)outAny)[(size_t)outOff + o] = v;
            else        ((bf16*)outAny)[(size_t)outOff + o] = __float2bfloat16(v);
        }
    }
    __syncthreads();
    if (w < 12) {  // stage 2: qkv = z @ Wai + bai  (K=64, DOUT=192)
        int c0 = w * 16;
        f32x4_t a = mfma_stage<64, 192>(&zt[0][0], nullptr, 68, Wai, c0, lo, g);
        int n = c0 + lo;
        float bs = bai[n];
#pragma unroll
        for (int r = 0; r < 4; r++) {
            float v = a[r] + bs;
            int node2 = blockIdx.x * 16 + 4 * g + r;
            if (n < 64) {
                Qkv[(size_t)node2 * 64 + n] = __float2bfloat16(v * QSCALE);
            } else if (n < 128) {
                Qkv[524288 + (size_t)node2 * 64 + (n - 64)] = __float2bfloat16(v);
            } else {
                Qkv[1048576 + (size_t)(n - 128) * 8192 + node2] = __float2bfloat16(v);
            }
        }
    }
}

// ---------------- FUSED out-proj + d1: agg(za) = agg(Bo)@Wao + c*bao; g1 = relu(.@Wd1+bd1) ----
__global__ void __launch_bounds__(512)
k_fused_d1(const float* __restrict__ Bo, const int* __restrict__ rowptr,
           const int* __restrict__ ssrc, const float* __restrict__ dsrc,
           const float* __restrict__ dis, const bf16* __restrict__ Wao,
           const float* __restrict__ bao, const bf16* __restrict__ Wd1,
           const float* __restrict__ bd1, bf16* __restrict__ outB) {
    constexpr int K = 64, SPN = 2, PADK = 68;
    __shared__ float Hs[SPN][16][PADK];
    __shared__ float zt[16][68];
    __shared__ float wsumL[16][2];
    __shared__ float carr[16];

    int tid = threadIdx.x;
    int gp = tid >> 4;              // LPR=16
    int li = tid & 15;
    int fl4 = li * 4;
    int nl = gp >> 1;
    int st = gp & 1;
    int node = blockIdx.x * 16 + nl;

    float di = dis[node];
    int e0 = rowptr[node], e1 = rowptr[node + 1];
    float4 acc = {0.f, 0.f, 0.f, 0.f};
    float ws = 0.f;
    if (st == 0) {
        float dii = di * di;
        float4 sv = *(const float4*)(Bo + (size_t)node * K + fl4);
        acc.x = sv.x * dii; acc.y = sv.y * dii; acc.z = sv.z * dii; acc.w = sv.w * dii;
    }
    int e = e0 + st;
    for (; e + 3 * SPN < e1; e += 4 * SPN) {
        int s0 = ssrc[e], s1 = ssrc[e + SPN], s2 = ssrc[e + 2 * SPN], s3 = ssrc[e + 3 * SPN];
        float w0 = dsrc[e] * di, w1 = dsrc[e + SPN] * di;
        float w2 = dsrc[e + 2 * SPN] * di, w3 = dsrc[e + 3 * SPN] * di;
        ws += ((w0 + w1) + (w2 + w3));
        float4 v0 = *(const float4*)(Bo + (size_t)s0 * K + fl4);
        float4 v1 = *(const float4*)(Bo + (size_t)s1 * K + fl4);
        float4 v2 = *(const float4*)(Bo + (size_t)s2 * K + fl4);
        float4 v3 = *(const float4*)(Bo + (size_t)s3 * K + fl4);
        acc.x += v0.x * w0; acc.y += v0.y * w0; acc.z += v0.z * w0; acc.w += v0.w * w0;
        acc.x += v1.x * w1; acc.y += v1.y * w1; acc.z += v1.z * w1; acc.w += v1.w * w1;
        acc.x += v2.x * w2; acc.y += v2.y * w2; acc.z += v2.z * w2; acc.w += v2.w * w2;
        acc.x += v3.x * w3; acc.y += v3.y * w3; acc.z += v3.z * w3; acc.w += v3.w * w3;
    }
    for (; e < e1; e += SPN) {
        int sv = ssrc[e];
        float wgt = dsrc[e] * di;
        ws += wgt;
        float4 v = *(const float4*)(Bo + (size_t)sv * K + fl4);
        acc.x += v.x * wgt; acc.y += v.y * wgt; acc.z += v.z * wgt; acc.w += v.w * wgt;
    }
    *(float4*)&Hs[st][nl][fl4] = acc;
    if (li == 0) wsumL[nl][st] = ws;
    __syncthreads();
    if (tid < 16) {
        float d2 = dis[blockIdx.x * 16 + tid];
        carr[tid] = d2 * d2 + wsumL[tid][0] + wsumL[tid][1];
    }
    __syncthreads();

    int w = tid >> 6, lane = tid & 63;
    int lo = lane & 15, g = lane >> 4;
    if (w < 4) {   // stage 1: za = agg(Bo) @ Wao + c*bao  (DOUT=64)
        int c0 = w * 16;
        f32x4_t a = mfma_stage<64, 64>(&Hs[0][0][0], &Hs[1][0][0], PADK, Wao, c0, lo, g);
        int col = c0 + lo;
        float bs = bao[col];
#pragma unroll
        for (int r = 0; r < 4; r++) {
            int row = 4 * g + r;
            zt[row][col] = a[r] + carr[row] * bs;
        }
    }
    __syncthreads();
    // stage 2: g1 = relu(za @ Wd1 + bd1)  (K=64, DOUT=128)
    {
        int c0 = w * 16;
        f32x4_t a = mfma_stage<64, 128>(&zt[0][0], nullptr, 68, Wd1, c0, lo, g);
        int col = c0 + lo;
        float bs = bd1[col];
#pragma unroll
        for (int r = 0; r < 4; r++) {
            float v = fmaxf(a[r] + bs, 0.f);
            int gnode = blockIdx.x * 16 + 4 * g + r;
            outB[(size_t)gnode * 128 + col] = __float2bfloat16(v);
        }
    }
}

// ---------------- MFMA flash attention (R11-proven; no unroll) ----------------
__global__ void __launch_bounds__(512)
k_flash(const bf16* __restrict__ Qb, const bf16* __restrict__ Kb,
        const bf16* __restrict__ VT, float* __restrict__ Bo) {
    __shared__ unsigned short plds[8][2][16][40];
    __shared__ float redo[8][2][16][16];
    __shared__ float redl[8][2][16];
    int w = threadIdx.x >> 6;
    int lane = threadIdx.x & 63;
    int lo = lane & 15;
    int g = lane >> 4;
    int qt = blockIdx.x & 255;
    int h = blockIdx.x >> 8;
    int q0 = qt * 32;
    int m0base = w * 1024;

    const f32x4_t Z = {0.f, 0.f, 0.f, 0.f};
    bf16x8_t zf;
#pragma unroll
    for (int i = 0; i < 8; i++) zf[i] = 0;

    bf16x8_t qf[2];
#pragma unroll
    for (int s = 0; s < 2; s++) {
        if (g < 2) qf[s] = *(const bf16x8_t*)(Qb + (size_t)(q0 + s * 16 + lo) * 64 + h * 16 + g * 8);
        else       qf[s] = zf;
    }

    f32x4_t oacc[2] = {Z, Z};
    float lr[2] = {0.f, 0.f};
    const bf16* kbase = Kb + h * 16 + g * 8;
    const bf16* vbase = VT + (size_t)(h * 16 + lo) * 8192;

    for (int t = 0; t < 32; t++) {
        int m0 = m0base + t * 32;
        bf16x8_t kf0 = zf, kf1 = zf;
        if (g < 2) {
            kf0 = *(const bf16x8_t*)(kbase + (size_t)m0 * 64);
            kf1 = *(const bf16x8_t*)(kbase + (size_t)(m0 + 16) * 64);
        }
        bf16x8_t vt = *(const bf16x8_t*)(vbase + m0 + 8 * g);
#pragma unroll
        for (int s = 0; s < 2; s++) {
            f32x4_t s0 = __builtin_amdgcn_mfma_f32_16x16x32_bf16(kf0, qf[s], Z, 0, 0, 0);
            f32x4_t s1 = __builtin_amdgcn_mfma_f32_16x16x32_bf16(kf1, qf[s], Z, 0, 0, 0);
            float p0 = __builtin_amdgcn_exp2f(s0[0]);
            float p1 = __builtin_amdgcn_exp2f(s0[1]);
            float p2 = __builtin_amdgcn_exp2f(s0[2]);
            float p3 = __builtin_amdgcn_exp2f(s0[3]);
            float p4 = __builtin_amdgcn_exp2f(s1[0]);
            float p5 = __builtin_amdgcn_exp2f(s1[1]);
            float p6 = __builtin_amdgcn_exp2f(s1[2]);
            float p7 = __builtin_amdgcn_exp2f(s1[3]);
            lr[s] += (((p0 + p1) + (p2 + p3)) + ((p4 + p5) + (p6 + p7)));
            unsigned* dst0 = (unsigned*)&plds[w][s][lo][4 * g];
            dst0[0] = pk2(p0, p1);
            dst0[1] = pk2(p2, p3);
            unsigned* dst1 = (unsigned*)&plds[w][s][lo][16 + 4 * g];
            dst1[0] = pk2(p4, p5);
            dst1[1] = pk2(p6, p7);
            bf16x8_t pf = *(const bf16x8_t*)&plds[w][s][lo][8 * g];
            oacc[s] = __builtin_amdgcn_mfma_f32_16x16x32_bf16(vt, pf, oacc[s], 0, 0, 0);
        }
    }
#pragma unroll
    for (int s = 0; s < 2; s++) {
        float l = lr[s];
        l += __shfl_xor(l, 16);
        l += __shfl_xor(l, 32);
        *(f32x4_t*)&redo[w][s][lo][4 * g] = oacc[s];
        if (g == 0) redl[w][s][lo] = l;
    }
    __syncthreads();
    int tid = threadIdx.x;
    int s2 = tid >> 8, q2 = (tid >> 4) & 15, d2 = tid & 15;
    float o = 0.f, l = 0.f;
#pragma unroll
    for (int ww = 0; ww < 8; ww++) {
        o += redo[ww][s2][q2][d2];
        l += redl[ww][s2][q2];
    }
    Bo[(size_t)(q0 + s2 * 16 + q2) * 64 + h * 16 + d2] = o / l;
}

// ---------------- launch ----------------
extern "C" void kernel_launch(void* const* d_in, const int* in_sizes, int n_in,
                              void* d_out, int out_size, void* d_ws, size_t ws_size,
                              hipStream_t stream) {
    int E = in_sizes[1] / 2;
    const int* ei = (const int*)d_in[1];

    int*   ib = (int*)d_ws;
    float* fb = (float*)d_ws;
    int* cnt    = ib;
    int* rowptr = ib + 8192;
    int* fill   = ib + 16448;
    int* ssrc   = ib + 24640;
    int* flagp  = ib + 286784;
    float* dis  = fb + OFF_DIS;
    float* Bias = fb + OFF_BIAS;
    bf16*  Wb   = (bf16*)(fb + OFF_WB);
    float* dsrc = fb + OFF_DSRC;
    bf16*  Xb   = (bf16*)(fb + OFF_X);
    bf16*  HAb  = (bf16*)(fb + OFF_HA);
    bf16*  HBb  = (bf16*)(fb + OFF_HB);
    float* Bo   = fb + OFF_BO;
    bf16*  Qkv  = (bf16*)(fb + OFF_QKV);   // Qb | Kb(+524288) | VT(+1048576)

    dim3 b1024(1024), b512(512), b256(256);
    int eb = (E + 255) / 256;

    CvtTab tab;
    auto ent = [&](int i, const void* s, int n, int dst, int mode, int p0, int p1) {
        tab.e[i] = CvtEnt{s, n, dst, mode, p0, p1};
    };
    ent(0,  d_in[0],  524288, HS_X, 4, 0, 0);   // x -> plain bf16
    ent(1,  d_in[2],  8192,  HS_E1, 2, 128, 0);
    ent(2,  d_in[3],  128,   OFF_BIAS + BF_E1, 0, 0, 0);
    ent(3,  d_in[4],  16384, HS_E2, 2, 128, 0);
    ent(4,  d_in[5],  128,   OFF_BIAS + BF_E2, 0, 0, 0);
    ent(5,  d_in[6],  16384, HS_E3, 2, 128, 0);
    ent(6,  d_in[7],  128,   OFF_BIAS + BF_E3, 0, 0, 0);
    ent(7,  d_in[8],  8192,  HS_E4, 2, 64, 0);
    ent(8,  d_in[9],  64,    OFF_BIAS + BF_E4, 0, 0, 0);
    ent(9,  d_in[10], 8192,  HS_D1, 2, 128, 0);
    ent(10, d_in[11], 128,   OFF_BIAS + BF_D1, 0, 0, 0);
    ent(11, d_in[12], 16384, HS_D2, 2, 128, 0);
    ent(12, d_in[13], 128,   OFF_BIAS + BF_D2, 0, 0, 0);
    ent(13, d_in[14], 16384, HS_D3, 2, 128, 0);
    ent(14, d_in[15], 128,   OFF_BIAS + BF_D3, 0, 0, 0);
    ent(15, d_in[16], 8192,  HS_D4, 2, 64, 0);
    ent(16, d_in[17], 64,    OFF_BIAS + BF_D4, 0, 0, 0);
    ent(17, d_in[18], 12288, HS_AI, 3, 0, 192);
    ent(18, d_in[19], 192,   OFF_BIAS + BF_AI, 0, 0, 0);
    ent(19, d_in[20], 4096,  HS_AO, 3, 0, 64);
    ent(20, d_in[21], 64,    OFF_BIAS + BF_AO, 0, 0, 0);

    hipMemsetAsync(cnt, 0, 8192 * sizeof(int), stream);
    k_convert<<<dim3(2501), b256, 0, stream>>>(tab, fb, Wb, flagp,
                                               (const unsigned short*)d_in[0], ei, E, cnt);
    k_scan<<<dim3(1), b256, 0, stream>>>(cnt, rowptr, fill, dis);
    k_scatter<<<dim3(eb), b256, 0, stream>>>(ei, E, fill, ssrc, dis, dsrc);

    dim3 g512(512), g1024(1024);

    // encoder (bf16 gathers)
    k_fused<64, 128, 1, 512, 1><<<g512, b512, 0, stream>>>(Xb, rowptr, ssrc, dsrc, dis,
        Wb + HS_E1, Bias + BF_E1, nullptr, HAb, nullptr, 0, flagp);
    k_fused<128, 128, 1, 1024, 1><<<g512, b1024, 0, stream>>>(HAb, rowptr, ssrc, dsrc, dis,
        Wb + HS_E2, Bias + BF_E2, HAb, HBb, nullptr, 0, flagp);
    k_fused<128, 128, 1, 1024, 1><<<g512, b1024, 0, stream>>>(HBb, rowptr, ssrc, dsrc, dis,
        Wb + HS_E3, Bias + BF_E3, HBb, HAb, nullptr, 0, flagp);
    // e4 + qkv projection fused (z -> d_out[524288:], qkv -> Qkv)
    k_fused_qkv<<<g512, b1024, 0, stream>>>(HAb, rowptr, ssrc, dsrc, dis,
        Wb + HS_E4, Bias + BF_E4, Wb + HS_AI, Bias + BF_AI, d_out, 524288, flagp, Qkv);

    // attention
    k_flash<<<g1024, b512, 0, stream>>>(Qkv, Qkv + 524288, Qkv + 1048576, Bo);

    // decoder: out-proj + d1 fused
    k_fused_d1<<<g512, b512, 0, stream>>>(Bo, rowptr, ssrc, dsrc, dis,
        Wb + HS_AO, Bias + BF_AO, Wb + HS_D1, Bias + BF_D1, HAb);
    k_fused<128, 128, 1, 1024, 1><<<g512, b1024, 0, stream>>>(HAb, rowptr, ssrc, dsrc, dis,
        Wb + HS_D2, Bias + BF_D2, HAb, HBb, nullptr, 0, flagp);
    k_fused<128, 128, 1, 1024, 1><<<g512, b1024, 0, stream>>>(HBb, rowptr, ssrc, dsrc, dis,
        Wb + HS_D3, Bias + BF_D3, HBb, HAb, nullptr, 0, flagp);
    k_fused<128, 64, 0, 1024, 1><<<g512, b1024, 0, stream>>>(HAb, rowptr, ssrc, dsrc, dis,
        Wb + HS_D4, Bias + BF_D4, nullptr, nullptr, d_out, 0, flagp);
}